// Round 1
// 335.786 us; speedup vs baseline: 1.0560x; 1.0560x over previous
//
#include <hip/hip_runtime.h>

#define VV 3
#define NN 6000
#define DD 512
#define HH 256
#define DYY 512
#define NPAD 6016   // 47*128
#define QK_BK 32
#define QK_ROWS 192              // 64 A-rows + 128 B-rows for ONE v-slice
#define QK_BUF (QK_ROWS * QK_BK) // u16 elems per staging buffer (12288 B)

typedef unsigned short u16;
typedef unsigned char u8;
typedef __bf16 bf16x8 __attribute__((ext_vector_type(8)));
typedef u16 u16x8 __attribute__((ext_vector_type(8)));
typedef float f32x4 __attribute__((ext_vector_type(4)));
typedef u16 u16x4 __attribute__((ext_vector_type(4)));
typedef unsigned int u32x4 __attribute__((ext_vector_type(4)));

__device__ __forceinline__ u16 f2bf(float f) {
  unsigned int b = __builtin_bit_cast(unsigned int, f);
  b += 0x7FFFu + ((b >> 16) & 1u);
  return (u16)(b >> 16);
}
__device__ __forceinline__ float bf2f(u16 u) {
  unsigned int b = ((unsigned int)u) << 16;
  return __builtin_bit_cast(float, b);
}
// manual OCP e4m3fn encode (RNE, clamp 448, subnormals) — no builtin dependency
__device__ __forceinline__ u8 f2fp8(float f) {
  unsigned int u = __builtin_bit_cast(unsigned int, f);
  u8 sign = (u >> 24) & 0x80;
  float af = __builtin_bit_cast(float, u & 0x7fffffffu);
  if (af >= 448.0f) return sign | 0x7E;
  if (af < 0.015625f) {                      // subnormal: round af*2^9
    int m = (int)(af * 512.0f + 0.5f);
    return sign | (u8)m;                     // m==8 -> 0x08 == 2^-6, correct
  }
  unsigned int mant = u & 0x7fffff;
  unsigned int exp = (u >> 23) & 0xff;       // 121..135
  unsigned int r = ((exp << 23) | mant) + 0x7FFFFu + ((mant >> 20) & 1u);
  exp = r >> 23; mant = (r >> 20) & 7u;
  return sign | (u8)(((exp - 120u) << 3) | mant);
}
__device__ __forceinline__ float fp82f(u8 b) {
  int e = (b >> 3) & 15, m = b & 7;
  float v = e ? __builtin_bit_cast(float, (unsigned)((e + 120) << 23 | (m << 20)))
              : (float)m * 0.001953125f;
  return (b & 0x80) ? -v : v;
}
__device__ __forceinline__ float leaky(float v) { return v >= 0.0f ? v : 0.1f * v; }

// ---- stage ROWS x DEPTH bf16 tile: global row-major (ld elems) -> LDS [ROWS][DEPTH]
template<int ROWS, int DEPTH = 64>
__device__ __forceinline__ void stage(const u16* __restrict__ g, int ld, u16* s, int wave, int lane) {
  constexpr int LPR = DEPTH / 8;   // lanes per row (16B each)
  constexpr int RPC = 64 / LPR;    // rows per chunk
  constexpr int PER = ROWS / 4;    // rows per wave
  const u16* gp = g + (wave * PER + lane / LPR) * ld + (lane % LPR) * 8;
  u16* sp = s + wave * PER * DEPTH;
#pragma unroll
  for (int ch = 0; ch < PER / RPC; ++ch) {
    __builtin_amdgcn_global_load_lds(
        (const __attribute__((address_space(1))) void*)(gp + ch * RPC * ld),
        (__attribute__((address_space(3))) void*)(sp + ch * RPC * DEPTH), 16, 0, 0);
  }
}

// ---- fp8 stage: ROWS x 64-byte rows with 16-B-chunk XOR swizzle (bank-conflict-free reads)
__device__ __forceinline__ int swz4(int r) { return (r & 3) ^ ((r >> 2) & 3); }
template<int ROWS>
__device__ __forceinline__ void stage8(const u8* __restrict__ g, int ld, u8* s, int wave, int lane) {
  constexpr int PER = ROWS / 4;    // rows per wave (4 lanes/row, 16 rows per 64-lane chunk)
  int rin = lane >> 2, c = lane & 3;
#pragma unroll
  for (int ch = 0; ch < PER / 16; ++ch) {
    int rloc = wave * PER + ch * 16 + rin;
    const u8* gp = g + (size_t)rloc * ld + ((c ^ swz4(rloc)) << 4);
    u8* sp = s + (wave * PER + ch * 16) * 64;   // wave-uniform; lane lands at +16B*lane
    __builtin_amdgcn_global_load_lds(
        (const __attribute__((address_space(1))) void*)gp,
        (__attribute__((address_space(3))) void*)sp, 16, 0, 0);
  }
}

// ---- wave computes (RT*16) x 64 outputs; block = 4 waves in 2x2 -> (RT*32) x 128 tile
template<int RT, int DEPTH = 64>
__device__ __forceinline__ void mfma_step(const u16* As, const u16* Bs, f32x4 (*acc)[4], int lane, int wave) {
  const int wr = (wave >> 1) * (RT * 16);
  const int wc = (wave & 1) * 64;
  const int l15 = lane & 15;
  const int lq = lane >> 4;
#pragma unroll
  for (int kk = 0; kk < DEPTH; kk += 32) {
    bf16x8 a[RT], b[4];
#pragma unroll
    for (int i = 0; i < RT; ++i)
      a[i] = *(const bf16x8*)(As + (wr + i * 16 + l15) * DEPTH + kk + lq * 8);
#pragma unroll
    for (int j = 0; j < 4; ++j)
      b[j] = *(const bf16x8*)(Bs + (wc + j * 16 + l15) * DEPTH + kk + lq * 8);
#pragma unroll
    for (int i = 0; i < RT; ++i)
#pragma unroll
      for (int j = 0; j < 4; ++j)
        acc[i][j] = __builtin_amdgcn_mfma_f32_16x16x32_bf16(a[i], b[j], acc[i][j], 0, 0, 0);
  }
}

// fp8 MFMA step: 128x128 tile, 64 K-elems (64 B) per slice, swizzled LDS
__device__ __forceinline__ void mfma_step8(const u8* As, const u8* Bs, f32x4 (*acc)[4], int lane, int wave) {
  const int wr = (wave >> 1) * 64;
  const int wc = (wave & 1) * 64;
  const int l15 = lane & 15, lq = lane >> 4;
#pragma unroll
  for (int kk = 0; kk < 64; kk += 32) {
    long a[4], b[4];
    int gch = (kk >> 4) + (lq >> 1), half = (lq & 1) << 3;
#pragma unroll
    for (int i = 0; i < 4; ++i) {
      int r = wr + i * 16 + l15;
      a[i] = *(const long*)(As + r * 64 + ((gch ^ swz4(r)) << 4) + half);
    }
#pragma unroll
    for (int j = 0; j < 4; ++j) {
      int r = wc + j * 16 + l15;
      b[j] = *(const long*)(Bs + r * 64 + ((gch ^ swz4(r)) << 4) + half);
    }
#pragma unroll
    for (int i = 0; i < 4; ++i)
#pragma unroll
      for (int j = 0; j < 4; ++j)
        acc[i][j] = __builtin_amdgcn_mfma_f32_16x16x32_fp8_fp8(a[i], b[j], acc[i][j], 0, 0, 0);
  }
}

// single-buffered K-loop
template<int RT>
__device__ __forceinline__ void gemm_loop(const u16* __restrict__ A, int lda,
                                          const u16* __restrict__ B, int ldb, int K,
                                          u16* As, u16* Bs, f32x4 (*acc)[4], int lane, int wave) {
  for (int k0 = 0; k0 < K; k0 += 64) {
    stage<RT * 32>(A + k0, lda, As, wave, lane);
    stage<128>(B + k0, ldb, Bs, wave, lane);
    __syncthreads();
    mfma_step<RT>(As, Bs, acc, lane, wave);
    __syncthreads();
  }
}

// double-buffered K-loop
template<int RT>
__device__ __forceinline__ void gemm_loop_db(const u16* __restrict__ A, int lda,
                                             const u16* __restrict__ B, int ldb, int K,
                                             u16* As, u16* Bs, f32x4 (*acc)[4], int lane, int wave) {
  const int niter = K / 64;
  stage<RT * 32>(A, lda, As, wave, lane);
  stage<128>(B, ldb, Bs, wave, lane);
  for (int it = 0; it < niter; ++it) {
    __syncthreads();
    int nb = (it + 1) & 1;
    if (it + 1 < niter) {
      stage<RT * 32>(A + (it + 1) * 64, lda, As + nb * RT * 32 * 64, wave, lane);
      stage<128>(B + (it + 1) * 64, ldb, Bs + nb * 128 * 64, wave, lane);
    }
    int cb = it & 1;
    mfma_step<RT>(As + cb * RT * 32 * 64, Bs + cb * 128 * 64, acc, lane, wave);
  }
  __syncthreads();
}

// ---------------- elementwise / prep kernels ----------------

__global__ __launch_bounds__(256) void k_conv(const float* __restrict__ in, u16* __restrict__ out, int n4) {
  int i = blockIdx.x * 256 + threadIdx.x;
  if (i >= n4) return;
  float4 f = ((const float4*)in)[i];
  u16x4 o = { f2bf(f.x), f2bf(f.y), f2bf(f.z), f2bf(f.w) };
  *(u16x4*)(out + i * 4) = o;
}

__global__ __launch_bounds__(256) void k_convx(const float* __restrict__ x, u16* __restrict__ xb) {
  int i = blockIdx.x * 256 + threadIdx.x;
  if (i >= VV * NN * DD / 4) return;
  int idx = i * 4;
  int v = idx / (NN * DD);
  int rem = idx - v * (NN * DD);
  int n = rem / DD;
  int d = rem - n * DD;
  float4 f = *(const float4*)(x + idx);
  u16x4 o = { f2bf(f.x), f2bf(f.y), f2bf(f.z), f2bf(f.w) };
  *(u16x4*)(xb + (size_t)(v * NPAD + n) * DD + d) = o;
}

__global__ __launch_bounds__(256) void k_mt(const float* __restrict__ mask, float* __restrict__ mT) {
  int i = blockIdx.x * 256 + threadIdx.x;
  if (i >= VV * NPAD) return;
  int v = i / NPAD, n = i - v * NPAD;
  mT[i] = (n < NN) ? mask[n * VV + v] : 0.0f;
}

__global__ __launch_bounds__(256) void k_qprep(const float* __restrict__ h, u16* __restrict__ qb) {
  int b = blockIdx.x;
  int v = b / NN, n = b - v * NN;
  int t = threadIdx.x;
  float val = h[(size_t)(v * NPAD + n) * HH + t];
  float ss = val * val;
#pragma unroll
  for (int o = 32; o > 0; o >>= 1) ss += __shfl_down(ss, o, 64);
  __shared__ float red[4];
  if ((t & 63) == 0) red[t >> 6] = ss;
  __syncthreads();
  float inv = 1.0f / fmaxf(sqrtf(red[0] + red[1] + red[2] + red[3]), 1e-12f);
  qb[(size_t)(v * NPAD + n) * HH + t] = f2bf(val * inv);
}

// hmT[v][j][m] = mT[v][m]*h[v][m][j] (fp8 e4m3, zero for m>=NN)
__global__ __launch_bounds__(1024) void k_hmt(const float* __restrict__ h, const float* __restrict__ mT,
                                              u8* __restrict__ hmT) {
  __shared__ float t[64][65];
  int m0 = blockIdx.x * 64, j0 = blockIdx.y * 64, v = blockIdx.z;
  int tx = threadIdx.x, ty = threadIdx.y;
#pragma unroll
  for (int p = 0; p < 4; ++p) {
    int ml = ty + p * 16;
    int m = m0 + ml;
    float val = 0.0f;
    if (m < NN) val = mT[v * NPAD + m] * h[(size_t)(v * NPAD + m) * HH + j0 + tx];
    t[ml][tx] = val;
  }
  __syncthreads();
#pragma unroll
  for (int p = 0; p < 4; ++p) {
    int j = j0 + ty + p * 16;
    hmT[(size_t)(v * HH + j) * NPAD + m0 + tx] = f2fp8(t[tx][ty + p * 16]);
  }
}

// ---------------- GEMM kernels ----------------

__global__ __launch_bounds__(256, 3) void k_gemm1(const u16* __restrict__ xb, const u16* __restrict__ winb,
                                                  const float* __restrict__ b_in, float* __restrict__ h) {
  __shared__ u16 As[2 * 64 * 64], Bs[2 * 128 * 64];
  int lane = threadIdx.x & 63, wave = threadIdx.x >> 6;
  int col0 = blockIdx.x * 128, row0 = blockIdx.y * 64, v = blockIdx.z;
  f32x4 acc[2][4];
  f32x4 z = {0.f, 0.f, 0.f, 0.f};
  for (int i = 0; i < 2; ++i) for (int j = 0; j < 4; ++j) acc[i][j] = z;
  gemm_loop_db<2>(xb + (size_t)(v * NPAD + row0) * DD, DD,
                  winb + (size_t)(v * HH + col0) * DD, DD, DD, As, Bs, acc, lane, wave);
  int wr = (wave >> 1) * 32, wc = (wave & 1) * 64, l15 = lane & 15, lq = lane >> 4;
#pragma unroll
  for (int i = 0; i < 2; ++i)
#pragma unroll
    for (int r = 0; r < 4; ++r) {
      int grow = row0 + wr + i * 16 + lq * 4 + r;
      if (grow < NN) {
#pragma unroll
        for (int j = 0; j < 4; ++j) {
          int gcol = col0 + wc + j * 16 + l15;
          h[(size_t)(v * NPAD + grow) * HH + gcol] = leaky(acc[i][j][r] + b_in[v * HH + gcol]);
        }
      }
    }
}

// A = max_v mask*exp(q_v q_v^T / beta), diag zeroed -> fp8 e4m3.
// Sequential-v staging (one v per K-step) -> 24.6 KB LDS dbuf -> 4 blocks/CU
// (__launch_bounds__(256,4)) vs the old 2. Per-v flush keeps a running masked
// MAX of raw scores (exp is monotone: max_v mask*e^{5s} == e^{5*max masked s},
// all-masked -> -inf -> exp -> 0), so only ONE expf+f2fp8 per element at the
// end. Row sums S moved to k_rowsum (A is fully materialized, both triangles).
__global__ __launch_bounds__(256, 4) void k_qk(const u16* __restrict__ qb, const float* __restrict__ mT,
                                               u8* __restrict__ Abf) {
  __shared__ u16 sh[2 * QK_BUF];   // 24576 B; reused for Dir/Tr in epilogue
  int lane = threadIdx.x & 63, wave = threadIdx.x >> 6;
  int bid = blockIdx.x;
  int x = (int)((sqrtf((float)(4 * bid + 1)) - 1.0f) * 0.5f);
  while ((x + 1) * (x + 2) <= bid) ++x;
  while (x * (x + 1) > bid) --x;
  int y = bid - x * (x + 1);
  int col0 = x * 128, row0 = y * 64;

  const int wr = (wave >> 1) * 32, wc = (wave & 1) * 64;
  const int l15 = lane & 15, lq = lane >> 4;

  f32x4 z = {0.f, 0.f, 0.f, 0.f};
  float ninf = -__builtin_inff();
  f32x4 nv = {ninf, ninf, ninf, ninf};
  f32x4 acc[2][4];
  f32x4 emax[2][4];
  for (int i = 0; i < 2; ++i)
    for (int j = 0; j < 4; ++j) { acc[i][j] = z; emax[i][j] = nv; }

  auto stage_it = [&](int it, u16* buf) {
    int v = it >> 3, k0 = (it & 7) * QK_BK;
    const u16* base = qb + (size_t)v * NPAD * HH + k0;
    stage<64, QK_BK>(base + (size_t)row0 * HH, HH, buf, wave, lane);
    stage<128, QK_BK>(base + (size_t)col0 * HH, HH, buf + 64 * QK_BK, wave, lane);
  };

  stage_it(0, sh);
  const int NIT = VV * (HH / QK_BK);   // 24
  for (int it = 0; it < NIT; ++it) {
    __syncthreads();
    if (it + 1 < NIT) stage_it(it + 1, sh + ((it + 1) & 1) * QK_BUF);
    u16* cur = sh + (it & 1) * QK_BUF;
    mfma_step<2, QK_BK>(cur, cur + 64 * QK_BK, acc, lane, wave);
    if ((it & 7) == 7) {               // v complete: fold masked scores into emax
      int v = it >> 3;
      const float* mv = mT + v * NPAD;
      float mc[4];
#pragma unroll
      for (int j = 0; j < 4; ++j) mc[j] = mv[col0 + wc + j * 16 + l15];
#pragma unroll
      for (int i = 0; i < 2; ++i)
#pragma unroll
        for (int r = 0; r < 4; ++r) {
          float mr = mv[row0 + wr + i * 16 + lq * 4 + r];
#pragma unroll
          for (int j = 0; j < 4; ++j) {
            if (mr * mc[j] != 0.0f) emax[i][j][r] = fmaxf(emax[i][j][r], acc[i][j][r]);
            acc[i][j][r] = 0.0f;
          }
        }
    }
  }
  __syncthreads();

  // epilogue: Dir [64][144] u8 (direct tile), Tr [128][80] u8 (mirror) in sh
  u8* Dir = (u8*)sh;
  u8* Tr  = (u8*)sh + 64 * 144;
#pragma unroll
  for (int i = 0; i < 2; ++i)
#pragma unroll
    for (int r = 0; r < 4; ++r) {
      int lrow = wr + i * 16 + lq * 4 + r;
      int grow = row0 + lrow;
#pragma unroll
      for (int j = 0; j < 4; ++j) {
        int lcol = wc + j * 16 + l15;
        int gcol = col0 + lcol;
        float val = __expf(emax[i][j][r] * 5.0f);
        if (grow == gcol) val = 0.0f;
        u8 q = f2fp8(val);
        Dir[lrow * 144 + lcol] = q;
        Tr[lcol * 80 + lrow] = (gcol > grow) ? q : (u8)0;
      }
    }
  __syncthreads();
  if (col0 >= row0 + 64) {   // fully-upper tile: 16-B vector stores
    int c8 = threadIdx.x & 7, rr = threadIdx.x >> 3;
#pragma unroll
    for (int p = 0; p < 2; ++p) {
      int row = rr + p * 32;
      u32x4 ch = *(const u32x4*)(Dir + row * 144 + c8 * 16);
      *(u32x4*)(Abf + (size_t)(row0 + row) * NPAD + col0 + c8 * 16) = ch;
    }
    int c = threadIdx.x & 3; rr = threadIdx.x >> 2;
#pragma unroll
    for (int p = 0; p < 2; ++p) {
      int cc = rr + p * 64;
      u32x4 ch = *(const u32x4*)(Tr + cc * 80 + c * 16);
      *(u32x4*)(Abf + (size_t)(col0 + cc) * NPAD + row0 + c * 16) = ch;
    }
  } else {                    // straddle tile: predicated scalar
    for (int idx = threadIdx.x; idx < 64 * 128; idx += 256) {
      int row = idx >> 7, cc = idx & 127;
      int R = row0 + row, C = col0 + cc;
      u8 val = Dir[row * 144 + cc];
      if (C >= R) Abf[(size_t)R * NPAD + C] = val;
      if (C > R)  Abf[(size_t)C * NPAD + R] = val;
    }
  }
}

// S[n] = sum_m dequant(Abf[n][m]) — replaces the atomicAdd path in k_qk.
// Abf holds both triangles with zero diag/pad, so a plain row sum is
// numerically identical to the old dequantized accumulation. ~36 MB read.
__global__ __launch_bounds__(256) void k_rowsum(const u8* __restrict__ Abf, float* __restrict__ S) {
  int row = blockIdx.x;
  const u8* rp = Abf + (size_t)row * NPAD;
  float s = 0.0f;
  for (int c = threadIdx.x * 16; c < NPAD; c += 256 * 16) {
    u32x4 ch = *(const u32x4*)(rp + c);
#pragma unroll
    for (int w = 0; w < 4; ++w) {
      unsigned int u = ch[w];
#pragma unroll
      for (int b = 0; b < 4; ++b) s += fp82f((u8)(u >> (8 * b)));
    }
  }
#pragma unroll
  for (int o = 32; o > 0; o >>= 1) s += __shfl_down(s, o, 64);
  __shared__ float red[4];
  if ((threadIdx.x & 63) == 0) red[threadIdx.x >> 6] = s;
  __syncthreads();
  if (threadIdx.x == 0) S[row] = red[0] + red[1] + red[2] + red[3];
}

// partial[z] = Abf[:, zK:(z+1)K] @ hmT_all[:, zK:(z+1)K]^T  (fp8 operands, f32 acc,
// bf16 partials). XCD-swizzled flat grid: all 12 blocks of a row-panel share an XCD.
__global__ __launch_bounds__(256, 4) void k_pvsk(const u8* __restrict__ Abf, const u8* __restrict__ hmT,
                                                 u16* __restrict__ part) {
  __shared__ u8 sh8[2 * 2 * 128 * 64];   // [buf][A/B][128][64] = 32 KB
  int lane = threadIdx.x & 63, wave = threadIdx.x >> 6;
  int bid = blockIdx.x;                  // 576 (12 dummy)
  int xcd = bid & 7, s = bid >> 3;
  int row = (s / 12) * 8 + xcd;
  if (row >= 47) return;
  int k = s % 12;
  int col0 = (k % 6) * 128, row0 = row * 128, kb = (k / 6) * (NPAD / 2);

  f32x4 acc[4][4];
  f32x4 z = {0.f, 0.f, 0.f, 0.f};
  for (int i = 0; i < 4; ++i) for (int j = 0; j < 4; ++j) acc[i][j] = z;

  const u8* Ap = Abf + (size_t)row0 * NPAD + kb;
  const u8* Bp = hmT + (size_t)col0 * NPAD + kb;
  auto pv_stage = [&](int it, int buf) {
    u8* base = sh8 + buf * 16384;
    stage8<128>(Ap + it * 64, NPAD, base, wave, lane);
    stage8<128>(Bp + it * 64, NPAD, base + 8192, wave, lane);
  };
  const int niter = (NPAD / 2) / 64;   // 47
  pv_stage(0, 0);
  for (int it = 0; it < niter; ++it) {
    __syncthreads();
    if (it + 1 < niter) pv_stage(it + 1, (it + 1) & 1);
    u8* cur = sh8 + (it & 1) * 16384;
    mfma_step8(cur, cur + 8192, acc, lane, wave);
  }

  u16* pp = part + (size_t)(k / 6) * NPAD * (VV * HH);
  int wr = (wave >> 1) * 64, wc = (wave & 1) * 64, l15 = lane & 15, lq = lane >> 4;
#pragma unroll
  for (int i = 0; i < 4; ++i)
#pragma unroll
    for (int r = 0; r < 4; ++r) {
      int grow = row0 + wr + i * 16 + lq * 4 + r;
#pragma unroll
      for (int j = 0; j < 4; ++j) {
        int gcol = col0 + wc + j * 16 + l15;
        pp[(size_t)grow * (VV * HH) + gcol] = f2bf(acc[i][j][r]);
      }
    }
}

// newx = blend((p0+p1)/S, h); writes out_newx (f32) and nxb (bf16)
__global__ __launch_bounds__(256) void k_pvred(const u16* __restrict__ part, const float* __restrict__ S,
                                               const float* __restrict__ mT, const float* __restrict__ h,
                                               float* __restrict__ out_newx, u16* __restrict__ nxb) {
  int i = (blockIdx.x * 256 + threadIdx.x) * 4;
  int v = i / (NN * HH);
  int rem = i - v * (NN * HH);
  int n = rem / HH;
  int j = rem - n * HH;
  int col = v * HH + j;
  u16x4 p0 = *(const u16x4*)(part + (size_t)n * (VV * HH) + col);
  u16x4 p1 = *(const u16x4*)(part + (size_t)NPAD * (VV * HH) + (size_t)n * (VV * HH) + col);
  float sc = 1.0f / (S[n] + 1e-9f);
  float mrow = mT[v * NPAD + n];
  float4 o;
  o.x = (bf2f(p0[0]) + bf2f(p1[0])) * sc;
  o.y = (bf2f(p0[1]) + bf2f(p1[1])) * sc;
  o.z = (bf2f(p0[2]) + bf2f(p1[2])) * sc;
  o.w = (bf2f(p0[3]) + bf2f(p1[3])) * sc;
  if (mrow != 0.0f) o = *(const float4*)(h + (size_t)(v * NPAD + n) * HH + j);
  *(float4*)(out_newx + (size_t)(v * NN + n) * HH + j) = o;
  u16x4 ob = { f2bf(o.x), f2bf(o.y), f2bf(o.z), f2bf(o.w) };
  *(u16x4*)(nxb + (size_t)(v * NPAD + n) * HH + j) = ob;
}

// x_new = leaky(new_x @ W_out^T + b_out), nan->0  [RT=2, double-buffered]
__global__ __launch_bounds__(256, 3) void k_gemm3(const u16* __restrict__ nxb, const u16* __restrict__ woutb,
                                                  const float* __restrict__ b_out, float* __restrict__ out_xnew) {
  __shared__ u16 As[2 * 64 * 64], Bs[2 * 128 * 64];
  int lane = threadIdx.x & 63, wave = threadIdx.x >> 6;
  int col0 = blockIdx.x * 128, row0 = blockIdx.y * 64, v = blockIdx.z;
  f32x4 acc[2][4];
  f32x4 z = {0.f, 0.f, 0.f, 0.f};
  for (int i = 0; i < 2; ++i) for (int j = 0; j < 4; ++j) acc[i][j] = z;
  gemm_loop_db<2>(nxb + (size_t)(v * NPAD + row0) * HH, HH,
                  woutb + (size_t)(v * DD + col0) * HH, HH, HH, As, Bs, acc, lane, wave);
  int wr = (wave >> 1) * 32, wc = (wave & 1) * 64, l15 = lane & 15, lq = lane >> 4;
#pragma unroll
  for (int i = 0; i < 2; ++i)
#pragma unroll
    for (int r = 0; r < 4; ++r) {
      int grow = row0 + wr + i * 16 + lq * 4 + r;
      if (grow < NN) {
#pragma unroll
        for (int j = 0; j < 4; ++j) {
          int gcol = col0 + wc + j * 16 + l15;
          float val = leaky(acc[i][j][r] + b_out[v * DD + gcol]);
          if (val != val) val = 0.0f;
          out_xnew[(size_t)(v * NN + grow) * DD + gcol] = val;
        }
      }
    }
}

// y_n = sigmoid(y @ Wy^T + by)  [RT=2, double-buffered]
__global__ __launch_bounds__(256, 3) void k_ygemm(const u16* __restrict__ yb, const u16* __restrict__ wyb,
                                                  const float* __restrict__ by, float* __restrict__ out_yn) {
  __shared__ u16 As[2 * 64 * 64], Bs[2 * 128 * 64];
  int lane = threadIdx.x & 63, wave = threadIdx.x >> 6;
  int col0 = blockIdx.x * 128, row0 = blockIdx.y * 64;
  f32x4 acc[2][4];
  f32x4 z = {0.f, 0.f, 0.f, 0.f};
  for (int i = 0; i < 2; ++i) for (int j = 0; j < 4; ++j) acc[i][j] = z;
  gemm_loop_db<2>(yb + (size_t)row0 * DYY, DYY, wyb + (size_t)col0 * DYY, DYY, DYY, As, Bs, acc, lane, wave);
  int wr = (wave >> 1) * 32, wc = (wave & 1) * 64, l15 = lane & 15, lq = lane >> 4;
#pragma unroll
  for (int i = 0; i < 2; ++i)
#pragma unroll
    for (int r = 0; r < 4; ++r) {
      int grow = row0 + wr + i * 16 + lq * 4 + r;
      if (grow < NN) {
#pragma unroll
        for (int j = 0; j < 4; ++j) {
          int gcol = col0 + wc + j * 16 + l15;
          float val = acc[i][j][r] + by[gcol];
          out_yn[(size_t)grow * HH + gcol] = 1.0f / (1.0f + __expf(-val));
        }
      }
    }
}

// ---------------- launch ----------------

extern "C" void kernel_launch(void* const* d_in, const int* in_sizes, int n_in,
                              void* d_out, int out_size, void* d_ws, size_t ws_size,
                              hipStream_t stream) {
  const float* x    = (const float*)d_in[0];
  const float* y    = (const float*)d_in[1];
  const float* mask = (const float*)d_in[2];
  const float* W_in = (const float*)d_in[3];
  const float* b_in = (const float*)d_in[4];
  const float* W_out= (const float*)d_in[5];
  const float* b_out= (const float*)d_in[6];
  const float* Wy   = (const float*)d_in[7];
  const float* by   = (const float*)d_in[8];

  float* out_newx = (float*)d_out;
  float* out_xnew = out_newx + (size_t)VV * NN * HH;
  float* out_yn   = out_xnew + (size_t)VV * NN * DD;

  char* w = (char*)d_ws;
  size_t off = 0;
  auto alloc = [&](size_t bytes) -> void* {
    void* p = w + off;
    off += (bytes + 255) & ~(size_t)255;
    return p;
  };
  u16*   xb    = (u16*)alloc((size_t)VV * NPAD * DD * 2);
  u16*   yb    = (u16*)alloc((size_t)NPAD * DYY * 2);
  u16*   winb  = (u16*)alloc((size_t)VV * HH * DD * 2);
  u16*   woutb = (u16*)alloc((size_t)VV * DD * HH * 2);
  u16*   wyb   = (u16*)alloc((size_t)HH * DYY * 2);
  float* h     = (float*)alloc((size_t)VV * NPAD * HH * 4);
  u16*   qb    = (u16*)alloc((size_t)VV * NPAD * HH * 2);
  u8*    hmT   = (u8*)alloc((size_t)VV * HH * NPAD);
  u16*   nxb   = (u16*)alloc((size_t)VV * NPAD * HH * 2);
  float* mT    = (float*)alloc((size_t)VV * NPAD * 4);
  float* S     = (float*)alloc((size_t)NPAD * 4);
  u8*    Abf   = (u8*)alloc((size_t)NPAD * NPAD);
  // split-K partials (2 x NPAD x 768 bf16 = 18.48 MB) reuse xb, dead after k_gemm1
  u16*   pvp   = xb;
  (void)ws_size; (void)in_sizes; (void)n_in; (void)out_size;

  // conversions
  k_conv<<<384, 256, 0, stream>>>(W_in, winb, VV * HH * DD / 4);
  k_conv<<<384, 256, 0, stream>>>(W_out, woutb, VV * DD * HH / 4);
  k_conv<<<128, 256, 0, stream>>>(Wy, wyb, HH * DYY / 4);
  k_conv<<<3000, 256, 0, stream>>>(y, yb, NN * DYY / 4);
  k_convx<<<9000, 256, 0, stream>>>(x, xb);
  k_mt<<<(VV * NPAD + 255) / 256, 256, 0, stream>>>(mask, mT);

  // h, q, hmT
  k_gemm1<<<dim3(2, 94, 3), 256, 0, stream>>>(xb, winb, b_in, h);
  k_qprep<<<VV * NN, 256, 0, stream>>>(h, qb);
  k_hmt<<<dim3(94, 4, 3), dim3(64, 16), 0, stream>>>(h, mT, hmT);

  // attention
  k_qk<<<2256, 256, 0, stream>>>(qb, mT, Abf);
  k_rowsum<<<NN, 256, 0, stream>>>(Abf, S);
  k_pvsk<<<576, 256, 0, stream>>>(Abf, hmT, pvp);
  k_pvred<<<4500, 256, 0, stream>>>(pvp, S, mT, h, out_newx, nxb);

  // outputs
  k_gemm3<<<dim3(4, 94, 3), 256, 0, stream>>>(nxb, woutb, b_out, out_xnew);
  k_ygemm<<<dim3(2, 94), 256, 0, stream>>>(yb, wyb, by, out_yn);
}

// Round 2
// 322.856 us; speedup vs baseline: 1.0983x; 1.0400x over previous
//
#include <hip/hip_runtime.h>

#define VV 3
#define NN 6000
#define DD 512
#define HH 256
#define DYY 512
#define NPAD 6016   // 47*128
#define QK_BK 32
#define QK_ROWS 192              // 64 A-rows + 128 B-rows for ONE v-slice
#define QK_BUF (QK_ROWS * QK_BK) // u16 elems per staging buffer (12288 B)

typedef unsigned short u16;
typedef unsigned char u8;
typedef __bf16 bf16x8 __attribute__((ext_vector_type(8)));
typedef u16 u16x8 __attribute__((ext_vector_type(8)));
typedef float f32x4 __attribute__((ext_vector_type(4)));
typedef u16 u16x4 __attribute__((ext_vector_type(4)));
typedef unsigned int u32x4 __attribute__((ext_vector_type(4)));

__device__ __forceinline__ u16 f2bf(float f) {
  unsigned int b = __builtin_bit_cast(unsigned int, f);
  b += 0x7FFFu + ((b >> 16) & 1u);
  return (u16)(b >> 16);
}
__device__ __forceinline__ float bf2f(u16 u) {
  unsigned int b = ((unsigned int)u) << 16;
  return __builtin_bit_cast(float, b);
}
// hardware OCP e4m3fn convert (RNE, saturating) — 1 inst vs ~20 for manual
__device__ __forceinline__ u8 f2fp8_hw(float f) {
  unsigned int r;
  asm("v_cvt_pk_fp8_f32 %0, %1, %2" : "=v"(r) : "v"(f), "v"(f));
  return (u8)(r & 0xffu);
}
__device__ __forceinline__ float fp82f(u8 b) {
  int e = (b >> 3) & 15, m = b & 7;
  float v = e ? __builtin_bit_cast(float, (unsigned)((e + 120) << 23 | (m << 20)))
              : (float)m * 0.001953125f;
  return (b & 0x80) ? -v : v;
}
__device__ __forceinline__ float leaky(float v) { return v >= 0.0f ? v : 0.1f * v; }

// ---- stage ROWS x DEPTH bf16 tile: global row-major (ld elems) -> LDS [ROWS][DEPTH]
template<int ROWS, int DEPTH = 64>
__device__ __forceinline__ void stage(const u16* __restrict__ g, int ld, u16* s, int wave, int lane) {
  constexpr int LPR = DEPTH / 8;   // lanes per row (16B each)
  constexpr int RPC = 64 / LPR;    // rows per chunk
  constexpr int PER = ROWS / 4;    // rows per wave
  const u16* gp = g + (wave * PER + lane / LPR) * ld + (lane % LPR) * 8;
  u16* sp = s + wave * PER * DEPTH;
#pragma unroll
  for (int ch = 0; ch < PER / RPC; ++ch) {
    __builtin_amdgcn_global_load_lds(
        (const __attribute__((address_space(1))) void*)(gp + ch * RPC * ld),
        (__attribute__((address_space(3))) void*)(sp + ch * RPC * DEPTH), 16, 0, 0);
  }
}

// ---- swizzled DEPTH=32 stage: 16B chunk c of row r lands at LDS slot c^((r>>1)&3)
// (conflict-free ds_read_b128: 8 consecutive lanes cover all 8 bank groups)
template<int ROWS>
__device__ __forceinline__ void stage_sw(const u16* __restrict__ g, int ld, u16* s, int wave, int lane) {
  constexpr int PER = ROWS / 4;    // 4 lanes/row
  int rin = lane >> 2, c = lane & 3;
#pragma unroll
  for (int ch = 0; ch < PER / 16; ++ch) {
    int rloc = wave * PER + ch * 16 + rin;
    const u16* gp = g + (size_t)rloc * ld + ((c ^ ((rloc >> 1) & 3)) << 3);
    u16* sp = s + (wave * PER + ch * 16) * 32;   // linear dest; lane at +16B*lane
    __builtin_amdgcn_global_load_lds(
        (const __attribute__((address_space(1))) void*)gp,
        (__attribute__((address_space(3))) void*)sp, 16, 0, 0);
  }
}

// ---- fp8 stage: ROWS x 64-byte rows with 16-B-chunk XOR swizzle (bank-conflict-free reads)
__device__ __forceinline__ int swz4(int r) { return (r & 3) ^ ((r >> 2) & 3); }
template<int ROWS>
__device__ __forceinline__ void stage8(const u8* __restrict__ g, int ld, u8* s, int wave, int lane) {
  constexpr int PER = ROWS / 4;    // rows per wave (4 lanes/row, 16 rows per 64-lane chunk)
  int rin = lane >> 2, c = lane & 3;
#pragma unroll
  for (int ch = 0; ch < PER / 16; ++ch) {
    int rloc = wave * PER + ch * 16 + rin;
    const u8* gp = g + (size_t)rloc * ld + ((c ^ swz4(rloc)) << 4);
    u8* sp = s + (wave * PER + ch * 16) * 64;   // wave-uniform; lane lands at +16B*lane
    __builtin_amdgcn_global_load_lds(
        (const __attribute__((address_space(1))) void*)gp,
        (__attribute__((address_space(3))) void*)sp, 16, 0, 0);
  }
}

// ---- wave computes (RT*16) x 64 outputs; block = 4 waves in 2x2 -> (RT*32) x 128 tile
template<int RT, int DEPTH = 64>
__device__ __forceinline__ void mfma_step(const u16* As, const u16* Bs, f32x4 (*acc)[4], int lane, int wave) {
  const int wr = (wave >> 1) * (RT * 16);
  const int wc = (wave & 1) * 64;
  const int l15 = lane & 15;
  const int lq = lane >> 4;
#pragma unroll
  for (int kk = 0; kk < DEPTH; kk += 32) {
    bf16x8 a[RT], b[4];
#pragma unroll
    for (int i = 0; i < RT; ++i)
      a[i] = *(const bf16x8*)(As + (wr + i * 16 + l15) * DEPTH + kk + lq * 8);
#pragma unroll
    for (int j = 0; j < 4; ++j)
      b[j] = *(const bf16x8*)(Bs + (wc + j * 16 + l15) * DEPTH + kk + lq * 8);
#pragma unroll
    for (int i = 0; i < RT; ++i)
#pragma unroll
      for (int j = 0; j < 4; ++j)
        acc[i][j] = __builtin_amdgcn_mfma_f32_16x16x32_bf16(a[i], b[j], acc[i][j], 0, 0, 0);
  }
}

// swizzled-read variant of mfma_step for DEPTH=32 (matches stage_sw layout)
__device__ __forceinline__ void mfma_step_sw(const u16* As, const u16* Bs, f32x4 (*acc)[4], int lane, int wave) {
  const int wr = (wave >> 1) * 32;
  const int wc = (wave & 1) * 64;
  const int l15 = lane & 15, lq = lane >> 4;
  bf16x8 a[2], b[4];
#pragma unroll
  for (int i = 0; i < 2; ++i) {
    int r = wr + i * 16 + l15;
    a[i] = *(const bf16x8*)(As + r * 32 + ((lq ^ ((r >> 1) & 3)) << 3));
  }
#pragma unroll
  for (int j = 0; j < 4; ++j) {
    int r = wc + j * 16 + l15;
    b[j] = *(const bf16x8*)(Bs + r * 32 + ((lq ^ ((r >> 1) & 3)) << 3));
  }
#pragma unroll
  for (int i = 0; i < 2; ++i)
#pragma unroll
    for (int j = 0; j < 4; ++j)
      acc[i][j] = __builtin_amdgcn_mfma_f32_16x16x32_bf16(a[i], b[j], acc[i][j], 0, 0, 0);
}

// fp8 MFMA step: 128x128 tile, 64 K-elems (64 B) per slice, swizzled LDS
__device__ __forceinline__ void mfma_step8(const u8* As, const u8* Bs, f32x4 (*acc)[4], int lane, int wave) {
  const int wr = (wave >> 1) * 64;
  const int wc = (wave & 1) * 64;
  const int l15 = lane & 15, lq = lane >> 4;
#pragma unroll
  for (int kk = 0; kk < 64; kk += 32) {
    long a[4], b[4];
    int gch = (kk >> 4) + (lq >> 1), half = (lq & 1) << 3;
#pragma unroll
    for (int i = 0; i < 4; ++i) {
      int r = wr + i * 16 + l15;
      a[i] = *(const long*)(As + r * 64 + ((gch ^ swz4(r)) << 4) + half);
    }
#pragma unroll
    for (int j = 0; j < 4; ++j) {
      int r = wc + j * 16 + l15;
      b[j] = *(const long*)(Bs + r * 64 + ((gch ^ swz4(r)) << 4) + half);
    }
#pragma unroll
    for (int i = 0; i < 4; ++i)
#pragma unroll
      for (int j = 0; j < 4; ++j)
        acc[i][j] = __builtin_amdgcn_mfma_f32_16x16x32_fp8_fp8(a[i], b[j], acc[i][j], 0, 0, 0);
  }
}

// double-buffered K-loop (full-drain variant, used by the dense bf16 GEMMs)
template<int RT>
__device__ __forceinline__ void gemm_loop_db(const u16* __restrict__ A, int lda,
                                             const u16* __restrict__ B, int ldb, int K,
                                             u16* As, u16* Bs, f32x4 (*acc)[4], int lane, int wave) {
  const int niter = K / 64;
  stage<RT * 32>(A, lda, As, wave, lane);
  stage<128>(B, ldb, Bs, wave, lane);
  for (int it = 0; it < niter; ++it) {
    __syncthreads();
    int nb = (it + 1) & 1;
    if (it + 1 < niter) {
      stage<RT * 32>(A + (it + 1) * 64, lda, As + nb * RT * 32 * 64, wave, lane);
      stage<128>(B + (it + 1) * 64, ldb, Bs + nb * 128 * 64, wave, lane);
    }
    int cb = it & 1;
    mfma_step<RT>(As + cb * RT * 32 * 64, Bs + cb * 128 * 64, acc, lane, wave);
  }
  __syncthreads();
}

// ---------------- elementwise / prep kernels ----------------

__global__ __launch_bounds__(256) void k_conv(const float* __restrict__ in, u16* __restrict__ out, int n4) {
  int i = blockIdx.x * 256 + threadIdx.x;
  if (i >= n4) return;
  float4 f = ((const float4*)in)[i];
  u16x4 o = { f2bf(f.x), f2bf(f.y), f2bf(f.z), f2bf(f.w) };
  *(u16x4*)(out + i * 4) = o;
}

__global__ __launch_bounds__(256) void k_convx(const float* __restrict__ x, u16* __restrict__ xb) {
  int i = blockIdx.x * 256 + threadIdx.x;
  if (i >= VV * NN * DD / 4) return;
  int idx = i * 4;
  int v = idx / (NN * DD);
  int rem = idx - v * (NN * DD);
  int n = rem / DD;
  int d = rem - n * DD;
  float4 f = *(const float4*)(x + idx);
  u16x4 o = { f2bf(f.x), f2bf(f.y), f2bf(f.z), f2bf(f.w) };
  *(u16x4*)(xb + (size_t)(v * NPAD + n) * DD + d) = o;
}

__global__ __launch_bounds__(256) void k_mt(const float* __restrict__ mask, float* __restrict__ mT) {
  int i = blockIdx.x * 256 + threadIdx.x;
  if (i >= VV * NPAD) return;
  int v = i / NPAD, n = i - v * NPAD;
  mT[i] = (n < NN) ? mask[n * VV + v] : 0.0f;
}

__global__ __launch_bounds__(256) void k_qprep(const float* __restrict__ h, u16* __restrict__ qb) {
  int b = blockIdx.x;
  int v = b / NN, n = b - v * NN;
  int t = threadIdx.x;
  float val = h[(size_t)(v * NPAD + n) * HH + t];
  float ss = val * val;
#pragma unroll
  for (int o = 32; o > 0; o >>= 1) ss += __shfl_down(ss, o, 64);
  __shared__ float red[4];
  if ((t & 63) == 0) red[t >> 6] = ss;
  __syncthreads();
  float inv = 1.0f / fmaxf(sqrtf(red[0] + red[1] + red[2] + red[3]), 1e-12f);
  qb[(size_t)(v * NPAD + n) * HH + t] = f2bf(val * inv);
}

// hmT[v][j][m] = mT[v][m]*h[v][m][j] (fp8 e4m3, zero for m>=NN)
__global__ __launch_bounds__(1024) void k_hmt(const float* __restrict__ h, const float* __restrict__ mT,
                                              u8* __restrict__ hmT) {
  __shared__ float t[64][65];
  int m0 = blockIdx.x * 64, j0 = blockIdx.y * 64, v = blockIdx.z;
  int tx = threadIdx.x, ty = threadIdx.y;
#pragma unroll
  for (int p = 0; p < 4; ++p) {
    int ml = ty + p * 16;
    int m = m0 + ml;
    float val = 0.0f;
    if (m < NN) val = mT[v * NPAD + m] * h[(size_t)(v * NPAD + m) * HH + j0 + tx];
    t[ml][tx] = val;
  }
  __syncthreads();
#pragma unroll
  for (int p = 0; p < 4; ++p) {
    int j = j0 + ty + p * 16;
    hmT[(size_t)(v * HH + j) * NPAD + m0 + tx] = f2fp8_hw(t[tx][ty + p * 16]);
  }
}

// ---------------- GEMM kernels ----------------

__global__ __launch_bounds__(256, 3) void k_gemm1(const u16* __restrict__ xb, const u16* __restrict__ winb,
                                                  const float* __restrict__ b_in, float* __restrict__ h) {
  __shared__ u16 As[2 * 64 * 64], Bs[2 * 128 * 64];
  int lane = threadIdx.x & 63, wave = threadIdx.x >> 6;
  int col0 = blockIdx.x * 128, row0 = blockIdx.y * 64, v = blockIdx.z;
  f32x4 acc[2][4];
  f32x4 z = {0.f, 0.f, 0.f, 0.f};
  for (int i = 0; i < 2; ++i) for (int j = 0; j < 4; ++j) acc[i][j] = z;
  gemm_loop_db<2>(xb + (size_t)(v * NPAD + row0) * DD, DD,
                  winb + (size_t)(v * HH + col0) * DD, DD, DD, As, Bs, acc, lane, wave);
  int wr = (wave >> 1) * 32, wc = (wave & 1) * 64, l15 = lane & 15, lq = lane >> 4;
#pragma unroll
  for (int i = 0; i < 2; ++i)
#pragma unroll
    for (int r = 0; r < 4; ++r) {
      int grow = row0 + wr + i * 16 + lq * 4 + r;
      if (grow < NN) {
#pragma unroll
        for (int j = 0; j < 4; ++j) {
          int gcol = col0 + wc + j * 16 + l15;
          h[(size_t)(v * NPAD + grow) * HH + gcol] = leaky(acc[i][j][r] + b_in[v * HH + gcol]);
        }
      }
    }
}

// A = max_v mask*exp(q_v q_v^T / beta), diag zeroed -> fp8 e4m3.
// 3-deep LDS ring + counted vmcnt (T4): stage(it+2) issued, wait vmcnt(6)
// (= 2 iters x 3 global_load_lds in flight), raw s_barrier — no full drain in
// the main loop. Chunk-XOR swizzle (stage_sw/mfma_step_sw) kills the 8-way
// ds_read_b128 bank conflict. Mask tests hoisted into 2 bitmask registers so
// no stray vmem ops enter the counted window.
__global__ __launch_bounds__(256, 4) void k_qk(const u16* __restrict__ qb, const float* __restrict__ mT,
                                               u8* __restrict__ Abf) {
  __shared__ u16 sh[3 * QK_BUF];   // 36864 B; reused for Dir/Tr in epilogue
  int lane = threadIdx.x & 63, wave = threadIdx.x >> 6;
  int bid = blockIdx.x;
  int x = (int)((sqrtf((float)(4 * bid + 1)) - 1.0f) * 0.5f);
  while ((x + 1) * (x + 2) <= bid) ++x;
  while (x * (x + 1) > bid) --x;
  int y = bid - x * (x + 1);
  int col0 = x * 128, row0 = y * 64;

  const int wr = (wave >> 1) * 32, wc = (wave & 1) * 64;
  const int l15 = lane & 15, lq = lane >> 4;

  // mask bitmasks: rbm bit v*8+i*4+r = (mT[v][grow]!=0); cbm bit v*4+j
  unsigned rbm = 0, cbm = 0;
#pragma unroll
  for (int v = 0; v < VV; ++v) {
#pragma unroll
    for (int t = 0; t < 8; ++t) {
      int grow = row0 + wr + (t >> 2) * 16 + lq * 4 + (t & 3);
      if (mT[v * NPAD + grow] != 0.0f) rbm |= 1u << (v * 8 + t);
    }
#pragma unroll
    for (int j = 0; j < 4; ++j)
      if (mT[v * NPAD + col0 + wc + j * 16 + l15] != 0.0f) cbm |= 1u << (v * 4 + j);
  }

  f32x4 z = {0.f, 0.f, 0.f, 0.f};
  float ninf = -__builtin_inff();
  f32x4 nv = {ninf, ninf, ninf, ninf};
  f32x4 acc[2][4];
  f32x4 emax[2][4];
  for (int i = 0; i < 2; ++i)
    for (int j = 0; j < 4; ++j) { acc[i][j] = z; emax[i][j] = nv; }

  auto stage_it = [&](int it, u16* buf) {
    int v = it >> 3, k0 = (it & 7) * QK_BK;
    const u16* base = qb + (size_t)v * NPAD * HH + k0;
    stage_sw<64>(base + (size_t)row0 * HH, HH, buf, wave, lane);
    stage_sw<128>(base + (size_t)col0 * HH, HH, buf + 64 * QK_BK, wave, lane);
  };

  const int NIT = VV * (HH / QK_BK);   // 24
  stage_it(0, sh);
  stage_it(1, sh + QK_BUF);
#pragma unroll
  for (int it = 0; it < NIT; ++it) {
    if (it + 2 < NIT) stage_it(it + 2, sh + ((it + 2) % 3) * QK_BUF);
    if (it < NIT - 2)       asm volatile("s_waitcnt vmcnt(6)" ::: "memory");
    else if (it == NIT - 2) asm volatile("s_waitcnt vmcnt(3)" ::: "memory");
    else                    asm volatile("s_waitcnt vmcnt(0)" ::: "memory");
    __builtin_amdgcn_sched_barrier(0);
    __builtin_amdgcn_s_barrier();
    __builtin_amdgcn_sched_barrier(0);
    const u16* cur = sh + (it % 3) * QK_BUF;
    mfma_step_sw(cur, cur + 64 * QK_BK, acc, lane, wave);
    if ((it & 7) == 7) {               // v complete: fold masked scores into emax
      int v = it >> 3;
#pragma unroll
      for (int i = 0; i < 2; ++i)
#pragma unroll
        for (int r = 0; r < 4; ++r) {
          bool rb = (rbm >> (v * 8 + i * 4 + r)) & 1;
#pragma unroll
          for (int j = 0; j < 4; ++j) {
            bool on = rb && ((cbm >> (v * 4 + j)) & 1);
            if (on) emax[i][j][r] = fmaxf(emax[i][j][r], acc[i][j][r]);
            acc[i][j][r] = 0.0f;
          }
        }
    }
    asm volatile("s_waitcnt lgkmcnt(0)" ::: "memory");
    __builtin_amdgcn_sched_barrier(0);
    __builtin_amdgcn_s_barrier();
    __builtin_amdgcn_sched_barrier(0);
  }
  __syncthreads();

  // epilogue: Dir [64][144] u8 (direct tile), Tr [128][80] u8 (mirror) in sh
  u8* Dir = (u8*)sh;
  u8* Tr  = (u8*)sh + 64 * 144;
#pragma unroll
  for (int i = 0; i < 2; ++i)
#pragma unroll
    for (int r = 0; r < 4; ++r) {
      int lrow = wr + i * 16 + lq * 4 + r;
      int grow = row0 + lrow;
#pragma unroll
      for (int j = 0; j < 4; ++j) {
        int lcol = wc + j * 16 + l15;
        int gcol = col0 + lcol;
        float val = __expf(emax[i][j][r] * 5.0f);
        if (grow == gcol) val = 0.0f;
        u8 q = f2fp8_hw(val);
        Dir[lrow * 144 + lcol] = q;
        Tr[lcol * 80 + lrow] = (gcol > grow) ? q : (u8)0;
      }
    }
  __syncthreads();
  if (col0 >= row0 + 64) {   // fully-upper tile: 16-B vector stores
    int c8 = threadIdx.x & 7, rr = threadIdx.x >> 3;
#pragma unroll
    for (int p = 0; p < 2; ++p) {
      int row = rr + p * 32;
      u32x4 ch = *(const u32x4*)(Dir + row * 144 + c8 * 16);
      *(u32x4*)(Abf + (size_t)(row0 + row) * NPAD + col0 + c8 * 16) = ch;
    }
    int c = threadIdx.x & 3; rr = threadIdx.x >> 2;
#pragma unroll
    for (int p = 0; p < 2; ++p) {
      int cc = rr + p * 64;
      u32x4 ch = *(const u32x4*)(Tr + cc * 80 + c * 16);
      *(u32x4*)(Abf + (size_t)(col0 + cc) * NPAD + row0 + c * 16) = ch;
    }
  } else {                    // straddle tile: predicated scalar
    for (int idx = threadIdx.x; idx < 64 * 128; idx += 256) {
      int row = idx >> 7, cc = idx & 127;
      int R = row0 + row, C = col0 + cc;
      u8 val = Dir[row * 144 + cc];
      if (C >= R) Abf[(size_t)R * NPAD + C] = val;
      if (C > R)  Abf[(size_t)C * NPAD + R] = val;
    }
  }
}

// S[n] = sum_m dequant(Abf[n][m]) — Abf holds both triangles, zero diag/pad.
__global__ __launch_bounds__(256) void k_rowsum(const u8* __restrict__ Abf, float* __restrict__ S) {
  int row = blockIdx.x;
  const u8* rp = Abf + (size_t)row * NPAD;
  float s = 0.0f;
  for (int c = threadIdx.x * 16; c < NPAD; c += 256 * 16) {
    u32x4 ch = *(const u32x4*)(rp + c);
#pragma unroll
    for (int w = 0; w < 4; ++w) {
      unsigned int u = ch[w];
#pragma unroll
      for (int b = 0; b < 4; ++b) s += fp82f((u8)(u >> (8 * b)));
    }
  }
#pragma unroll
  for (int o = 32; o > 0; o >>= 1) s += __shfl_down(s, o, 64);
  __shared__ float red[4];
  if ((threadIdx.x & 63) == 0) red[threadIdx.x >> 6] = s;
  __syncthreads();
  if (threadIdx.x == 0) S[row] = red[0] + red[1] + red[2] + red[3];
}

// partial[z] = Abf[:, zK:(z+1)K] @ hmT_all[:, zK:(z+1)K]^T  (fp8 operands, f32 acc,
// bf16 partials). XCD-swizzled flat grid. Counted-vmcnt dbuf: stage(it+1) stays
// in flight (vmcnt(4)) across raw barriers — stage latency hides under MFMA.
__global__ __launch_bounds__(256, 4) void k_pvsk(const u8* __restrict__ Abf, const u8* __restrict__ hmT,
                                                 u16* __restrict__ part) {
  __shared__ u8 sh8[2 * 2 * 128 * 64];   // [buf][A/B][128][64] = 32 KB
  int lane = threadIdx.x & 63, wave = threadIdx.x >> 6;
  int bid = blockIdx.x;                  // 576 (12 dummy)
  int xcd = bid & 7, s = bid >> 3;
  int row = (s / 12) * 8 + xcd;
  if (row >= 47) return;
  int k = s % 12;
  int col0 = (k % 6) * 128, row0 = row * 128, kb = (k / 6) * (NPAD / 2);

  f32x4 acc[4][4];
  f32x4 z = {0.f, 0.f, 0.f, 0.f};
  for (int i = 0; i < 4; ++i) for (int j = 0; j < 4; ++j) acc[i][j] = z;

  const u8* Ap = Abf + (size_t)row0 * NPAD + kb;
  const u8* Bp = hmT + (size_t)col0 * NPAD + kb;
  auto pv_stage = [&](int it, int buf) {
    u8* base = sh8 + buf * 16384;
    stage8<128>(Ap + it * 64, NPAD, base, wave, lane);
    stage8<128>(Bp + it * 64, NPAD, base + 8192, wave, lane);
  };
  const int niter = (NPAD / 2) / 64;   // 47
  pv_stage(0, 0);
  for (int it = 0; it < niter; ++it) {
    if (it + 1 < niter) {
      pv_stage(it + 1, (it + 1) & 1);
      asm volatile("s_waitcnt vmcnt(4)" ::: "memory");
    } else {
      asm volatile("s_waitcnt vmcnt(0)" ::: "memory");
    }
    __builtin_amdgcn_sched_barrier(0);
    __builtin_amdgcn_s_barrier();
    __builtin_amdgcn_sched_barrier(0);
    u8* cur = sh8 + (it & 1) * 16384;
    mfma_step8(cur, cur + 8192, acc, lane, wave);
    asm volatile("s_waitcnt lgkmcnt(0)" ::: "memory");
    __builtin_amdgcn_sched_barrier(0);
    __builtin_amdgcn_s_barrier();
    __builtin_amdgcn_sched_barrier(0);
  }

  u16* pp = part + (size_t)(k / 6) * NPAD * (VV * HH);
  int wr = (wave >> 1) * 64, wc = (wave & 1) * 64, l15 = lane & 15, lq = lane >> 4;
#pragma unroll
  for (int i = 0; i < 4; ++i)
#pragma unroll
    for (int r = 0; r < 4; ++r) {
      int grow = row0 + wr + i * 16 + lq * 4 + r;
#pragma unroll
      for (int j = 0; j < 4; ++j) {
        int gcol = col0 + wc + j * 16 + l15;
        pp[(size_t)grow * (VV * HH) + gcol] = f2bf(acc[i][j][r]);
      }
    }
}

// newx = blend((p0+p1)/S, h); writes out_newx (f32) and nxb (bf16)
__global__ __launch_bounds__(256) void k_pvred(const u16* __restrict__ part, const float* __restrict__ S,
                                               const float* __restrict__ mT, const float* __restrict__ h,
                                               float* __restrict__ out_newx, u16* __restrict__ nxb) {
  int i = (blockIdx.x * 256 + threadIdx.x) * 4;
  int v = i / (NN * HH);
  int rem = i - v * (NN * HH);
  int n = rem / HH;
  int j = rem - n * HH;
  int col = v * HH + j;
  u16x4 p0 = *(const u16x4*)(part + (size_t)n * (VV * HH) + col);
  u16x4 p1 = *(const u16x4*)(part + (size_t)NPAD * (VV * HH) + (size_t)n * (VV * HH) + col);
  float sc = 1.0f / (S[n] + 1e-9f);
  float mrow = mT[v * NPAD + n];
  float4 o;
  o.x = (bf2f(p0[0]) + bf2f(p1[0])) * sc;
  o.y = (bf2f(p0[1]) + bf2f(p1[1])) * sc;
  o.z = (bf2f(p0[2]) + bf2f(p1[2])) * sc;
  o.w = (bf2f(p0[3]) + bf2f(p1[3])) * sc;
  if (mrow != 0.0f) o = *(const float4*)(h + (size_t)(v * NPAD + n) * HH + j);
  *(float4*)(out_newx + (size_t)(v * NN + n) * HH + j) = o;
  u16x4 ob = { f2bf(o.x), f2bf(o.y), f2bf(o.z), f2bf(o.w) };
  *(u16x4*)(nxb + (size_t)(v * NPAD + n) * HH + j) = ob;
}

// x_new = leaky(new_x @ W_out^T + b_out), nan->0  [RT=2, double-buffered]
__global__ __launch_bounds__(256, 3) void k_gemm3(const u16* __restrict__ nxb, const u16* __restrict__ woutb,
                                                  const float* __restrict__ b_out, float* __restrict__ out_xnew) {
  __shared__ u16 As[2 * 64 * 64], Bs[2 * 128 * 64];
  int lane = threadIdx.x & 63, wave = threadIdx.x >> 6;
  int col0 = blockIdx.x * 128, row0 = blockIdx.y * 64, v = blockIdx.z;
  f32x4 acc[2][4];
  f32x4 z = {0.f, 0.f, 0.f, 0.f};
  for (int i = 0; i < 2; ++i) for (int j = 0; j < 4; ++j) acc[i][j] = z;
  gemm_loop_db<2>(nxb + (size_t)(v * NPAD + row0) * HH, HH,
                  woutb + (size_t)(v * DD + col0) * HH, HH, HH, As, Bs, acc, lane, wave);
  int wr = (wave >> 1) * 32, wc = (wave & 1) * 64, l15 = lane & 15, lq = lane >> 4;
#pragma unroll
  for (int i = 0; i < 2; ++i)
#pragma unroll
    for (int r = 0; r < 4; ++r) {
      int grow = row0 + wr + i * 16 + lq * 4 + r;
      if (grow < NN) {
#pragma unroll
        for (int j = 0; j < 4; ++j) {
          int gcol = col0 + wc + j * 16 + l15;
          float val = leaky(acc[i][j][r] + b_out[v * DD + gcol]);
          if (val != val) val = 0.0f;
          out_xnew[(size_t)(v * NN + grow) * DD + gcol] = val;
        }
      }
    }
}

// y_n = sigmoid(y @ Wy^T + by)  [RT=2, double-buffered]
__global__ __launch_bounds__(256, 3) void k_ygemm(const u16* __restrict__ yb, const u16* __restrict__ wyb,
                                                  const float* __restrict__ by, float* __restrict__ out_yn) {
  __shared__ u16 As[2 * 64 * 64], Bs[2 * 128 * 64];
  int lane = threadIdx.x & 63, wave = threadIdx.x >> 6;
  int col0 = blockIdx.x * 128, row0 = blockIdx.y * 64;
  f32x4 acc[2][4];
  f32x4 z = {0.f, 0.f, 0.f, 0.f};
  for (int i = 0; i < 2; ++i) for (int j = 0; j < 4; ++j) acc[i][j] = z;
  gemm_loop_db<2>(yb + (size_t)row0 * DYY, DYY, wyb + (size_t)col0 * DYY, DYY, DYY, As, Bs, acc, lane, wave);
  int wr = (wave >> 1) * 32, wc = (wave & 1) * 64, l15 = lane & 15, lq = lane >> 4;
#pragma unroll
  for (int i = 0; i < 2; ++i)
#pragma unroll
    for (int r = 0; r < 4; ++r) {
      int grow = row0 + wr + i * 16 + lq * 4 + r;
      if (grow < NN) {
#pragma unroll
        for (int j = 0; j < 4; ++j) {
          int gcol = col0 + wc + j * 16 + l15;
          float val = acc[i][j][r] + by[gcol];
          out_yn[(size_t)grow * HH + gcol] = 1.0f / (1.0f + __expf(-val));
        }
      }
    }
}

// ---------------- launch ----------------

extern "C" void kernel_launch(void* const* d_in, const int* in_sizes, int n_in,
                              void* d_out, int out_size, void* d_ws, size_t ws_size,
                              hipStream_t stream) {
  const float* x    = (const float*)d_in[0];
  const float* y    = (const float*)d_in[1];
  const float* mask = (const float*)d_in[2];
  const float* W_in = (const float*)d_in[3];
  const float* b_in = (const float*)d_in[4];
  const float* W_out= (const float*)d_in[5];
  const float* b_out= (const float*)d_in[6];
  const float* Wy   = (const float*)d_in[7];
  const float* by   = (const float*)d_in[8];

  float* out_newx = (float*)d_out;
  float* out_xnew = out_newx + (size_t)VV * NN * HH;
  float* out_yn   = out_xnew + (size_t)VV * NN * DD;

  char* w = (char*)d_ws;
  size_t off = 0;
  auto alloc = [&](size_t bytes) -> void* {
    void* p = w + off;
    off += (bytes + 255) & ~(size_t)255;
    return p;
  };
  u16*   xb    = (u16*)alloc((size_t)VV * NPAD * DD * 2);
  u16*   yb    = (u16*)alloc((size_t)NPAD * DYY * 2);
  u16*   winb  = (u16*)alloc((size_t)VV * HH * DD * 2);
  u16*   woutb = (u16*)alloc((size_t)VV * DD * HH * 2);
  u16*   wyb   = (u16*)alloc((size_t)HH * DYY * 2);
  float* h     = (float*)alloc((size_t)VV * NPAD * HH * 4);
  u16*   qb    = (u16*)alloc((size_t)VV * NPAD * HH * 2);
  u8*    hmT   = (u8*)alloc((size_t)VV * HH * NPAD);
  u16*   nxb   = (u16*)alloc((size_t)VV * NPAD * HH * 2);
  float* mT    = (float*)alloc((size_t)VV * NPAD * 4);
  float* S     = (float*)alloc((size_t)NPAD * 4);
  u8*    Abf   = (u8*)alloc((size_t)NPAD * NPAD);
  // split-K partials (2 x NPAD x 768 bf16 = 18.48 MB) reuse xb, dead after k_gemm1
  u16*   pvp   = xb;
  (void)ws_size; (void)in_sizes; (void)n_in; (void)out_size;

  // conversions
  k_conv<<<384, 256, 0, stream>>>(W_in, winb, VV * HH * DD / 4);
  k_conv<<<384, 256, 0, stream>>>(W_out, woutb, VV * DD * HH / 4);
  k_conv<<<128, 256, 0, stream>>>(Wy, wyb, HH * DYY / 4);
  k_conv<<<3000, 256, 0, stream>>>(y, yb, NN * DYY / 4);
  k_convx<<<9000, 256, 0, stream>>>(x, xb);
  k_mt<<<(VV * NPAD + 255) / 256, 256, 0, stream>>>(mask, mT);

  // h, q, hmT
  k_gemm1<<<dim3(2, 94, 3), 256, 0, stream>>>(xb, winb, b_in, h);
  k_qprep<<<VV * NN, 256, 0, stream>>>(h, qb);
  k_hmt<<<dim3(94, 4, 3), dim3(64, 16), 0, stream>>>(h, mT, hmT);

  // attention
  k_qk<<<2256, 256, 0, stream>>>(qb, mT, Abf);
  k_rowsum<<<NN, 256, 0, stream>>>(Abf, S);
  k_pvsk<<<576, 256, 0, stream>>>(Abf, hmT, pvp);
  k_pvred<<<4500, 256, 0, stream>>>(pvp, S, mT, h, out_newx, nxb);

  // outputs
  k_gemm3<<<dim3(4, 94, 3), 256, 0, stream>>>(nxb, woutb, b_out, out_xnew);
  k_ygemm<<<dim3(2, 94), 256, 0, stream>>>(yb, wyb, by, out_yn);
}

// Round 3
// 314.195 us; speedup vs baseline: 1.1286x; 1.0276x over previous
//
#include <hip/hip_runtime.h>

#define VV 3
#define NN 6000
#define DD 512
#define HH 256
#define DYY 512
#define NPAD 6016   // 47*128
#define QK_BK 32
#define QK_ROWS 192              // 64 A-rows + 128 B-rows for ONE v-slice
#define QK_BUF (QK_ROWS * QK_BK) // u16 elems per staging buffer (12288 B)

typedef unsigned short u16;
typedef unsigned char u8;
typedef __bf16 bf16x8 __attribute__((ext_vector_type(8)));
typedef u16 u16x8 __attribute__((ext_vector_type(8)));
typedef float f32x4 __attribute__((ext_vector_type(4)));
typedef float f32x2 __attribute__((ext_vector_type(2)));
typedef u16 u16x4 __attribute__((ext_vector_type(4)));
typedef unsigned int u32x4 __attribute__((ext_vector_type(4)));

__device__ __forceinline__ u16 f2bf(float f) {
  unsigned int b = __builtin_bit_cast(unsigned int, f);
  b += 0x7FFFu + ((b >> 16) & 1u);
  return (u16)(b >> 16);
}
__device__ __forceinline__ float bf2f(u16 u) {
  unsigned int b = ((unsigned int)u) << 16;
  return __builtin_bit_cast(float, b);
}
// hardware OCP e4m3fn convert (RNE, saturating) — 1 inst vs ~20 for manual
__device__ __forceinline__ u8 f2fp8_hw(float f) {
  unsigned int r;
  asm("v_cvt_pk_fp8_f32 %0, %1, %2" : "=v"(r) : "v"(f), "v"(f));
  return (u8)(r & 0xffu);
}
__device__ __forceinline__ float fp82f(u8 b) {
  int e = (b >> 3) & 15, m = b & 7;
  float v = e ? __builtin_bit_cast(float, (unsigned)((e + 120) << 23 | (m << 20)))
              : (float)m * 0.001953125f;
  return (b & 0x80) ? -v : v;
}
__device__ __forceinline__ float leaky(float v) { return v >= 0.0f ? v : 0.1f * v; }

// ---- stage ROWS x DEPTH bf16 tile: global row-major (ld elems) -> LDS [ROWS][DEPTH]
template<int ROWS, int DEPTH = 64>
__device__ __forceinline__ void stage(const u16* __restrict__ g, int ld, u16* s, int wave, int lane) {
  constexpr int LPR = DEPTH / 8;   // lanes per row (16B each)
  constexpr int RPC = 64 / LPR;    // rows per chunk
  constexpr int PER = ROWS / 4;    // rows per wave
  const u16* gp = g + (wave * PER + lane / LPR) * ld + (lane % LPR) * 8;
  u16* sp = s + wave * PER * DEPTH;
#pragma unroll
  for (int ch = 0; ch < PER / RPC; ++ch) {
    __builtin_amdgcn_global_load_lds(
        (const __attribute__((address_space(1))) void*)(gp + ch * RPC * ld),
        (__attribute__((address_space(3))) void*)(sp + ch * RPC * DEPTH), 16, 0, 0);
  }
}

// ---- swizzled DEPTH=32 stage: 16B chunk c of row r lands at LDS slot c^((r>>1)&3)
// (conflict-free ds_read_b128: 8 consecutive lanes cover all 8 bank groups)
template<int ROWS>
__device__ __forceinline__ void stage_sw(const u16* __restrict__ g, int ld, u16* s, int wave, int lane) {
  constexpr int PER = ROWS / 4;    // 4 lanes/row
  int rin = lane >> 2, c = lane & 3;
#pragma unroll
  for (int ch = 0; ch < PER / 16; ++ch) {
    int rloc = wave * PER + ch * 16 + rin;
    const u16* gp = g + (size_t)rloc * ld + ((c ^ ((rloc >> 1) & 3)) << 3);
    u16* sp = s + (wave * PER + ch * 16) * 32;   // linear dest; lane at +16B*lane
    __builtin_amdgcn_global_load_lds(
        (const __attribute__((address_space(1))) void*)gp,
        (__attribute__((address_space(3))) void*)sp, 16, 0, 0);
  }
}

// ---- fp8 stage: ROWS x 64-byte rows with 16-B-chunk XOR swizzle (bank-conflict-free reads)
__device__ __forceinline__ int swz4(int r) { return (r & 3) ^ ((r >> 2) & 3); }
template<int ROWS>
__device__ __forceinline__ void stage8(const u8* __restrict__ g, int ld, u8* s, int wave, int lane) {
  constexpr int PER = ROWS / 4;    // rows per wave (4 lanes/row, 16 rows per 64-lane chunk)
  int rin = lane >> 2, c = lane & 3;
#pragma unroll
  for (int ch = 0; ch < PER / 16; ++ch) {
    int rloc = wave * PER + ch * 16 + rin;
    const u8* gp = g + (size_t)rloc * ld + ((c ^ swz4(rloc)) << 4);
    u8* sp = s + (wave * PER + ch * 16) * 64;   // wave-uniform; lane lands at +16B*lane
    __builtin_amdgcn_global_load_lds(
        (const __attribute__((address_space(1))) void*)gp,
        (__attribute__((address_space(3))) void*)sp, 16, 0, 0);
  }
}

// ---- wave computes (RT*16) x 64 outputs; block = 4 waves in 2x2 -> (RT*32) x 128 tile
template<int RT, int DEPTH = 64>
__device__ __forceinline__ void mfma_step(const u16* As, const u16* Bs, f32x4 (*acc)[4], int lane, int wave) {
  const int wr = (wave >> 1) * (RT * 16);
  const int wc = (wave & 1) * 64;
  const int l15 = lane & 15;
  const int lq = lane >> 4;
#pragma unroll
  for (int kk = 0; kk < DEPTH; kk += 32) {
    bf16x8 a[RT], b[4];
#pragma unroll
    for (int i = 0; i < RT; ++i)
      a[i] = *(const bf16x8*)(As + (wr + i * 16 + l15) * DEPTH + kk + lq * 8);
#pragma unroll
    for (int j = 0; j < 4; ++j)
      b[j] = *(const bf16x8*)(Bs + (wc + j * 16 + l15) * DEPTH + kk + lq * 8);
#pragma unroll
    for (int i = 0; i < RT; ++i)
#pragma unroll
      for (int j = 0; j < 4; ++j)
        acc[i][j] = __builtin_amdgcn_mfma_f32_16x16x32_bf16(a[i], b[j], acc[i][j], 0, 0, 0);
  }
}

// swizzled-read variant of mfma_step for DEPTH=32 (matches stage_sw layout)
__device__ __forceinline__ void mfma_step_sw(const u16* As, const u16* Bs, f32x4 (*acc)[4], int lane, int wave) {
  const int wr = (wave >> 1) * 32;
  const int wc = (wave & 1) * 64;
  const int l15 = lane & 15, lq = lane >> 4;
  bf16x8 a[2], b[4];
#pragma unroll
  for (int i = 0; i < 2; ++i) {
    int r = wr + i * 16 + l15;
    a[i] = *(const bf16x8*)(As + r * 32 + ((lq ^ ((r >> 1) & 3)) << 3));
  }
#pragma unroll
  for (int j = 0; j < 4; ++j) {
    int r = wc + j * 16 + l15;
    b[j] = *(const bf16x8*)(Bs + r * 32 + ((lq ^ ((r >> 1) & 3)) << 3));
  }
#pragma unroll
  for (int i = 0; i < 2; ++i)
#pragma unroll
    for (int j = 0; j < 4; ++j)
      acc[i][j] = __builtin_amdgcn_mfma_f32_16x16x32_bf16(a[i], b[j], acc[i][j], 0, 0, 0);
}

// fp8 MFMA step: 128x128 tile, 64 K-elems (64 B) per slice, swizzled LDS
__device__ __forceinline__ void mfma_step8(const u8* As, const u8* Bs, f32x4 (*acc)[4], int lane, int wave) {
  const int wr = (wave >> 1) * 64;
  const int wc = (wave & 1) * 64;
  const int l15 = lane & 15, lq = lane >> 4;
#pragma unroll
  for (int kk = 0; kk < 64; kk += 32) {
    long a[4], b[4];
    int gch = (kk >> 4) + (lq >> 1), half = (lq & 1) << 3;
#pragma unroll
    for (int i = 0; i < 4; ++i) {
      int r = wr + i * 16 + l15;
      a[i] = *(const long*)(As + r * 64 + ((gch ^ swz4(r)) << 4) + half);
    }
#pragma unroll
    for (int j = 0; j < 4; ++j) {
      int r = wc + j * 16 + l15;
      b[j] = *(const long*)(Bs + r * 64 + ((gch ^ swz4(r)) << 4) + half);
    }
#pragma unroll
    for (int i = 0; i < 4; ++i)
#pragma unroll
      for (int j = 0; j < 4; ++j)
        acc[i][j] = __builtin_amdgcn_mfma_f32_16x16x32_fp8_fp8(a[i], b[j], acc[i][j], 0, 0, 0);
  }
}

// double-buffered K-loop (full-drain variant, used by the dense bf16 GEMMs)
template<int RT>
__device__ __forceinline__ void gemm_loop_db(const u16* __restrict__ A, int lda,
                                             const u16* __restrict__ B, int ldb, int K,
                                             u16* As, u16* Bs, f32x4 (*acc)[4], int lane, int wave) {
  const int niter = K / 64;
  stage<RT * 32>(A, lda, As, wave, lane);
  stage<128>(B, ldb, Bs, wave, lane);
  for (int it = 0; it < niter; ++it) {
    __syncthreads();
    int nb = (it + 1) & 1;
    if (it + 1 < niter) {
      stage<RT * 32>(A + (it + 1) * 64, lda, As + nb * RT * 32 * 64, wave, lane);
      stage<128>(B + (it + 1) * 64, ldb, Bs + nb * 128 * 64, wave, lane);
    }
    int cb = it & 1;
    mfma_step<RT>(As + cb * RT * 32 * 64, Bs + cb * 128 * 64, acc, lane, wave);
  }
  __syncthreads();
}

// ---------------- elementwise / prep kernels ----------------

__global__ __launch_bounds__(256) void k_conv(const float* __restrict__ in, u16* __restrict__ out, int n4) {
  int i = blockIdx.x * 256 + threadIdx.x;
  if (i >= n4) return;
  float4 f = ((const float4*)in)[i];
  u16x4 o = { f2bf(f.x), f2bf(f.y), f2bf(f.z), f2bf(f.w) };
  *(u16x4*)(out + i * 4) = o;
}

__global__ __launch_bounds__(256) void k_convx(const float* __restrict__ x, u16* __restrict__ xb) {
  int i = blockIdx.x * 256 + threadIdx.x;
  if (i >= VV * NN * DD / 4) return;
  int idx = i * 4;
  int v = idx / (NN * DD);
  int rem = idx - v * (NN * DD);
  int n = rem / DD;
  int d = rem - n * DD;
  float4 f = *(const float4*)(x + idx);
  u16x4 o = { f2bf(f.x), f2bf(f.y), f2bf(f.z), f2bf(f.w) };
  *(u16x4*)(xb + (size_t)(v * NPAD + n) * DD + d) = o;
}

__global__ __launch_bounds__(256) void k_mt(const float* __restrict__ mask, float* __restrict__ mT) {
  int i = blockIdx.x * 256 + threadIdx.x;
  if (i >= VV * NPAD) return;
  int v = i / NPAD, n = i - v * NPAD;
  mT[i] = (n < NN) ? mask[n * VV + v] : 0.0f;
}

__global__ __launch_bounds__(256) void k_qprep(const float* __restrict__ h, u16* __restrict__ qb) {
  int b = blockIdx.x;
  int v = b / NN, n = b - v * NN;
  int t = threadIdx.x;
  float val = h[(size_t)(v * NPAD + n) * HH + t];
  float ss = val * val;
#pragma unroll
  for (int o = 32; o > 0; o >>= 1) ss += __shfl_down(ss, o, 64);
  __shared__ float red[4];
  if ((t & 63) == 0) red[t >> 6] = ss;
  __syncthreads();
  float inv = 1.0f / fmaxf(sqrtf(red[0] + red[1] + red[2] + red[3]), 1e-12f);
  qb[(size_t)(v * NPAD + n) * HH + t] = f2bf(val * inv);
}

// hmT[v][j][m] = mT[v][m]*h[v][m][j] (fp8 e4m3, zero for m>=NN)
__global__ __launch_bounds__(1024) void k_hmt(const float* __restrict__ h, const float* __restrict__ mT,
                                              u8* __restrict__ hmT) {
  __shared__ float t[64][65];
  int m0 = blockIdx.x * 64, j0 = blockIdx.y * 64, v = blockIdx.z;
  int tx = threadIdx.x, ty = threadIdx.y;
#pragma unroll
  for (int p = 0; p < 4; ++p) {
    int ml = ty + p * 16;
    int m = m0 + ml;
    float val = 0.0f;
    if (m < NN) val = mT[v * NPAD + m] * h[(size_t)(v * NPAD + m) * HH + j0 + tx];
    t[ml][tx] = val;
  }
  __syncthreads();
#pragma unroll
  for (int p = 0; p < 4; ++p) {
    int j = j0 + ty + p * 16;
    hmT[(size_t)(v * HH + j) * NPAD + m0 + tx] = f2fp8_hw(t[tx][ty + p * 16]);
  }
}

// ---------------- GEMM kernels ----------------

__global__ __launch_bounds__(256, 3) void k_gemm1(const u16* __restrict__ xb, const u16* __restrict__ winb,
                                                  const float* __restrict__ b_in, float* __restrict__ h) {
  __shared__ u16 As[2 * 64 * 64], Bs[2 * 128 * 64];
  int lane = threadIdx.x & 63, wave = threadIdx.x >> 6;
  int col0 = blockIdx.x * 128, row0 = blockIdx.y * 64, v = blockIdx.z;
  f32x4 acc[2][4];
  f32x4 z = {0.f, 0.f, 0.f, 0.f};
  for (int i = 0; i < 2; ++i) for (int j = 0; j < 4; ++j) acc[i][j] = z;
  gemm_loop_db<2>(xb + (size_t)(v * NPAD + row0) * DD, DD,
                  winb + (size_t)(v * HH + col0) * DD, DD, DD, As, Bs, acc, lane, wave);
  int wr = (wave >> 1) * 32, wc = (wave & 1) * 64, l15 = lane & 15, lq = lane >> 4;
#pragma unroll
  for (int i = 0; i < 2; ++i)
#pragma unroll
    for (int r = 0; r < 4; ++r) {
      int grow = row0 + wr + i * 16 + lq * 4 + r;
      if (grow < NN) {
#pragma unroll
        for (int j = 0; j < 4; ++j) {
          int gcol = col0 + wc + j * 16 + l15;
          h[(size_t)(v * NPAD + grow) * HH + gcol] = leaky(acc[i][j][r] + b_in[v * HH + gcol]);
        }
      }
    }
}

// A = max_v mask*exp(q_v q_v^T / beta), diag zeroed -> fp8 e4m3.
// SINGLE barrier per K-iteration: wait vmcnt(3) [stage(it) done, stage(it+1)
// in flight] -> s_barrier -> issue stage(it+2) -> MFMA. The old 2nd barrier +
// lgkmcnt(0) drain is unnecessary: all waves past barrier(it) have consumed
// their iter-(it-1) ds_reads (MFMA issue forces the lgkm wait), so
// buf[(it+2)%3] == buf[(it-1)%3] is free to overwrite.
__global__ __launch_bounds__(256, 4) void k_qk(const u16* __restrict__ qb, const float* __restrict__ mT,
                                               u8* __restrict__ Abf) {
  __shared__ u16 sh[3 * QK_BUF];   // 36864 B; reused for Dir/Tr in epilogue
  int lane = threadIdx.x & 63, wave = threadIdx.x >> 6;
  int bid = blockIdx.x;
  int x = (int)((sqrtf((float)(4 * bid + 1)) - 1.0f) * 0.5f);
  while ((x + 1) * (x + 2) <= bid) ++x;
  while (x * (x + 1) > bid) --x;
  int y = bid - x * (x + 1);
  int col0 = x * 128, row0 = y * 64;

  const int wr = (wave >> 1) * 32, wc = (wave & 1) * 64;
  const int l15 = lane & 15, lq = lane >> 4;

  // mask bitmasks: rbm bit v*8+i*4+r = (mT[v][grow]!=0); cbm bit v*4+j
  unsigned rbm = 0, cbm = 0;
#pragma unroll
  for (int v = 0; v < VV; ++v) {
#pragma unroll
    for (int t = 0; t < 8; ++t) {
      int grow = row0 + wr + (t >> 2) * 16 + lq * 4 + (t & 3);
      if (mT[v * NPAD + grow] != 0.0f) rbm |= 1u << (v * 8 + t);
    }
#pragma unroll
    for (int j = 0; j < 4; ++j)
      if (mT[v * NPAD + col0 + wc + j * 16 + l15] != 0.0f) cbm |= 1u << (v * 4 + j);
  }
  // pin mask-load consumption here so no compiler vmcnt waits land in the loop
  asm volatile("" : "+v"(rbm), "+v"(cbm));

  f32x4 z = {0.f, 0.f, 0.f, 0.f};
  float ninf = -__builtin_inff();
  f32x4 nv = {ninf, ninf, ninf, ninf};
  f32x4 acc[2][4];
  f32x4 emax[2][4];
  for (int i = 0; i < 2; ++i)
    for (int j = 0; j < 4; ++j) { acc[i][j] = z; emax[i][j] = nv; }

  auto stage_it = [&](int it, u16* buf) {
    int v = it >> 3, k0 = (it & 7) * QK_BK;
    const u16* base = qb + (size_t)v * NPAD * HH + k0;
    stage_sw<64>(base + (size_t)row0 * HH, HH, buf, wave, lane);
    stage_sw<128>(base + (size_t)col0 * HH, HH, buf + 64 * QK_BK, wave, lane);
  };

  const int NIT = VV * (HH / QK_BK);   // 24
  stage_it(0, sh);
  stage_it(1, sh + QK_BUF);
#pragma unroll
  for (int it = 0; it < NIT; ++it) {
    if (it == NIT - 1) asm volatile("s_waitcnt vmcnt(0)" ::: "memory");
    else               asm volatile("s_waitcnt vmcnt(3)" ::: "memory");
    __builtin_amdgcn_sched_barrier(0);
    __builtin_amdgcn_s_barrier();
    __builtin_amdgcn_sched_barrier(0);
    if (it + 2 < NIT) stage_it(it + 2, sh + ((it + 2) % 3) * QK_BUF);
    const u16* cur = sh + (it % 3) * QK_BUF;
    __builtin_amdgcn_s_setprio(1);
    mfma_step_sw(cur, cur + 64 * QK_BK, acc, lane, wave);
    __builtin_amdgcn_s_setprio(0);
    if ((it & 7) == 7) {               // v complete: fold masked scores into emax
      int v = it >> 3;
#pragma unroll
      for (int i = 0; i < 2; ++i)
#pragma unroll
        for (int r = 0; r < 4; ++r) {
          bool rb = (rbm >> (v * 8 + i * 4 + r)) & 1;
#pragma unroll
          for (int j = 0; j < 4; ++j) {
            bool on = rb && ((cbm >> (v * 4 + j)) & 1);
            if (on) emax[i][j][r] = fmaxf(emax[i][j][r], acc[i][j][r]);
            acc[i][j][r] = 0.0f;
          }
        }
    }
  }
  __syncthreads();

  // epilogue: Dir [64][144] u8 (direct tile), Tr [128][80] u8 (mirror) in sh
  u8* Dir = (u8*)sh;
  u8* Tr  = (u8*)sh + 64 * 144;
#pragma unroll
  for (int i = 0; i < 2; ++i)
#pragma unroll
    for (int r = 0; r < 4; ++r) {
      int lrow = wr + i * 16 + lq * 4 + r;
      int grow = row0 + lrow;
#pragma unroll
      for (int j = 0; j < 4; ++j) {
        int lcol = wc + j * 16 + l15;
        int gcol = col0 + lcol;
        float val = __expf(emax[i][j][r] * 5.0f);
        if (grow == gcol) val = 0.0f;
        u8 q = f2fp8_hw(val);
        Dir[lrow * 144 + lcol] = q;
        Tr[lcol * 80 + lrow] = (gcol > grow) ? q : (u8)0;
      }
    }
  __syncthreads();
  if (col0 >= row0 + 64) {   // fully-upper tile: 16-B vector stores
    int c8 = threadIdx.x & 7, rr = threadIdx.x >> 3;
#pragma unroll
    for (int p = 0; p < 2; ++p) {
      int row = rr + p * 32;
      u32x4 ch = *(const u32x4*)(Dir + row * 144 + c8 * 16);
      *(u32x4*)(Abf + (size_t)(row0 + row) * NPAD + col0 + c8 * 16) = ch;
    }
    int c = threadIdx.x & 3; rr = threadIdx.x >> 2;
#pragma unroll
    for (int p = 0; p < 2; ++p) {
      int cc = rr + p * 64;
      u32x4 ch = *(const u32x4*)(Tr + cc * 80 + c * 16);
      *(u32x4*)(Abf + (size_t)(col0 + cc) * NPAD + row0 + c * 16) = ch;
    }
  } else {                    // straddle tile: predicated scalar
    for (int idx = threadIdx.x; idx < 64 * 128; idx += 256) {
      int row = idx >> 7, cc = idx & 127;
      int R = row0 + row, C = col0 + cc;
      u8 val = Dir[row * 144 + cc];
      if (C >= R) Abf[(size_t)R * NPAD + C] = val;
      if (C > R)  Abf[(size_t)C * NPAD + R] = val;
    }
  }
}

// S[n] = sum_m dequant(Abf[n][m]) — Abf holds both triangles, zero diag/pad.
// HW fp8 dequant: v_cvt_pk_f32_fp8 (2 values/inst) vs ~6 VALU ops/value manual.
__global__ __launch_bounds__(256) void k_rowsum(const u8* __restrict__ Abf, float* __restrict__ S) {
  int row = blockIdx.x;
  const u8* rp = Abf + (size_t)row * NPAD;
  float s = 0.0f;
  for (int c = threadIdx.x * 16; c < NPAD; c += 256 * 16) {
    u32x4 ch = *(const u32x4*)(rp + c);
#pragma unroll
    for (int w = 0; w < 4; ++w) {
      f32x2 lo = __builtin_amdgcn_cvt_pk_f32_fp8((int)ch[w], false);
      f32x2 hi = __builtin_amdgcn_cvt_pk_f32_fp8((int)ch[w], true);
      s += (lo[0] + lo[1]) + (hi[0] + hi[1]);
    }
  }
#pragma unroll
  for (int o = 32; o > 0; o >>= 1) s += __shfl_down(s, o, 64);
  __shared__ float red[4];
  if ((threadIdx.x & 63) == 0) red[threadIdx.x >> 6] = s;
  __syncthreads();
  if (threadIdx.x == 0) S[row] = red[0] + red[1] + red[2] + red[3];
}

// partial[z] = Abf[:, zK:(z+1)K] @ hmT_all[:, zK:(z+1)K]^T  (fp8 operands, f32 acc,
// bf16 partials). XCD-swizzled flat grid. Single-barrier 3-deep ring, counted
// vmcnt(4) — stage loads stay in flight across the barrier, hidden under MFMA.
__global__ __launch_bounds__(256, 3) void k_pvsk(const u8* __restrict__ Abf, const u8* __restrict__ hmT,
                                                 u16* __restrict__ part) {
  __shared__ u8 sh8[3 * 2 * 128 * 64];   // [ring3][A/B][128][64] = 48 KB
  int lane = threadIdx.x & 63, wave = threadIdx.x >> 6;
  int bid = blockIdx.x;                  // 576 (12 dummy)
  int xcd = bid & 7, s = bid >> 3;
  int row = (s / 12) * 8 + xcd;
  if (row >= 47) return;
  int k = s % 12;
  int col0 = (k % 6) * 128, row0 = row * 128, kb = (k / 6) * (NPAD / 2);

  f32x4 acc[4][4];
  f32x4 z = {0.f, 0.f, 0.f, 0.f};
  for (int i = 0; i < 4; ++i) for (int j = 0; j < 4; ++j) acc[i][j] = z;

  const u8* Ap = Abf + (size_t)row0 * NPAD + kb;
  const u8* Bp = hmT + (size_t)col0 * NPAD + kb;
  auto pv_stage = [&](int it, u8* base) {
    stage8<128>(Ap + it * 64, NPAD, base, wave, lane);
    stage8<128>(Bp + it * 64, NPAD, base + 8192, wave, lane);
  };
  const int niter = (NPAD / 2) / 64;   // 47
  pv_stage(0, sh8);
  pv_stage(1, sh8 + 16384);
  u8* cur = sh8;                 // buffer for compute(it)
  u8* nxt = sh8 + 2 * 16384;     // buffer for stage(it+2)
  for (int it = 0; it < niter; ++it) {
    if (it == niter - 1) asm volatile("s_waitcnt vmcnt(0)" ::: "memory");
    else                 asm volatile("s_waitcnt vmcnt(4)" ::: "memory");
    __builtin_amdgcn_sched_barrier(0);
    __builtin_amdgcn_s_barrier();
    __builtin_amdgcn_sched_barrier(0);
    if (it + 2 < niter) pv_stage(it + 2, nxt);
    __builtin_amdgcn_s_setprio(1);
    mfma_step8(cur, cur + 8192, acc, lane, wave);
    __builtin_amdgcn_s_setprio(0);
    cur += 16384; if (cur == sh8 + 3 * 16384) cur = sh8;
    nxt += 16384; if (nxt == sh8 + 3 * 16384) nxt = sh8;
  }

  u16* pp = part + (size_t)(k / 6) * NPAD * (VV * HH);
  int wr = (wave >> 1) * 64, wc = (wave & 1) * 64, l15 = lane & 15, lq = lane >> 4;
#pragma unroll
  for (int i = 0; i < 4; ++i)
#pragma unroll
    for (int r = 0; r < 4; ++r) {
      int grow = row0 + wr + i * 16 + lq * 4 + r;
#pragma unroll
      for (int j = 0; j < 4; ++j) {
        int gcol = col0 + wc + j * 16 + l15;
        pp[(size_t)grow * (VV * HH) + gcol] = f2bf(acc[i][j][r]);
      }
    }
}

// newx = blend((p0+p1)/S, h); writes out_newx (f32) and nxb (bf16)
__global__ __launch_bounds__(256) void k_pvred(const u16* __restrict__ part, const float* __restrict__ S,
                                               const float* __restrict__ mT, const float* __restrict__ h,
                                               float* __restrict__ out_newx, u16* __restrict__ nxb) {
  int i = (blockIdx.x * 256 + threadIdx.x) * 4;
  int v = i / (NN * HH);
  int rem = i - v * (NN * HH);
  int n = rem / HH;
  int j = rem - n * HH;
  int col = v * HH + j;
  u16x4 p0 = *(const u16x4*)(part + (size_t)n * (VV * HH) + col);
  u16x4 p1 = *(const u16x4*)(part + (size_t)NPAD * (VV * HH) + (size_t)n * (VV * HH) + col);
  float sc = 1.0f / (S[n] + 1e-9f);
  float mrow = mT[v * NPAD + n];
  float4 o;
  o.x = (bf2f(p0[0]) + bf2f(p1[0])) * sc;
  o.y = (bf2f(p0[1]) + bf2f(p1[1])) * sc;
  o.z = (bf2f(p0[2]) + bf2f(p1[2])) * sc;
  o.w = (bf2f(p0[3]) + bf2f(p1[3])) * sc;
  if (mrow != 0.0f) o = *(const float4*)(h + (size_t)(v * NPAD + n) * HH + j);
  *(float4*)(out_newx + (size_t)(v * NN + n) * HH + j) = o;
  u16x4 ob = { f2bf(o.x), f2bf(o.y), f2bf(o.z), f2bf(o.w) };
  *(u16x4*)(nxb + (size_t)(v * NPAD + n) * HH + j) = ob;
}

// x_new = leaky(new_x @ W_out^T + b_out), nan->0  [RT=2, double-buffered]
__global__ __launch_bounds__(256, 3) void k_gemm3(const u16* __restrict__ nxb, const u16* __restrict__ woutb,
                                                  const float* __restrict__ b_out, float* __restrict__ out_xnew) {
  __shared__ u16 As[2 * 64 * 64], Bs[2 * 128 * 64];
  int lane = threadIdx.x & 63, wave = threadIdx.x >> 6;
  int col0 = blockIdx.x * 128, row0 = blockIdx.y * 64, v = blockIdx.z;
  f32x4 acc[2][4];
  f32x4 z = {0.f, 0.f, 0.f, 0.f};
  for (int i = 0; i < 2; ++i) for (int j = 0; j < 4; ++j) acc[i][j] = z;
  gemm_loop_db<2>(nxb + (size_t)(v * NPAD + row0) * HH, HH,
                  woutb + (size_t)(v * DD + col0) * HH, HH, HH, As, Bs, acc, lane, wave);
  int wr = (wave >> 1) * 32, wc = (wave & 1) * 64, l15 = lane & 15, lq = lane >> 4;
#pragma unroll
  for (int i = 0; i < 2; ++i)
#pragma unroll
    for (int r = 0; r < 4; ++r) {
      int grow = row0 + wr + i * 16 + lq * 4 + r;
      if (grow < NN) {
#pragma unroll
        for (int j = 0; j < 4; ++j) {
          int gcol = col0 + wc + j * 16 + l15;
          float val = leaky(acc[i][j][r] + b_out[v * DD + gcol]);
          if (val != val) val = 0.0f;
          out_xnew[(size_t)(v * NN + grow) * DD + gcol] = val;
        }
      }
    }
}

// y_n = sigmoid(y @ Wy^T + by)  [RT=2, double-buffered]
__global__ __launch_bounds__(256, 3) void k_ygemm(const u16* __restrict__ yb, const u16* __restrict__ wyb,
                                                  const float* __restrict__ by, float* __restrict__ out_yn) {
  __shared__ u16 As[2 * 64 * 64], Bs[2 * 128 * 64];
  int lane = threadIdx.x & 63, wave = threadIdx.x >> 6;
  int col0 = blockIdx.x * 128, row0 = blockIdx.y * 64;
  f32x4 acc[2][4];
  f32x4 z = {0.f, 0.f, 0.f, 0.f};
  for (int i = 0; i < 2; ++i) for (int j = 0; j < 4; ++j) acc[i][j] = z;
  gemm_loop_db<2>(yb + (size_t)row0 * DYY, DYY, wyb + (size_t)col0 * DYY, DYY, DYY, As, Bs, acc, lane, wave);
  int wr = (wave >> 1) * 32, wc = (wave & 1) * 64, l15 = lane & 15, lq = lane >> 4;
#pragma unroll
  for (int i = 0; i < 2; ++i)
#pragma unroll
    for (int r = 0; r < 4; ++r) {
      int grow = row0 + wr + i * 16 + lq * 4 + r;
      if (grow < NN) {
#pragma unroll
        for (int j = 0; j < 4; ++j) {
          int gcol = col0 + wc + j * 16 + l15;
          float val = acc[i][j][r] + by[gcol];
          out_yn[(size_t)grow * HH + gcol] = 1.0f / (1.0f + __expf(-val));
        }
      }
    }
}

// ---------------- launch ----------------

extern "C" void kernel_launch(void* const* d_in, const int* in_sizes, int n_in,
                              void* d_out, int out_size, void* d_ws, size_t ws_size,
                              hipStream_t stream) {
  const float* x    = (const float*)d_in[0];
  const float* y    = (const float*)d_in[1];
  const float* mask = (const float*)d_in[2];
  const float* W_in = (const float*)d_in[3];
  const float* b_in = (const float*)d_in[4];
  const float* W_out= (const float*)d_in[5];
  const float* b_out= (const float*)d_in[6];
  const float* Wy   = (const float*)d_in[7];
  const float* by   = (const float*)d_in[8];

  float* out_newx = (float*)d_out;
  float* out_xnew = out_newx + (size_t)VV * NN * HH;
  float* out_yn   = out_xnew + (size_t)VV * NN * DD;

  char* w = (char*)d_ws;
  size_t off = 0;
  auto alloc = [&](size_t bytes) -> void* {
    void* p = w + off;
    off += (bytes + 255) & ~(size_t)255;
    return p;
  };
  u16*   xb    = (u16*)alloc((size_t)VV * NPAD * DD * 2);
  u16*   yb    = (u16*)alloc((size_t)NPAD * DYY * 2);
  u16*   winb  = (u16*)alloc((size_t)VV * HH * DD * 2);
  u16*   woutb = (u16*)alloc((size_t)VV * DD * HH * 2);
  u16*   wyb   = (u16*)alloc((size_t)HH * DYY * 2);
  float* h     = (float*)alloc((size_t)VV * NPAD * HH * 4);
  u16*   qb    = (u16*)alloc((size_t)VV * NPAD * HH * 2);
  u8*    hmT   = (u8*)alloc((size_t)VV * HH * NPAD);
  u16*   nxb   = (u16*)alloc((size_t)VV * NPAD * HH * 2);
  float* mT    = (float*)alloc((size_t)VV * NPAD * 4);
  float* S     = (float*)alloc((size_t)NPAD * 4);
  u8*    Abf   = (u8*)alloc((size_t)NPAD * NPAD);
  // split-K partials (2 x NPAD x 768 bf16 = 18.48 MB) reuse xb, dead after k_gemm1
  u16*   pvp   = xb;
  (void)ws_size; (void)in_sizes; (void)n_in; (void)out_size;

  // conversions
  k_conv<<<384, 256, 0, stream>>>(W_in, winb, VV * HH * DD / 4);
  k_conv<<<384, 256, 0, stream>>>(W_out, woutb, VV * DD * HH / 4);
  k_conv<<<128, 256, 0, stream>>>(Wy, wyb, HH * DYY / 4);
  k_conv<<<3000, 256, 0, stream>>>(y, yb, NN * DYY / 4);
  k_convx<<<9000, 256, 0, stream>>>(x, xb);
  k_mt<<<(VV * NPAD + 255) / 256, 256, 0, stream>>>(mask, mT);

  // h, q, hmT
  k_gemm1<<<dim3(2, 94, 3), 256, 0, stream>>>(xb, winb, b_in, h);
  k_qprep<<<VV * NN, 256, 0, stream>>>(h, qb);
  k_hmt<<<dim3(94, 4, 3), dim3(64, 16), 0, stream>>>(h, mT, hmT);

  // attention
  k_qk<<<2256, 256, 0, stream>>>(qb, mT, Abf);
  k_rowsum<<<NN, 256, 0, stream>>>(Abf, S);
  k_pvsk<<<576, 256, 0, stream>>>(Abf, hmT, pvp);
  k_pvred<<<4500, 256, 0, stream>>>(pvp, S, mT, h, out_newx, nxb);

  // outputs
  k_gemm3<<<dim3(4, 94, 3), 256, 0, stream>>>(nxb, woutb, b_out, out_xnew);
  k_ygemm<<<dim3(2, 94), 256, 0, stream>>>(yb, wyb, by, out_yn);
}

// Round 4
// 312.391 us; speedup vs baseline: 1.1351x; 1.0058x over previous
//
#include <hip/hip_runtime.h>

#define VV 3
#define NN 6000
#define DD 512
#define HH 256
#define DYY 512
#define NPAD 6016   // 47*128
#define QK_BK 32
#define QK_BUF2 (256 * QK_BK)   // u16 per ring slot: A 128 rows + B 128 rows (16384 B)

typedef unsigned short u16;
typedef unsigned char u8;
typedef __bf16 bf16x8 __attribute__((ext_vector_type(8)));
typedef u16 u16x8 __attribute__((ext_vector_type(8)));
typedef float f32x4 __attribute__((ext_vector_type(4)));
typedef float f32x2 __attribute__((ext_vector_type(2)));
typedef u16 u16x4 __attribute__((ext_vector_type(4)));
typedef unsigned int u32x4 __attribute__((ext_vector_type(4)));

__device__ __forceinline__ u16 f2bf(float f) {
  unsigned int b = __builtin_bit_cast(unsigned int, f);
  b += 0x7FFFu + ((b >> 16) & 1u);
  return (u16)(b >> 16);
}
__device__ __forceinline__ float bf2f(u16 u) {
  unsigned int b = ((unsigned int)u) << 16;
  return __builtin_bit_cast(float, b);
}
// hardware OCP e4m3fn convert (RNE, saturating) — 1 inst vs ~20 for manual
__device__ __forceinline__ u8 f2fp8_hw(float f) {
  unsigned int r;
  asm("v_cvt_pk_fp8_f32 %0, %1, %2" : "=v"(r) : "v"(f), "v"(f));
  return (u8)(r & 0xffu);
}
__device__ __forceinline__ float fp82f(u8 b) {
  int e = (b >> 3) & 15, m = b & 7;
  float v = e ? __builtin_bit_cast(float, (unsigned)((e + 120) << 23 | (m << 20)))
              : (float)m * 0.001953125f;
  return (b & 0x80) ? -v : v;
}
__device__ __forceinline__ float leaky(float v) { return v >= 0.0f ? v : 0.1f * v; }

// ---- stage ROWS x DEPTH bf16 tile: global row-major (ld elems) -> LDS [ROWS][DEPTH]
template<int ROWS, int DEPTH = 64>
__device__ __forceinline__ void stage(const u16* __restrict__ g, int ld, u16* s, int wave, int lane) {
  constexpr int LPR = DEPTH / 8;   // lanes per row (16B each)
  constexpr int RPC = 64 / LPR;    // rows per chunk
  constexpr int PER = ROWS / 4;    // rows per wave
  const u16* gp = g + (wave * PER + lane / LPR) * ld + (lane % LPR) * 8;
  u16* sp = s + wave * PER * DEPTH;
#pragma unroll
  for (int ch = 0; ch < PER / RPC; ++ch) {
    __builtin_amdgcn_global_load_lds(
        (const __attribute__((address_space(1))) void*)(gp + ch * RPC * ld),
        (__attribute__((address_space(3))) void*)(sp + ch * RPC * DEPTH), 16, 0, 0);
  }
}

// ---- swizzled DEPTH=32 stage: 16B chunk c of row r lands at LDS slot c^((r>>1)&3)
// (conflict-free ds_read_b128: 8 consecutive lanes cover all 8 bank groups)
template<int ROWS>
__device__ __forceinline__ void stage_sw(const u16* __restrict__ g, int ld, u16* s, int wave, int lane) {
  constexpr int PER = ROWS / 4;    // 4 lanes/row
  int rin = lane >> 2, c = lane & 3;
#pragma unroll
  for (int ch = 0; ch < PER / 16; ++ch) {
    int rloc = wave * PER + ch * 16 + rin;
    const u16* gp = g + (size_t)rloc * ld + ((c ^ ((rloc >> 1) & 3)) << 3);
    u16* sp = s + (wave * PER + ch * 16) * 32;   // linear dest; lane at +16B*lane
    __builtin_amdgcn_global_load_lds(
        (const __attribute__((address_space(1))) void*)gp,
        (__attribute__((address_space(3))) void*)sp, 16, 0, 0);
  }
}

// ---- fp8 stage: ROWS x 64-byte rows with 16-B-chunk XOR swizzle (bank-conflict-free reads)
__device__ __forceinline__ int swz4(int r) { return (r & 3) ^ ((r >> 2) & 3); }
template<int ROWS>
__device__ __forceinline__ void stage8(const u8* __restrict__ g, int ld, u8* s, int wave, int lane) {
  constexpr int PER = ROWS / 4;    // rows per wave (4 lanes/row, 16 rows per 64-lane chunk)
  int rin = lane >> 2, c = lane & 3;
#pragma unroll
  for (int ch = 0; ch < PER / 16; ++ch) {
    int rloc = wave * PER + ch * 16 + rin;
    const u8* gp = g + (size_t)rloc * ld + ((c ^ swz4(rloc)) << 4);
    u8* sp = s + (wave * PER + ch * 16) * 64;   // wave-uniform; lane lands at +16B*lane
    __builtin_amdgcn_global_load_lds(
        (const __attribute__((address_space(1))) void*)gp,
        (__attribute__((address_space(3))) void*)sp, 16, 0, 0);
  }
}

// ---- wave computes (RT*16) x 64 outputs; block = 4 waves in 2x2 -> (RT*32) x 128 tile
template<int RT, int DEPTH = 64>
__device__ __forceinline__ void mfma_step(const u16* As, const u16* Bs, f32x4 (*acc)[4], int lane, int wave) {
  const int wr = (wave >> 1) * (RT * 16);
  const int wc = (wave & 1) * 64;
  const int l15 = lane & 15;
  const int lq = lane >> 4;
#pragma unroll
  for (int kk = 0; kk < DEPTH; kk += 32) {
    bf16x8 a[RT], b[4];
#pragma unroll
    for (int i = 0; i < RT; ++i)
      a[i] = *(const bf16x8*)(As + (wr + i * 16 + l15) * DEPTH + kk + lq * 8);
#pragma unroll
    for (int j = 0; j < 4; ++j)
      b[j] = *(const bf16x8*)(Bs + (wc + j * 16 + l15) * DEPTH + kk + lq * 8);
#pragma unroll
    for (int i = 0; i < RT; ++i)
#pragma unroll
      for (int j = 0; j < 4; ++j)
        acc[i][j] = __builtin_amdgcn_mfma_f32_16x16x32_bf16(a[i], b[j], acc[i][j], 0, 0, 0);
  }
}

// RT=4 swizzled-read step: wave computes 64x64, block 2x2 waves -> 128x128 tile
__device__ __forceinline__ void mfma_step_sw4(const u16* As, const u16* Bs, f32x4 (*acc)[4], int lane, int wave) {
  const int wr = (wave >> 1) * 64;
  const int wc = (wave & 1) * 64;
  const int l15 = lane & 15, lq = lane >> 4;
  bf16x8 a[4], b[4];
#pragma unroll
  for (int i = 0; i < 4; ++i) {
    int r = wr + i * 16 + l15;
    a[i] = *(const bf16x8*)(As + r * 32 + ((lq ^ ((r >> 1) & 3)) << 3));
  }
#pragma unroll
  for (int j = 0; j < 4; ++j) {
    int r = wc + j * 16 + l15;
    b[j] = *(const bf16x8*)(Bs + r * 32 + ((lq ^ ((r >> 1) & 3)) << 3));
  }
#pragma unroll
  for (int i = 0; i < 4; ++i)
#pragma unroll
    for (int j = 0; j < 4; ++j)
      acc[i][j] = __builtin_amdgcn_mfma_f32_16x16x32_bf16(a[i], b[j], acc[i][j], 0, 0, 0);
}

// fp8 MFMA step: 128x128 tile, 64 K-elems (64 B) per slice, swizzled LDS
__device__ __forceinline__ void mfma_step8(const u8* As, const u8* Bs, f32x4 (*acc)[4], int lane, int wave) {
  const int wr = (wave >> 1) * 64;
  const int wc = (wave & 1) * 64;
  const int l15 = lane & 15, lq = lane >> 4;
#pragma unroll
  for (int kk = 0; kk < 64; kk += 32) {
    long a[4], b[4];
    int gch = (kk >> 4) + (lq >> 1), half = (lq & 1) << 3;
#pragma unroll
    for (int i = 0; i < 4; ++i) {
      int r = wr + i * 16 + l15;
      a[i] = *(const long*)(As + r * 64 + ((gch ^ swz4(r)) << 4) + half);
    }
#pragma unroll
    for (int j = 0; j < 4; ++j) {
      int r = wc + j * 16 + l15;
      b[j] = *(const long*)(Bs + r * 64 + ((gch ^ swz4(r)) << 4) + half);
    }
#pragma unroll
    for (int i = 0; i < 4; ++i)
#pragma unroll
      for (int j = 0; j < 4; ++j)
        acc[i][j] = __builtin_amdgcn_mfma_f32_16x16x32_fp8_fp8(a[i], b[j], acc[i][j], 0, 0, 0);
  }
}

// double-buffered K-loop (full-drain variant, used by the dense bf16 GEMMs)
template<int RT>
__device__ __forceinline__ void gemm_loop_db(const u16* __restrict__ A, int lda,
                                             const u16* __restrict__ B, int ldb, int K,
                                             u16* As, u16* Bs, f32x4 (*acc)[4], int lane, int wave) {
  const int niter = K / 64;
  stage<RT * 32>(A, lda, As, wave, lane);
  stage<128>(B, ldb, Bs, wave, lane);
  for (int it = 0; it < niter; ++it) {
    __syncthreads();
    int nb = (it + 1) & 1;
    if (it + 1 < niter) {
      stage<RT * 32>(A + (it + 1) * 64, lda, As + nb * RT * 32 * 64, wave, lane);
      stage<128>(B + (it + 1) * 64, ldb, Bs + nb * 128 * 64, wave, lane);
    }
    int cb = it & 1;
    mfma_step<RT>(As + cb * RT * 32 * 64, Bs + cb * 128 * 64, acc, lane, wave);
  }
  __syncthreads();
}

// ---------------- merged prep kernel (was 4x k_conv + k_convx + k_mt) ----------------

__device__ __forceinline__ void conv4(const float* __restrict__ in, u16* __restrict__ out, int i) {
  float4 f = ((const float4*)in)[i];
  u16x4 o = { f2bf(f.x), f2bf(f.y), f2bf(f.z), f2bf(f.w) };
  *(u16x4*)(out + i * 4) = o;
}

#define N_WIN  (VV * HH * DD / 4)
#define N_WOUT (VV * DD * HH / 4)
#define N_WY   (HH * DYY / 4)
#define N_Y    (NN * DYY / 4)
#define N_X    (VV * NN * DD / 4)
#define N_MT   (VV * NPAD / 4)
#define N_PREP (N_WIN + N_WOUT + N_WY + N_Y + N_X + N_MT)

__global__ __launch_bounds__(256) void k_prep(const float* __restrict__ x, const float* __restrict__ y,
                                              const float* __restrict__ mask,
                                              const float* __restrict__ W_in, const float* __restrict__ W_out,
                                              const float* __restrict__ Wy,
                                              u16* __restrict__ xb, u16* __restrict__ yb,
                                              u16* __restrict__ winb, u16* __restrict__ woutb,
                                              u16* __restrict__ wyb, float* __restrict__ mT) {
  int i = blockIdx.x * 256 + threadIdx.x;
  if (i < N_X) {   // biggest segment first
    int idx = i * 4;
    int v = idx / (NN * DD);
    int rem = idx - v * (NN * DD);
    int n = rem / DD;
    int d = rem - n * DD;
    float4 f = *(const float4*)(x + idx);
    u16x4 o = { f2bf(f.x), f2bf(f.y), f2bf(f.z), f2bf(f.w) };
    *(u16x4*)(xb + (size_t)(v * NPAD + n) * DD + d) = o;
    return;
  }
  i -= N_X;
  if (i < N_Y)  { conv4(y, yb, i); return; }
  i -= N_Y;
  if (i < N_WIN) { conv4(W_in, winb, i); return; }
  i -= N_WIN;
  if (i < N_WOUT){ conv4(W_out, woutb, i); return; }
  i -= N_WOUT;
  if (i < N_WY) { conv4(Wy, wyb, i); return; }
  i -= N_WY;
  if (i < N_MT) {
#pragma unroll
    for (int t = 0; t < 4; ++t) {
      int idx = i * 4 + t;
      int v = idx / NPAD, n = idx - v * NPAD;
      mT[idx] = (n < NN) ? mask[n * VV + v] : 0.0f;
    }
  }
}

// ---------------- elementwise kernels ----------------

__global__ __launch_bounds__(256) void k_qprep(const float* __restrict__ h, u16* __restrict__ qb) {
  int b = blockIdx.x;
  int v = b / NN, n = b - v * NN;
  int t = threadIdx.x;
  float val = h[(size_t)(v * NPAD + n) * HH + t];
  float ss = val * val;
#pragma unroll
  for (int o = 32; o > 0; o >>= 1) ss += __shfl_down(ss, o, 64);
  __shared__ float red[4];
  if ((t & 63) == 0) red[t >> 6] = ss;
  __syncthreads();
  float inv = 1.0f / fmaxf(sqrtf(red[0] + red[1] + red[2] + red[3]), 1e-12f);
  qb[(size_t)(v * NPAD + n) * HH + t] = f2bf(val * inv);
}

// hmT[v][j][m] = mT[v][m]*h[v][m][j] (fp8 e4m3, zero for m>=NN)
__global__ __launch_bounds__(1024) void k_hmt(const float* __restrict__ h, const float* __restrict__ mT,
                                              u8* __restrict__ hmT) {
  __shared__ float t[64][65];
  int m0 = blockIdx.x * 64, j0 = blockIdx.y * 64, v = blockIdx.z;
  int tx = threadIdx.x, ty = threadIdx.y;
#pragma unroll
  for (int p = 0; p < 4; ++p) {
    int ml = ty + p * 16;
    int m = m0 + ml;
    float val = 0.0f;
    if (m < NN) val = mT[v * NPAD + m] * h[(size_t)(v * NPAD + m) * HH + j0 + tx];
    t[ml][tx] = val;
  }
  __syncthreads();
#pragma unroll
  for (int p = 0; p < 4; ++p) {
    int j = j0 + ty + p * 16;
    hmT[(size_t)(v * HH + j) * NPAD + m0 + tx] = f2fp8_hw(t[tx][ty + p * 16]);
  }
}

// ---------------- GEMM kernels ----------------

__global__ __launch_bounds__(256, 3) void k_gemm1(const u16* __restrict__ xb, const u16* __restrict__ winb,
                                                  const float* __restrict__ b_in, float* __restrict__ h) {
  __shared__ u16 As[2 * 64 * 64], Bs[2 * 128 * 64];
  int lane = threadIdx.x & 63, wave = threadIdx.x >> 6;
  int col0 = blockIdx.x * 128, row0 = blockIdx.y * 64, v = blockIdx.z;
  f32x4 acc[2][4];
  f32x4 z = {0.f, 0.f, 0.f, 0.f};
  for (int i = 0; i < 2; ++i) for (int j = 0; j < 4; ++j) acc[i][j] = z;
  gemm_loop_db<2>(xb + (size_t)(v * NPAD + row0) * DD, DD,
                  winb + (size_t)(v * HH + col0) * DD, DD, DD, As, Bs, acc, lane, wave);
  int wr = (wave >> 1) * 32, wc = (wave & 1) * 64, l15 = lane & 15, lq = lane >> 4;
#pragma unroll
  for (int i = 0; i < 2; ++i)
#pragma unroll
    for (int r = 0; r < 4; ++r) {
      int grow = row0 + wr + i * 16 + lq * 4 + r;
      if (grow < NN) {
#pragma unroll
        for (int j = 0; j < 4; ++j) {
          int gcol = col0 + wc + j * 16 + l15;
          h[(size_t)(v * NPAD + grow) * HH + gcol] = leaky(acc[i][j][r] + b_in[v * HH + gcol]);
        }
      }
    }
}

// A = max_v mask*exp(q_v q_v^T / beta), diag zeroed -> fp8 e4m3.
// 128x128 tiles (RT=4): 8 ds_reads feed 16 MFMAs per wave per K-step — halves
// the LDS-port traffic per FLOP vs the old 64x128 tile (the measured floor).
// Upper-triangle grid 1128 = 8*141 blocks, bijective XCD swizzle. 3-deep ring,
// single barrier, counted vmcnt(4) (= stage(it+1) in flight).
__global__ __launch_bounds__(256, 2) void k_qk(const u16* __restrict__ qb, const float* __restrict__ mT,
                                               u8* __restrict__ Abf) {
  __shared__ u16 sh[3 * QK_BUF2];   // 49152 B; reused for Dir/Tr in epilogue
  int lane = threadIdx.x & 63, wave = threadIdx.x >> 6;
  int bid = (blockIdx.x & 7) * 141 + (blockIdx.x >> 3);   // XCD swizzle (1128=8*141)
  int x = (int)((sqrtf((float)(8 * bid + 1)) - 1.0f) * 0.5f);
  while ((x + 1) * (x + 2) / 2 <= bid) ++x;
  while (x * (x + 1) / 2 > bid) --x;
  int y = bid - x * (x + 1) / 2;
  int col0 = x * 128, row0 = y * 128;

  const int wr = (wave >> 1) * 64, wc = (wave & 1) * 64;
  const int l15 = lane & 15, lq = lane >> 4;

  // mask bitmasks: rbm bit v*16+i*4+r = (mT[v][grow]!=0); cbm bit v*4+j
  unsigned long long rbm = 0; unsigned cbm = 0;
#pragma unroll
  for (int v = 0; v < VV; ++v) {
#pragma unroll
    for (int t = 0; t < 16; ++t) {
      int grow = row0 + wr + (t >> 2) * 16 + lq * 4 + (t & 3);
      if (mT[v * NPAD + grow] != 0.0f) rbm |= 1ull << (v * 16 + t);
    }
#pragma unroll
    for (int j = 0; j < 4; ++j)
      if (mT[v * NPAD + col0 + wc + j * 16 + l15] != 0.0f) cbm |= 1u << (v * 4 + j);
  }
  // pin mask-load consumption here so no compiler vmcnt waits land in the loop
  asm volatile("" : "+v"(rbm), "+v"(cbm));

  f32x4 z = {0.f, 0.f, 0.f, 0.f};
  float ninf = -__builtin_inff();
  f32x4 nv = {ninf, ninf, ninf, ninf};
  f32x4 acc[4][4];
  f32x4 emax[4][4];
  for (int i = 0; i < 4; ++i)
    for (int j = 0; j < 4; ++j) { acc[i][j] = z; emax[i][j] = nv; }

  auto stage_it = [&](int it, u16* buf) {
    int v = it >> 3, k0 = (it & 7) * QK_BK;
    const u16* base = qb + (size_t)v * NPAD * HH + k0;
    stage_sw<128>(base + (size_t)row0 * HH, HH, buf, wave, lane);
    stage_sw<128>(base + (size_t)col0 * HH, HH, buf + 128 * QK_BK, wave, lane);
  };

  const int NIT = VV * (HH / QK_BK);   // 24
  stage_it(0, sh);
  stage_it(1, sh + QK_BUF2);
#pragma unroll
  for (int it = 0; it < NIT; ++it) {
    if (it == NIT - 1) asm volatile("s_waitcnt vmcnt(0)" ::: "memory");
    else               asm volatile("s_waitcnt vmcnt(4)" ::: "memory");
    __builtin_amdgcn_sched_barrier(0);
    __builtin_amdgcn_s_barrier();
    __builtin_amdgcn_sched_barrier(0);
    if (it + 2 < NIT) stage_it(it + 2, sh + ((it + 2) % 3) * QK_BUF2);
    const u16* cur = sh + (it % 3) * QK_BUF2;
    __builtin_amdgcn_s_setprio(1);
    mfma_step_sw4(cur, cur + 128 * QK_BK, acc, lane, wave);
    __builtin_amdgcn_s_setprio(0);
    if ((it & 7) == 7) {               // v complete: fold masked scores into emax
      int v = it >> 3;
#pragma unroll
      for (int i = 0; i < 4; ++i)
#pragma unroll
        for (int r = 0; r < 4; ++r) {
          bool rb = (rbm >> (v * 16 + i * 4 + r)) & 1;
#pragma unroll
          for (int j = 0; j < 4; ++j) {
            bool on = rb && ((cbm >> (v * 4 + j)) & 1);
            if (on) emax[i][j][r] = fmaxf(emax[i][j][r], acc[i][j][r]);
            acc[i][j][r] = 0.0f;
          }
        }
    }
  }
  __syncthreads();

  // epilogue: Dir [128][144] u8 (direct tile), Tr [128][144] u8 (mirror) in sh
  u8* Dir = (u8*)sh;
  u8* Tr  = (u8*)sh + 128 * 144;
#pragma unroll
  for (int i = 0; i < 4; ++i)
#pragma unroll
    for (int r = 0; r < 4; ++r) {
      int lrow = wr + i * 16 + lq * 4 + r;
      int grow = row0 + lrow;
#pragma unroll
      for (int j = 0; j < 4; ++j) {
        int lcol = wc + j * 16 + l15;
        int gcol = col0 + lcol;
        float val = __expf(emax[i][j][r] * 5.0f);
        if (grow == gcol) val = 0.0f;
        u8 q = f2fp8_hw(val);
        Dir[lrow * 144 + lcol] = q;
        Tr[lcol * 144 + lrow] = (gcol > grow) ? q : (u8)0;
      }
    }
  __syncthreads();
  if (x > y) {               // fully-upper tile: 16-B vector stores, both copies
    int c8 = threadIdx.x & 7, rr = threadIdx.x >> 3;
#pragma unroll
    for (int p = 0; p < 4; ++p) {
      int row = rr + p * 32;
      u32x4 ch = *(const u32x4*)(Dir + row * 144 + c8 * 16);
      *(u32x4*)(Abf + (size_t)(row0 + row) * NPAD + col0 + c8 * 16) = ch;
    }
#pragma unroll
    for (int p = 0; p < 4; ++p) {
      int cc = rr + p * 32;
      u32x4 ch = *(const u32x4*)(Tr + cc * 144 + c8 * 16);
      *(u32x4*)(Abf + (size_t)(col0 + cc) * NPAD + row0 + c8 * 16) = ch;
    }
  } else {                    // diagonal tile: predicated scalar
    for (int idx = threadIdx.x; idx < 128 * 128; idx += 256) {
      int row = idx >> 7, cc = idx & 127;
      int R = row0 + row, C = col0 + cc;
      u8 val = Dir[row * 144 + cc];
      if (C >= R) Abf[(size_t)R * NPAD + C] = val;
      if (C > R)  Abf[(size_t)C * NPAD + R] = val;
    }
  }
}

// S[n] = sum_m dequant(Abf[n][m]) — Abf holds both triangles, zero diag/pad.
// HW fp8 dequant: v_cvt_pk_f32_fp8 (2 values/inst) vs ~6 VALU ops/value manual.
__global__ __launch_bounds__(256) void k_rowsum(const u8* __restrict__ Abf, float* __restrict__ S) {
  int row = blockIdx.x;
  const u8* rp = Abf + (size_t)row * NPAD;
  float s = 0.0f;
  for (int c = threadIdx.x * 16; c < NPAD; c += 256 * 16) {
    u32x4 ch = *(const u32x4*)(rp + c);
#pragma unroll
    for (int w = 0; w < 4; ++w) {
      f32x2 lo = __builtin_amdgcn_cvt_pk_f32_fp8((int)ch[w], false);
      f32x2 hi = __builtin_amdgcn_cvt_pk_f32_fp8((int)ch[w], true);
      s += (lo[0] + lo[1]) + (hi[0] + hi[1]);
    }
  }
#pragma unroll
  for (int o = 32; o > 0; o >>= 1) s += __shfl_down(s, o, 64);
  __shared__ float red[4];
  if ((threadIdx.x & 63) == 0) red[threadIdx.x >> 6] = s;
  __syncthreads();
  if (threadIdx.x == 0) S[row] = red[0] + red[1] + red[2] + red[3];
}

// partial[z] = Abf[:, zK:(z+1)K] @ hmT_all[:, zK:(z+1)K]^T  (fp8 operands, f32 acc,
// bf16 partials). XCD-swizzled flat grid. Single-barrier 3-deep ring, counted
// vmcnt(4) — stage loads stay in flight across the barrier, hidden under MFMA.
__global__ __launch_bounds__(256, 3) void k_pvsk(const u8* __restrict__ Abf, const u8* __restrict__ hmT,
                                                 u16* __restrict__ part) {
  __shared__ u8 sh8[3 * 2 * 128 * 64];   // [ring3][A/B][128][64] = 48 KB
  int lane = threadIdx.x & 63, wave = threadIdx.x >> 6;
  int bid = blockIdx.x;                  // 576 (12 dummy)
  int xcd = bid & 7, s = bid >> 3;
  int row = (s / 12) * 8 + xcd;
  if (row >= 47) return;
  int k = s % 12;
  int col0 = (k % 6) * 128, row0 = row * 128, kb = (k / 6) * (NPAD / 2);

  f32x4 acc[4][4];
  f32x4 z = {0.f, 0.f, 0.f, 0.f};
  for (int i = 0; i < 4; ++i) for (int j = 0; j < 4; ++j) acc[i][j] = z;

  const u8* Ap = Abf + (size_t)row0 * NPAD + kb;
  const u8* Bp = hmT + (size_t)col0 * NPAD + kb;
  auto pv_stage = [&](int it, u8* base) {
    stage8<128>(Ap + it * 64, NPAD, base, wave, lane);
    stage8<128>(Bp + it * 64, NPAD, base + 8192, wave, lane);
  };
  const int niter = (NPAD / 2) / 64;   // 47
  pv_stage(0, sh8);
  pv_stage(1, sh8 + 16384);
  u8* cur = sh8;                 // buffer for compute(it)
  u8* nxt = sh8 + 2 * 16384;     // buffer for stage(it+2)
  for (int it = 0; it < niter; ++it) {
    if (it == niter - 1) asm volatile("s_waitcnt vmcnt(0)" ::: "memory");
    else                 asm volatile("s_waitcnt vmcnt(4)" ::: "memory");
    __builtin_amdgcn_sched_barrier(0);
    __builtin_amdgcn_s_barrier();
    __builtin_amdgcn_sched_barrier(0);
    if (it + 2 < niter) pv_stage(it + 2, nxt);
    __builtin_amdgcn_s_setprio(1);
    mfma_step8(cur, cur + 8192, acc, lane, wave);
    __builtin_amdgcn_s_setprio(0);
    cur += 16384; if (cur == sh8 + 3 * 16384) cur = sh8;
    nxt += 16384; if (nxt == sh8 + 3 * 16384) nxt = sh8;
  }

  u16* pp = part + (size_t)(k / 6) * NPAD * (VV * HH);
  int wr = (wave >> 1) * 64, wc = (wave & 1) * 64, l15 = lane & 15, lq = lane >> 4;
#pragma unroll
  for (int i = 0; i < 4; ++i)
#pragma unroll
    for (int r = 0; r < 4; ++r) {
      int grow = row0 + wr + i * 16 + lq * 4 + r;
#pragma unroll
      for (int j = 0; j < 4; ++j) {
        int gcol = col0 + wc + j * 16 + l15;
        pp[(size_t)grow * (VV * HH) + gcol] = f2bf(acc[i][j][r]);
      }
    }
}

// newx = blend((p0+p1)/S, h); writes out_newx (f32) and nxb (bf16)
__global__ __launch_bounds__(256) void k_pvred(const u16* __restrict__ part, const float* __restrict__ S,
                                               const float* __restrict__ mT, const float* __restrict__ h,
                                               float* __restrict__ out_newx, u16* __restrict__ nxb) {
  int i = (blockIdx.x * 256 + threadIdx.x) * 4;
  int v = i / (NN * HH);
  int rem = i - v * (NN * HH);
  int n = rem / HH;
  int j = rem - n * HH;
  int col = v * HH + j;
  u16x4 p0 = *(const u16x4*)(part + (size_t)n * (VV * HH) + col);
  u16x4 p1 = *(const u16x4*)(part + (size_t)NPAD * (VV * HH) + (size_t)n * (VV * HH) + col);
  float sc = 1.0f / (S[n] + 1e-9f);
  float mrow = mT[v * NPAD + n];
  float4 o;
  o.x = (bf2f(p0[0]) + bf2f(p1[0])) * sc;
  o.y = (bf2f(p0[1]) + bf2f(p1[1])) * sc;
  o.z = (bf2f(p0[2]) + bf2f(p1[2])) * sc;
  o.w = (bf2f(p0[3]) + bf2f(p1[3])) * sc;
  if (mrow != 0.0f) o = *(const float4*)(h + (size_t)(v * NPAD + n) * HH + j);
  *(float4*)(out_newx + (size_t)(v * NN + n) * HH + j) = o;
  u16x4 ob = { f2bf(o.x), f2bf(o.y), f2bf(o.z), f2bf(o.w) };
  *(u16x4*)(nxb + (size_t)(v * NPAD + n) * HH + j) = ob;
}

// x_new = leaky(new_x @ W_out^T + b_out), nan->0  [RT=2, double-buffered]
__global__ __launch_bounds__(256, 3) void k_gemm3(const u16* __restrict__ nxb, const u16* __restrict__ woutb,
                                                  const float* __restrict__ b_out, float* __restrict__ out_xnew) {
  __shared__ u16 As[2 * 64 * 64], Bs[2 * 128 * 64];
  int lane = threadIdx.x & 63, wave = threadIdx.x >> 6;
  int col0 = blockIdx.x * 128, row0 = blockIdx.y * 64, v = blockIdx.z;
  f32x4 acc[2][4];
  f32x4 z = {0.f, 0.f, 0.f, 0.f};
  for (int i = 0; i < 2; ++i) for (int j = 0; j < 4; ++j) acc[i][j] = z;
  gemm_loop_db<2>(nxb + (size_t)(v * NPAD + row0) * HH, HH,
                  woutb + (size_t)(v * DD + col0) * HH, HH, HH, As, Bs, acc, lane, wave);
  int wr = (wave >> 1) * 32, wc = (wave & 1) * 64, l15 = lane & 15, lq = lane >> 4;
#pragma unroll
  for (int i = 0; i < 2; ++i)
#pragma unroll
    for (int r = 0; r < 4; ++r) {
      int grow = row0 + wr + i * 16 + lq * 4 + r;
      if (grow < NN) {
#pragma unroll
        for (int j = 0; j < 4; ++j) {
          int gcol = col0 + wc + j * 16 + l15;
          float val = leaky(acc[i][j][r] + b_out[v * DD + gcol]);
          if (val != val) val = 0.0f;
          out_xnew[(size_t)(v * NN + grow) * DD + gcol] = val;
        }
      }
    }
}

// y_n = sigmoid(y @ Wy^T + by)  [RT=2, double-buffered]
__global__ __launch_bounds__(256, 3) void k_ygemm(const u16* __restrict__ yb, const u16* __restrict__ wyb,
                                                  const float* __restrict__ by, float* __restrict__ out_yn) {
  __shared__ u16 As[2 * 64 * 64], Bs[2 * 128 * 64];
  int lane = threadIdx.x & 63, wave = threadIdx.x >> 6;
  int col0 = blockIdx.x * 128, row0 = blockIdx.y * 64;
  f32x4 acc[2][4];
  f32x4 z = {0.f, 0.f, 0.f, 0.f};
  for (int i = 0; i < 2; ++i) for (int j = 0; j < 4; ++j) acc[i][j] = z;
  gemm_loop_db<2>(yb + (size_t)row0 * DYY, DYY, wyb + (size_t)col0 * DYY, DYY, DYY, As, Bs, acc, lane, wave);
  int wr = (wave >> 1) * 32, wc = (wave & 1) * 64, l15 = lane & 15, lq = lane >> 4;
#pragma unroll
  for (int i = 0; i < 2; ++i)
#pragma unroll
    for (int r = 0; r < 4; ++r) {
      int grow = row0 + wr + i * 16 + lq * 4 + r;
      if (grow < NN) {
#pragma unroll
        for (int j = 0; j < 4; ++j) {
          int gcol = col0 + wc + j * 16 + l15;
          float val = acc[i][j][r] + by[gcol];
          out_yn[(size_t)grow * HH + gcol] = 1.0f / (1.0f + __expf(-val));
        }
      }
    }
}

// ---------------- launch ----------------

extern "C" void kernel_launch(void* const* d_in, const int* in_sizes, int n_in,
                              void* d_out, int out_size, void* d_ws, size_t ws_size,
                              hipStream_t stream) {
  const float* x    = (const float*)d_in[0];
  const float* y    = (const float*)d_in[1];
  const float* mask = (const float*)d_in[2];
  const float* W_in = (const float*)d_in[3];
  const float* b_in = (const float*)d_in[4];
  const float* W_out= (const float*)d_in[5];
  const float* b_out= (const float*)d_in[6];
  const float* Wy   = (const float*)d_in[7];
  const float* by   = (const float*)d_in[8];

  float* out_newx = (float*)d_out;
  float* out_xnew = out_newx + (size_t)VV * NN * HH;
  float* out_yn   = out_xnew + (size_t)VV * NN * DD;

  char* w = (char*)d_ws;
  size_t off = 0;
  auto alloc = [&](size_t bytes) -> void* {
    void* p = w + off;
    off += (bytes + 255) & ~(size_t)255;
    return p;
  };
  u16*   xb    = (u16*)alloc((size_t)VV * NPAD * DD * 2);
  u16*   yb    = (u16*)alloc((size_t)NPAD * DYY * 2);
  u16*   winb  = (u16*)alloc((size_t)VV * HH * DD * 2);
  u16*   woutb = (u16*)alloc((size_t)VV * DD * HH * 2);
  u16*   wyb   = (u16*)alloc((size_t)HH * DYY * 2);
  float* h     = (float*)alloc((size_t)VV * NPAD * HH * 4);
  u16*   qb    = (u16*)alloc((size_t)VV * NPAD * HH * 2);
  u8*    hmT   = (u8*)alloc((size_t)VV * HH * NPAD);
  u16*   nxb   = (u16*)alloc((size_t)VV * NPAD * HH * 2);
  float* mT    = (float*)alloc((size_t)VV * NPAD * 4);
  float* S     = (float*)alloc((size_t)NPAD * 4);
  u8*    Abf   = (u8*)alloc((size_t)NPAD * NPAD);
  // split-K partials (2 x NPAD x 768 bf16 = 18.48 MB) reuse xb, dead after k_gemm1
  u16*   pvp   = xb;
  (void)ws_size; (void)in_sizes; (void)n_in; (void)out_size;

  // merged conversions (4x conv + convx + mT)
  k_prep<<<(N_PREP + 255) / 256, 256, 0, stream>>>(x, y, mask, W_in, W_out, Wy,
                                                   xb, yb, winb, woutb, wyb, mT);

  // h, q, hmT
  k_gemm1<<<dim3(2, 94, 3), 256, 0, stream>>>(xb, winb, b_in, h);
  k_qprep<<<VV * NN, 256, 0, stream>>>(h, qb);
  k_hmt<<<dim3(94, 4, 3), dim3(64, 16), 0, stream>>>(h, mT, hmT);

  // attention
  k_qk<<<1128, 256, 0, stream>>>(qb, mT, Abf);
  k_rowsum<<<NN, 256, 0, stream>>>(Abf, S);
  k_pvsk<<<576, 256, 0, stream>>>(Abf, hmT, pvp);
  k_pvred<<<4500, 256, 0, stream>>>(pvp, S, mT, h, out_newx, nxb);

  // outputs
  k_gemm3<<<dim3(4, 94, 3), 256, 0, stream>>>(nxb, woutb, b_out, out_xnew);
  k_ygemm<<<dim3(2, 94), 256, 0, stream>>>(yb, wyb, by, out_yn);
}

// Round 5
// 303.062 us; speedup vs baseline: 1.1700x; 1.0308x over previous
//
#include <hip/hip_runtime.h>

#define VV 3
#define NN 6000
#define DD 512
#define HH 256
#define DYY 512
#define NPAD 6016   // 47*128
#define QK_BK 32
#define QK_BUF (192 * QK_BK)   // u16 per ring slot: A 64 rows + B 128 rows (12288 B)

typedef unsigned short u16;
typedef unsigned char u8;
typedef __bf16 bf16x8 __attribute__((ext_vector_type(8)));
typedef u16 u16x8 __attribute__((ext_vector_type(8)));
typedef float f32x4 __attribute__((ext_vector_type(4)));
typedef float f32x2 __attribute__((ext_vector_type(2)));
typedef u16 u16x4 __attribute__((ext_vector_type(4)));
typedef unsigned int u32x4 __attribute__((ext_vector_type(4)));

__device__ __forceinline__ u16 f2bf(float f) {
  unsigned int b = __builtin_bit_cast(unsigned int, f);
  b += 0x7FFFu + ((b >> 16) & 1u);
  return (u16)(b >> 16);
}
__device__ __forceinline__ float bf2f(u16 u) {
  unsigned int b = ((unsigned int)u) << 16;
  return __builtin_bit_cast(float, b);
}
// hardware OCP e4m3fn convert (RNE, saturating) — 1 inst vs ~20 for manual
__device__ __forceinline__ u8 f2fp8_hw(float f) {
  unsigned int r;
  asm("v_cvt_pk_fp8_f32 %0, %1, %2" : "=v"(r) : "v"(f), "v"(f));
  return (u8)(r & 0xffu);
}
__device__ __forceinline__ float leaky(float v) { return v >= 0.0f ? v : 0.1f * v; }

// ---- stage ROWS x DEPTH bf16 tile: global row-major (ld elems) -> LDS [ROWS][DEPTH]
template<int ROWS, int DEPTH = 64>
__device__ __forceinline__ void stage(const u16* __restrict__ g, int ld, u16* s, int wave, int lane) {
  constexpr int LPR = DEPTH / 8;   // lanes per row (16B each)
  constexpr int RPC = 64 / LPR;    // rows per chunk
  constexpr int PER = ROWS / 4;    // rows per wave
  const u16* gp = g + (wave * PER + lane / LPR) * ld + (lane % LPR) * 8;
  u16* sp = s + wave * PER * DEPTH;
#pragma unroll
  for (int ch = 0; ch < PER / RPC; ++ch) {
    __builtin_amdgcn_global_load_lds(
        (const __attribute__((address_space(1))) void*)(gp + ch * RPC * ld),
        (__attribute__((address_space(3))) void*)(sp + ch * RPC * DEPTH), 16, 0, 0);
  }
}

// ---- swizzled DEPTH=32 stage: 16B chunk c of row r lands at LDS slot c^((r>>1)&3)
// (conflict-free ds_read_b128: 8 consecutive lanes cover all 8 bank groups)
template<int ROWS>
__device__ __forceinline__ void stage_sw(const u16* __restrict__ g, int ld, u16* s, int wave, int lane) {
  constexpr int PER = ROWS / 4;    // 4 lanes/row
  int rin = lane >> 2, c = lane & 3;
#pragma unroll
  for (int ch = 0; ch < PER / 16; ++ch) {
    int rloc = wave * PER + ch * 16 + rin;
    const u16* gp = g + (size_t)rloc * ld + ((c ^ ((rloc >> 1) & 3)) << 3);
    u16* sp = s + (wave * PER + ch * 16) * 32;   // linear dest; lane at +16B*lane
    __builtin_amdgcn_global_load_lds(
        (const __attribute__((address_space(1))) void*)gp,
        (__attribute__((address_space(3))) void*)sp, 16, 0, 0);
  }
}

// ---- fp8 stage: ROWS x 64-byte rows with 16-B-chunk XOR swizzle (bank-conflict-free reads)
__device__ __forceinline__ int swz4(int r) { return (r & 3) ^ ((r >> 2) & 3); }
template<int ROWS>
__device__ __forceinline__ void stage8(const u8* __restrict__ g, int ld, u8* s, int wave, int lane) {
  constexpr int PER = ROWS / 4;    // rows per wave (4 lanes/row, 16 rows per 64-lane chunk)
  int rin = lane >> 2, c = lane & 3;
#pragma unroll
  for (int ch = 0; ch < PER / 16; ++ch) {
    int rloc = wave * PER + ch * 16 + rin;
    const u8* gp = g + (size_t)rloc * ld + ((c ^ swz4(rloc)) << 4);
    u8* sp = s + (wave * PER + ch * 16) * 64;   // wave-uniform; lane lands at +16B*lane
    __builtin_amdgcn_global_load_lds(
        (const __attribute__((address_space(1))) void*)gp,
        (__attribute__((address_space(3))) void*)sp, 16, 0, 0);
  }
}

// ---- wave computes (RT*16) x 64 outputs; block = 4 waves in 2x2 -> (RT*32) x 128 tile
template<int RT, int DEPTH = 64>
__device__ __forceinline__ void mfma_step(const u16* As, const u16* Bs, f32x4 (*acc)[4], int lane, int wave) {
  const int wr = (wave >> 1) * (RT * 16);
  const int wc = (wave & 1) * 64;
  const int l15 = lane & 15;
  const int lq = lane >> 4;
#pragma unroll
  for (int kk = 0; kk < DEPTH; kk += 32) {
    bf16x8 a[RT], b[4];
#pragma unroll
    for (int i = 0; i < RT; ++i)
      a[i] = *(const bf16x8*)(As + (wr + i * 16 + l15) * DEPTH + kk + lq * 8);
#pragma unroll
    for (int j = 0; j < 4; ++j)
      b[j] = *(const bf16x8*)(Bs + (wc + j * 16 + l15) * DEPTH + kk + lq * 8);
#pragma unroll
    for (int i = 0; i < RT; ++i)
#pragma unroll
      for (int j = 0; j < 4; ++j)
        acc[i][j] = __builtin_amdgcn_mfma_f32_16x16x32_bf16(a[i], b[j], acc[i][j], 0, 0, 0);
  }
}

// swizzled-read variant of mfma_step for DEPTH=32 (matches stage_sw layout)
__device__ __forceinline__ void mfma_step_sw(const u16* As, const u16* Bs, f32x4 (*acc)[4], int lane, int wave) {
  const int wr = (wave >> 1) * 32;
  const int wc = (wave & 1) * 64;
  const int l15 = lane & 15, lq = lane >> 4;
  bf16x8 a[2], b[4];
#pragma unroll
  for (int i = 0; i < 2; ++i) {
    int r = wr + i * 16 + l15;
    a[i] = *(const bf16x8*)(As + r * 32 + ((lq ^ ((r >> 1) & 3)) << 3));
  }
#pragma unroll
  for (int j = 0; j < 4; ++j) {
    int r = wc + j * 16 + l15;
    b[j] = *(const bf16x8*)(Bs + r * 32 + ((lq ^ ((r >> 1) & 3)) << 3));
  }
#pragma unroll
  for (int i = 0; i < 2; ++i)
#pragma unroll
    for (int j = 0; j < 4; ++j)
      acc[i][j] = __builtin_amdgcn_mfma_f32_16x16x32_bf16(a[i], b[j], acc[i][j], 0, 0, 0);
}

// fp8 MFMA step: 128x128 tile, 64 K-elems (64 B) per slice, swizzled LDS
__device__ __forceinline__ void mfma_step8(const u8* As, const u8* Bs, f32x4 (*acc)[4], int lane, int wave) {
  const int wr = (wave >> 1) * 64;
  const int wc = (wave & 1) * 64;
  const int l15 = lane & 15, lq = lane >> 4;
#pragma unroll
  for (int kk = 0; kk < 64; kk += 32) {
    long a[4], b[4];
    int gch = (kk >> 4) + (lq >> 1), half = (lq & 1) << 3;
#pragma unroll
    for (int i = 0; i < 4; ++i) {
      int r = wr + i * 16 + l15;
      a[i] = *(const long*)(As + r * 64 + ((gch ^ swz4(r)) << 4) + half);
    }
#pragma unroll
    for (int j = 0; j < 4; ++j) {
      int r = wc + j * 16 + l15;
      b[j] = *(const long*)(Bs + r * 64 + ((gch ^ swz4(r)) << 4) + half);
    }
#pragma unroll
    for (int i = 0; i < 4; ++i)
#pragma unroll
      for (int j = 0; j < 4; ++j)
        acc[i][j] = __builtin_amdgcn_mfma_f32_16x16x32_fp8_fp8(a[i], b[j], acc[i][j], 0, 0, 0);
  }
}

// double-buffered K-loop (full-drain variant, used by the dense bf16 GEMMs)
template<int RT>
__device__ __forceinline__ void gemm_loop_db(const u16* __restrict__ A, int lda,
                                             const u16* __restrict__ B, int ldb, int K,
                                             u16* As, u16* Bs, f32x4 (*acc)[4], int lane, int wave) {
  const int niter = K / 64;
  stage<RT * 32>(A, lda, As, wave, lane);
  stage<128>(B, ldb, Bs, wave, lane);
  for (int it = 0; it < niter; ++it) {
    __syncthreads();
    int nb = (it + 1) & 1;
    if (it + 1 < niter) {
      stage<RT * 32>(A + (it + 1) * 64, lda, As + nb * RT * 32 * 64, wave, lane);
      stage<128>(B + (it + 1) * 64, ldb, Bs + nb * 128 * 64, wave, lane);
    }
    int cb = it & 1;
    mfma_step<RT>(As + cb * RT * 32 * 64, Bs + cb * 128 * 64, acc, lane, wave);
  }
  __syncthreads();
}

// ---------------- merged prep kernel (was 4x k_conv + k_convx + k_mt) ----------------

__device__ __forceinline__ void conv4(const float* __restrict__ in, u16* __restrict__ out, int i) {
  float4 f = ((const float4*)in)[i];
  u16x4 o = { f2bf(f.x), f2bf(f.y), f2bf(f.z), f2bf(f.w) };
  *(u16x4*)(out + i * 4) = o;
}

#define N_WIN  (VV * HH * DD / 4)
#define N_WOUT (VV * DD * HH / 4)
#define N_WY   (HH * DYY / 4)
#define N_Y    (NN * DYY / 4)
#define N_X    (VV * NN * DD / 4)
#define N_MT   (VV * NPAD / 4)
#define N_PREP (N_WIN + N_WOUT + N_WY + N_Y + N_X + N_MT)

__global__ __launch_bounds__(256) void k_prep(const float* __restrict__ x, const float* __restrict__ y,
                                              const float* __restrict__ mask,
                                              const float* __restrict__ W_in, const float* __restrict__ W_out,
                                              const float* __restrict__ Wy,
                                              u16* __restrict__ xb, u16* __restrict__ yb,
                                              u16* __restrict__ winb, u16* __restrict__ woutb,
                                              u16* __restrict__ wyb, float* __restrict__ mT) {
  int i = blockIdx.x * 256 + threadIdx.x;
  if (i < N_X) {   // biggest segment first
    int idx = i * 4;
    int v = idx / (NN * DD);
    int rem = idx - v * (NN * DD);
    int n = rem / DD;
    int d = rem - n * DD;
    float4 f = *(const float4*)(x + idx);
    u16x4 o = { f2bf(f.x), f2bf(f.y), f2bf(f.z), f2bf(f.w) };
    *(u16x4*)(xb + (size_t)(v * NPAD + n) * DD + d) = o;
    return;
  }
  i -= N_X;
  if (i < N_Y)  { conv4(y, yb, i); return; }
  i -= N_Y;
  if (i < N_WIN) { conv4(W_in, winb, i); return; }
  i -= N_WIN;
  if (i < N_WOUT){ conv4(W_out, woutb, i); return; }
  i -= N_WOUT;
  if (i < N_WY) { conv4(Wy, wyb, i); return; }
  i -= N_WY;
  if (i < N_MT) {
#pragma unroll
    for (int t = 0; t < 4; ++t) {
      int idx = i * 4 + t;
      int v = idx / NPAD, n = idx - v * NPAD;
      mT[idx] = (n < NN) ? mask[n * VV + v] : 0.0f;
    }
  }
}

// ---------------- elementwise kernels ----------------

__global__ __launch_bounds__(256) void k_qprep(const float* __restrict__ h, u16* __restrict__ qb) {
  int b = blockIdx.x;
  int v = b / NN, n = b - v * NN;
  int t = threadIdx.x;
  float val = h[(size_t)(v * NPAD + n) * HH + t];
  float ss = val * val;
#pragma unroll
  for (int o = 32; o > 0; o >>= 1) ss += __shfl_down(ss, o, 64);
  __shared__ float red[4];
  if ((t & 63) == 0) red[t >> 6] = ss;
  __syncthreads();
  float inv = 1.0f / fmaxf(sqrtf(red[0] + red[1] + red[2] + red[3]), 1e-12f);
  qb[(size_t)(v * NPAD + n) * HH + t] = f2bf(val * inv);
}

// hmT[v][j][m] = mT[v][m]*h[v][m][j] (fp8 e4m3, zero for m>=NN)
__global__ __launch_bounds__(1024) void k_hmt(const float* __restrict__ h, const float* __restrict__ mT,
                                              u8* __restrict__ hmT) {
  __shared__ float t[64][65];
  int m0 = blockIdx.x * 64, j0 = blockIdx.y * 64, v = blockIdx.z;
  int tx = threadIdx.x, ty = threadIdx.y;
#pragma unroll
  for (int p = 0; p < 4; ++p) {
    int ml = ty + p * 16;
    int m = m0 + ml;
    float val = 0.0f;
    if (m < NN) val = mT[v * NPAD + m] * h[(size_t)(v * NPAD + m) * HH + j0 + tx];
    t[ml][tx] = val;
  }
  __syncthreads();
#pragma unroll
  for (int p = 0; p < 4; ++p) {
    int j = j0 + ty + p * 16;
    hmT[(size_t)(v * HH + j) * NPAD + m0 + tx] = f2fp8_hw(t[tx][ty + p * 16]);
  }
}

// ---------------- GEMM kernels ----------------

__global__ __launch_bounds__(256, 3) void k_gemm1(const u16* __restrict__ xb, const u16* __restrict__ winb,
                                                  const float* __restrict__ b_in, float* __restrict__ h) {
  __shared__ u16 As[2 * 64 * 64], Bs[2 * 128 * 64];
  int lane = threadIdx.x & 63, wave = threadIdx.x >> 6;
  int col0 = blockIdx.x * 128, row0 = blockIdx.y * 64, v = blockIdx.z;
  f32x4 acc[2][4];
  f32x4 z = {0.f, 0.f, 0.f, 0.f};
  for (int i = 0; i < 2; ++i) for (int j = 0; j < 4; ++j) acc[i][j] = z;
  gemm_loop_db<2>(xb + (size_t)(v * NPAD + row0) * DD, DD,
                  winb + (size_t)(v * HH + col0) * DD, DD, DD, As, Bs, acc, lane, wave);
  int wr = (wave >> 1) * 32, wc = (wave & 1) * 64, l15 = lane & 15, lq = lane >> 4;
#pragma unroll
  for (int i = 0; i < 2; ++i)
#pragma unroll
    for (int r = 0; r < 4; ++r) {
      int grow = row0 + wr + i * 16 + lq * 4 + r;
      if (grow < NN) {
#pragma unroll
        for (int j = 0; j < 4; ++j) {
          int gcol = col0 + wc + j * 16 + l15;
          h[(size_t)(v * NPAD + grow) * HH + gcol] = leaky(acc[i][j][r] + b_in[v * HH + gcol]);
        }
      }
    }
}

// A = max_v mask*exp(q_v q_v^T / beta), diag zeroed -> fp8 e4m3.
// R3 structure (measured 62.9 us): 64x128 tile RT=2, 3-deep ring, single
// barrier per iter, counted vmcnt(3), 36 KB LDS -> 4 blocks/CU.
// NEW: bijective XCD swizzle (2256 = 8*282) — consecutive bids share a
// col-panel; contiguous range per XCD makes panel re-reads L2-local.
__global__ __launch_bounds__(256, 4) void k_qk(const u16* __restrict__ qb, const float* __restrict__ mT,
                                               u8* __restrict__ Abf) {
  __shared__ u16 sh[3 * QK_BUF];   // 36864 B; reused for Dir/Tr in epilogue
  int lane = threadIdx.x & 63, wave = threadIdx.x >> 6;
  int bid = (blockIdx.x & 7) * 282 + (blockIdx.x >> 3);   // XCD swizzle (2256=8*282)
  int x = (int)((sqrtf((float)(4 * bid + 1)) - 1.0f) * 0.5f);
  while ((x + 1) * (x + 2) <= bid) ++x;
  while (x * (x + 1) > bid) --x;
  int y = bid - x * (x + 1);
  int col0 = x * 128, row0 = y * 64;

  const int wr = (wave >> 1) * 32, wc = (wave & 1) * 64;
  const int l15 = lane & 15, lq = lane >> 4;

  // mask bitmasks: rbm bit v*8+i*4+r = (mT[v][grow]!=0); cbm bit v*4+j
  unsigned rbm = 0, cbm = 0;
#pragma unroll
  for (int v = 0; v < VV; ++v) {
#pragma unroll
    for (int t = 0; t < 8; ++t) {
      int grow = row0 + wr + (t >> 2) * 16 + lq * 4 + (t & 3);
      if (mT[v * NPAD + grow] != 0.0f) rbm |= 1u << (v * 8 + t);
    }
#pragma unroll
    for (int j = 0; j < 4; ++j)
      if (mT[v * NPAD + col0 + wc + j * 16 + l15] != 0.0f) cbm |= 1u << (v * 4 + j);
  }
  // pin mask-load consumption here so no compiler vmcnt waits land in the loop
  asm volatile("" : "+v"(rbm), "+v"(cbm));

  f32x4 z = {0.f, 0.f, 0.f, 0.f};
  float ninf = -__builtin_inff();
  f32x4 nv = {ninf, ninf, ninf, ninf};
  f32x4 acc[2][4];
  f32x4 emax[2][4];
  for (int i = 0; i < 2; ++i)
    for (int j = 0; j < 4; ++j) { acc[i][j] = z; emax[i][j] = nv; }

  auto stage_it = [&](int it, u16* buf) {
    int v = it >> 3, k0 = (it & 7) * QK_BK;
    const u16* base = qb + (size_t)v * NPAD * HH + k0;
    stage_sw<64>(base + (size_t)row0 * HH, HH, buf, wave, lane);
    stage_sw<128>(base + (size_t)col0 * HH, HH, buf + 64 * QK_BK, wave, lane);
  };

  const int NIT = VV * (HH / QK_BK);   // 24
  stage_it(0, sh);
  stage_it(1, sh + QK_BUF);
#pragma unroll
  for (int it = 0; it < NIT; ++it) {
    if (it == NIT - 1) asm volatile("s_waitcnt vmcnt(0)" ::: "memory");
    else               asm volatile("s_waitcnt vmcnt(3)" ::: "memory");
    __builtin_amdgcn_sched_barrier(0);
    __builtin_amdgcn_s_barrier();
    __builtin_amdgcn_sched_barrier(0);
    if (it + 2 < NIT) stage_it(it + 2, sh + ((it + 2) % 3) * QK_BUF);
    const u16* cur = sh + (it % 3) * QK_BUF;
    __builtin_amdgcn_s_setprio(1);
    mfma_step_sw(cur, cur + 64 * QK_BK, acc, lane, wave);
    __builtin_amdgcn_s_setprio(0);
    if ((it & 7) == 7) {               // v complete: fold masked scores into emax
      int v = it >> 3;
#pragma unroll
      for (int i = 0; i < 2; ++i)
#pragma unroll
        for (int r = 0; r < 4; ++r) {
          bool rb = (rbm >> (v * 8 + i * 4 + r)) & 1;
#pragma unroll
          for (int j = 0; j < 4; ++j) {
            bool on = rb && ((cbm >> (v * 4 + j)) & 1);
            if (on) emax[i][j][r] = fmaxf(emax[i][j][r], acc[i][j][r]);
            acc[i][j][r] = 0.0f;
          }
        }
    }
  }
  __syncthreads();

  // epilogue: Dir [64][144] u8 (direct tile), Tr [128][80] u8 (mirror) in sh
  u8* Dir = (u8*)sh;
  u8* Tr  = (u8*)sh + 64 * 144;
#pragma unroll
  for (int i = 0; i < 2; ++i)
#pragma unroll
    for (int r = 0; r < 4; ++r) {
      int lrow = wr + i * 16 + lq * 4 + r;
      int grow = row0 + lrow;
#pragma unroll
      for (int j = 0; j < 4; ++j) {
        int lcol = wc + j * 16 + l15;
        int gcol = col0 + lcol;
        float val = __expf(emax[i][j][r] * 5.0f);
        if (grow == gcol) val = 0.0f;
        u8 q = f2fp8_hw(val);
        Dir[lrow * 144 + lcol] = q;
        Tr[lcol * 80 + lrow] = (gcol > grow) ? q : (u8)0;
      }
    }
  __syncthreads();
  if (col0 >= row0 + 64) {   // fully-upper tile: 16-B vector stores
    int c8 = threadIdx.x & 7, rr = threadIdx.x >> 3;
#pragma unroll
    for (int p = 0; p < 2; ++p) {
      int row = rr + p * 32;
      u32x4 ch = *(const u32x4*)(Dir + row * 144 + c8 * 16);
      *(u32x4*)(Abf + (size_t)(row0 + row) * NPAD + col0 + c8 * 16) = ch;
    }
    int c = threadIdx.x & 3; rr = threadIdx.x >> 2;
#pragma unroll
    for (int p = 0; p < 2; ++p) {
      int cc = rr + p * 64;
      u32x4 ch = *(const u32x4*)(Tr + cc * 80 + c * 16);
      *(u32x4*)(Abf + (size_t)(col0 + cc) * NPAD + row0 + c * 16) = ch;
    }
  } else {                    // straddle tile: predicated scalar
    for (int idx = threadIdx.x; idx < 64 * 128; idx += 256) {
      int row = idx >> 7, cc = idx & 127;
      int R = row0 + row, C = col0 + cc;
      u8 val = Dir[row * 144 + cc];
      if (C >= R) Abf[(size_t)R * NPAD + C] = val;
      if (C > R)  Abf[(size_t)C * NPAD + R] = val;
    }
  }
}

// S[n] = sum_m dequant(Abf[n][m]) — Abf holds both triangles, zero diag/pad.
// HW fp8 dequant: v_cvt_pk_f32_fp8 (2 values/inst) vs ~6 VALU ops/value manual.
__global__ __launch_bounds__(256) void k_rowsum(const u8* __restrict__ Abf, float* __restrict__ S) {
  int row = blockIdx.x;
  const u8* rp = Abf + (size_t)row * NPAD;
  float s = 0.0f;
  for (int c = threadIdx.x * 16; c < NPAD; c += 256 * 16) {
    u32x4 ch = *(const u32x4*)(rp + c);
#pragma unroll
    for (int w = 0; w < 4; ++w) {
      f32x2 lo = __builtin_amdgcn_cvt_pk_f32_fp8((int)ch[w], false);
      f32x2 hi = __builtin_amdgcn_cvt_pk_f32_fp8((int)ch[w], true);
      s += (lo[0] + lo[1]) + (hi[0] + hi[1]);
    }
  }
#pragma unroll
  for (int o = 32; o > 0; o >>= 1) s += __shfl_down(s, o, 64);
  __shared__ float red[4];
  if ((threadIdx.x & 63) == 0) red[threadIdx.x >> 6] = s;
  __syncthreads();
  if (threadIdx.x == 0) S[row] = red[0] + red[1] + red[2] + red[3];
}

// partial[z] = Abf[:, zK:(z+1)K] @ hmT_all[:, zK:(z+1)K]^T  (fp8 operands, f32 acc,
// bf16 partials). XCD-swizzled flat grid. Single-barrier 3-deep ring, counted
// vmcnt(4) — stage loads stay in flight across the barrier, hidden under MFMA.
__global__ __launch_bounds__(256, 3) void k_pvsk(const u8* __restrict__ Abf, const u8* __restrict__ hmT,
                                                 u16* __restrict__ part) {
  __shared__ u8 sh8[3 * 2 * 128 * 64];   // [ring3][A/B][128][64] = 48 KB
  int lane = threadIdx.x & 63, wave = threadIdx.x >> 6;
  int bid = blockIdx.x;                  // 576 (12 dummy)
  int xcd = bid & 7, s = bid >> 3;
  int row = (s / 12) * 8 + xcd;
  if (row >= 47) return;
  int k = s % 12;
  int col0 = (k % 6) * 128, row0 = row * 128, kb = (k / 6) * (NPAD / 2);

  f32x4 acc[4][4];
  f32x4 z = {0.f, 0.f, 0.f, 0.f};
  for (int i = 0; i < 4; ++i) for (int j = 0; j < 4; ++j) acc[i][j] = z;

  const u8* Ap = Abf + (size_t)row0 * NPAD + kb;
  const u8* Bp = hmT + (size_t)col0 * NPAD + kb;
  auto pv_stage = [&](int it, u8* base) {
    stage8<128>(Ap + it * 64, NPAD, base, wave, lane);
    stage8<128>(Bp + it * 64, NPAD, base + 8192, wave, lane);
  };
  const int niter = (NPAD / 2) / 64;   // 47
  pv_stage(0, sh8);
  pv_stage(1, sh8 + 16384);
  u8* cur = sh8;                 // buffer for compute(it)
  u8* nxt = sh8 + 2 * 16384;     // buffer for stage(it+2)
  for (int it = 0; it < niter; ++it) {
    if (it == niter - 1) asm volatile("s_waitcnt vmcnt(0)" ::: "memory");
    else                 asm volatile("s_waitcnt vmcnt(4)" ::: "memory");
    __builtin_amdgcn_sched_barrier(0);
    __builtin_amdgcn_s_barrier();
    __builtin_amdgcn_sched_barrier(0);
    if (it + 2 < niter) pv_stage(it + 2, nxt);
    __builtin_amdgcn_s_setprio(1);
    mfma_step8(cur, cur + 8192, acc, lane, wave);
    __builtin_amdgcn_s_setprio(0);
    cur += 16384; if (cur == sh8 + 3 * 16384) cur = sh8;
    nxt += 16384; if (nxt == sh8 + 3 * 16384) nxt = sh8;
  }

  u16* pp = part + (size_t)(k / 6) * NPAD * (VV * HH);
  int wr = (wave >> 1) * 64, wc = (wave & 1) * 64, l15 = lane & 15, lq = lane >> 4;
#pragma unroll
  for (int i = 0; i < 4; ++i)
#pragma unroll
    for (int r = 0; r < 4; ++r) {
      int grow = row0 + wr + i * 16 + lq * 4 + r;
#pragma unroll
      for (int j = 0; j < 4; ++j) {
        int gcol = col0 + wc + j * 16 + l15;
        pp[(size_t)grow * (VV * HH) + gcol] = f2bf(acc[i][j][r]);
      }
    }
}

// newx = blend((p0+p1)/S, h); writes out_newx (f32) and nxb (bf16)
__global__ __launch_bounds__(256) void k_pvred(const u16* __restrict__ part, const float* __restrict__ S,
                                               const float* __restrict__ mT, const float* __restrict__ h,
                                               float* __restrict__ out_newx, u16* __restrict__ nxb) {
  int i = (blockIdx.x * 256 + threadIdx.x) * 4;
  int v = i / (NN * HH);
  int rem = i - v * (NN * HH);
  int n = rem / HH;
  int j = rem - n * HH;
  int col = v * HH + j;
  u16x4 p0 = *(const u16x4*)(part + (size_t)n * (VV * HH) + col);
  u16x4 p1 = *(const u16x4*)(part + (size_t)NPAD * (VV * HH) + (size_t)n * (VV * HH) + col);
  float sc = 1.0f / (S[n] + 1e-9f);
  float mrow = mT[v * NPAD + n];
  float4 o;
  o.x = (bf2f(p0[0]) + bf2f(p1[0])) * sc;
  o.y = (bf2f(p0[1]) + bf2f(p1[1])) * sc;
  o.z = (bf2f(p0[2]) + bf2f(p1[2])) * sc;
  o.w = (bf2f(p0[3]) + bf2f(p1[3])) * sc;
  if (mrow != 0.0f) o = *(const float4*)(h + (size_t)(v * NPAD + n) * HH + j);
  *(float4*)(out_newx + (size_t)(v * NN + n) * HH + j) = o;
  u16x4 ob = { f2bf(o.x), f2bf(o.y), f2bf(o.z), f2bf(o.w) };
  *(u16x4*)(nxb + (size_t)(v * NPAD + n) * HH + j) = ob;
}

// x_new = leaky(new_x @ W_out^T + b_out), nan->0  [RT=2, double-buffered]
__global__ __launch_bounds__(256, 3) void k_gemm3(const u16* __restrict__ nxb, const u16* __restrict__ woutb,
                                                  const float* __restrict__ b_out, float* __restrict__ out_xnew) {
  __shared__ u16 As[2 * 64 * 64], Bs[2 * 128 * 64];
  int lane = threadIdx.x & 63, wave = threadIdx.x >> 6;
  int col0 = blockIdx.x * 128, row0 = blockIdx.y * 64, v = blockIdx.z;
  f32x4 acc[2][4];
  f32x4 z = {0.f, 0.f, 0.f, 0.f};
  for (int i = 0; i < 2; ++i) for (int j = 0; j < 4; ++j) acc[i][j] = z;
  gemm_loop_db<2>(nxb + (size_t)(v * NPAD + row0) * HH, HH,
                  woutb + (size_t)(v * DD + col0) * HH, HH, HH, As, Bs, acc, lane, wave);
  int wr = (wave >> 1) * 32, wc = (wave & 1) * 64, l15 = lane & 15, lq = lane >> 4;
#pragma unroll
  for (int i = 0; i < 2; ++i)
#pragma unroll
    for (int r = 0; r < 4; ++r) {
      int grow = row0 + wr + i * 16 + lq * 4 + r;
      if (grow < NN) {
#pragma unroll
        for (int j = 0; j < 4; ++j) {
          int gcol = col0 + wc + j * 16 + l15;
          float val = leaky(acc[i][j][r] + b_out[v * DD + gcol]);
          if (val != val) val = 0.0f;
          out_xnew[(size_t)(v * NN + grow) * DD + gcol] = val;
        }
      }
    }
}

// y_n = sigmoid(y @ Wy^T + by)  [RT=2, double-buffered]
__global__ __launch_bounds__(256, 3) void k_ygemm(const u16* __restrict__ yb, const u16* __restrict__ wyb,
                                                  const float* __restrict__ by, float* __restrict__ out_yn) {
  __shared__ u16 As[2 * 64 * 64], Bs[2 * 128 * 64];
  int lane = threadIdx.x & 63, wave = threadIdx.x >> 6;
  int col0 = blockIdx.x * 128, row0 = blockIdx.y * 64;
  f32x4 acc[2][4];
  f32x4 z = {0.f, 0.f, 0.f, 0.f};
  for (int i = 0; i < 2; ++i) for (int j = 0; j < 4; ++j) acc[i][j] = z;
  gemm_loop_db<2>(yb + (size_t)row0 * DYY, DYY, wyb + (size_t)col0 * DYY, DYY, DYY, As, Bs, acc, lane, wave);
  int wr = (wave >> 1) * 32, wc = (wave & 1) * 64, l15 = lane & 15, lq = lane >> 4;
#pragma unroll
  for (int i = 0; i < 2; ++i)
#pragma unroll
    for (int r = 0; r < 4; ++r) {
      int grow = row0 + wr + i * 16 + lq * 4 + r;
      if (grow < NN) {
#pragma unroll
        for (int j = 0; j < 4; ++j) {
          int gcol = col0 + wc + j * 16 + l15;
          float val = acc[i][j][r] + by[gcol];
          out_yn[(size_t)grow * HH + gcol] = 1.0f / (1.0f + __expf(-val));
        }
      }
    }
}

// ---------------- launch ----------------

extern "C" void kernel_launch(void* const* d_in, const int* in_sizes, int n_in,
                              void* d_out, int out_size, void* d_ws, size_t ws_size,
                              hipStream_t stream) {
  const float* x    = (const float*)d_in[0];
  const float* y    = (const float*)d_in[1];
  const float* mask = (const float*)d_in[2];
  const float* W_in = (const float*)d_in[3];
  const float* b_in = (const float*)d_in[4];
  const float* W_out= (const float*)d_in[5];
  const float* b_out= (const float*)d_in[6];
  const float* Wy   = (const float*)d_in[7];
  const float* by   = (const float*)d_in[8];

  float* out_newx = (float*)d_out;
  float* out_xnew = out_newx + (size_t)VV * NN * HH;
  float* out_yn   = out_xnew + (size_t)VV * NN * DD;

  char* w = (char*)d_ws;
  size_t off = 0;
  auto alloc = [&](size_t bytes) -> void* {
    void* p = w + off;
    off += (bytes + 255) & ~(size_t)255;
    return p;
  };
  u16*   xb    = (u16*)alloc((size_t)VV * NPAD * DD * 2);
  u16*   yb    = (u16*)alloc((size_t)NPAD * DYY * 2);
  u16*   winb  = (u16*)alloc((size_t)VV * HH * DD * 2);
  u16*   woutb = (u16*)alloc((size_t)VV * DD * HH * 2);
  u16*   wyb   = (u16*)alloc((size_t)HH * DYY * 2);
  float* h     = (float*)alloc((size_t)VV * NPAD * HH * 4);
  u16*   qb    = (u16*)alloc((size_t)VV * NPAD * HH * 2);
  u8*    hmT   = (u8*)alloc((size_t)VV * HH * NPAD);
  u16*   nxb   = (u16*)alloc((size_t)VV * NPAD * HH * 2);
  float* mT    = (float*)alloc((size_t)VV * NPAD * 4);
  float* S     = (float*)alloc((size_t)NPAD * 4);
  u8*    Abf   = (u8*)alloc((size_t)NPAD * NPAD);
  // split-K partials (2 x NPAD x 768 bf16 = 18.48 MB) reuse xb, dead after k_gemm1
  u16*   pvp   = xb;
  (void)ws_size; (void)in_sizes; (void)n_in; (void)out_size;

  // merged conversions (4x conv + convx + mT)
  k_prep<<<(N_PREP + 255) / 256, 256, 0, stream>>>(x, y, mask, W_in, W_out, Wy,
                                                   xb, yb, winb, woutb, wyb, mT);

  // h, q, hmT
  k_gemm1<<<dim3(2, 94, 3), 256, 0, stream>>>(xb, winb, b_in, h);
  k_qprep<<<VV * NN, 256, 0, stream>>>(h, qb);
  k_hmt<<<dim3(94, 4, 3), dim3(64, 16), 0, stream>>>(h, mT, hmT);

  // attention
  k_qk<<<2256, 256, 0, stream>>>(qb, mT, Abf);
  k_rowsum<<<NN, 256, 0, stream>>>(Abf, S);
  k_pvsk<<<576, 256, 0, stream>>>(Abf, hmT, pvp);
  k_pvred<<<4500, 256, 0, stream>>>(pvp, S, mT, h, out_newx, nxb);

  // outputs
  k_gemm3<<<dim3(4, 94, 3), 256, 0, stream>>>(nxb, woutb, b_out, out_xnew);
  k_ygemm<<<dim3(2, 94), 256, 0, stream>>>(yb, wyb, by, out_yn);
}

// Round 6
// 296.499 us; speedup vs baseline: 1.1959x; 1.0221x over previous
//
#include <hip/hip_runtime.h>

#define VV 3
#define NN 6000
#define DD 512
#define HH 256
#define DYY 512
#define NPAD 6016   // 47*128
#define QK_BK 32
#define QK_BUF (192 * QK_BK)   // u16 per ring slot: A 64 rows + B 128 rows (12288 B)

typedef unsigned short u16;
typedef unsigned char u8;
typedef __bf16 bf16x8 __attribute__((ext_vector_type(8)));
typedef u16 u16x8 __attribute__((ext_vector_type(8)));
typedef float f32x4 __attribute__((ext_vector_type(4)));
typedef float f32x2 __attribute__((ext_vector_type(2)));
typedef u16 u16x4 __attribute__((ext_vector_type(4)));
typedef unsigned int u32x4 __attribute__((ext_vector_type(4)));

__device__ __forceinline__ u16 f2bf(float f) {
  unsigned int b = __builtin_bit_cast(unsigned int, f);
  b += 0x7FFFu + ((b >> 16) & 1u);
  return (u16)(b >> 16);
}
__device__ __forceinline__ float bf2f(u16 u) {
  unsigned int b = ((unsigned int)u) << 16;
  return __builtin_bit_cast(float, b);
}
// hardware OCP e4m3fn convert (RNE, saturating) — 1 inst vs ~20 for manual
__device__ __forceinline__ u8 f2fp8_hw(float f) {
  unsigned int r;
  asm("v_cvt_pk_fp8_f32 %0, %1, %2" : "=v"(r) : "v"(f), "v"(f));
  return (u8)(r & 0xffu);
}
__device__ __forceinline__ float leaky(float v) { return v >= 0.0f ? v : 0.1f * v; }

// ---- stage ROWS x DEPTH bf16 tile: global row-major (ld elems) -> LDS [ROWS][DEPTH]
template<int ROWS, int DEPTH = 64>
__device__ __forceinline__ void stage(const u16* __restrict__ g, int ld, u16* s, int wave, int lane) {
  constexpr int LPR = DEPTH / 8;   // lanes per row (16B each)
  constexpr int RPC = 64 / LPR;    // rows per chunk
  constexpr int PER = ROWS / 4;    // rows per wave
  const u16* gp = g + (wave * PER + lane / LPR) * ld + (lane % LPR) * 8;
  u16* sp = s + wave * PER * DEPTH;
#pragma unroll
  for (int ch = 0; ch < PER / RPC; ++ch) {
    __builtin_amdgcn_global_load_lds(
        (const __attribute__((address_space(1))) void*)(gp + ch * RPC * ld),
        (__attribute__((address_space(3))) void*)(sp + ch * RPC * DEPTH), 16, 0, 0);
  }
}

// ---- swizzled DEPTH=32 stage: 16B chunk c of row r lands at LDS slot c^((r>>1)&3)
// (conflict-free ds_read_b128: 8 consecutive lanes cover all 8 bank groups)
template<int ROWS>
__device__ __forceinline__ void stage_sw(const u16* __restrict__ g, int ld, u16* s, int wave, int lane) {
  constexpr int PER = ROWS / 4;    // 4 lanes/row
  int rin = lane >> 2, c = lane & 3;
#pragma unroll
  for (int ch = 0; ch < PER / 16; ++ch) {
    int rloc = wave * PER + ch * 16 + rin;
    const u16* gp = g + (size_t)rloc * ld + ((c ^ ((rloc >> 1) & 3)) << 3);
    u16* sp = s + (wave * PER + ch * 16) * 32;   // linear dest; lane at +16B*lane
    __builtin_amdgcn_global_load_lds(
        (const __attribute__((address_space(1))) void*)gp,
        (__attribute__((address_space(3))) void*)sp, 16, 0, 0);
  }
}

// ---- fp8 stage: ROWS x 64-byte rows with 16-B-chunk XOR swizzle (bank-conflict-free reads)
__device__ __forceinline__ int swz4(int r) { return (r & 3) ^ ((r >> 2) & 3); }
template<int ROWS>
__device__ __forceinline__ void stage8(const u8* __restrict__ g, int ld, u8* s, int wave, int lane) {
  constexpr int PER = ROWS / 4;    // rows per wave (4 lanes/row, 16 rows per 64-lane chunk)
  int rin = lane >> 2, c = lane & 3;
#pragma unroll
  for (int ch = 0; ch < PER / 16; ++ch) {
    int rloc = wave * PER + ch * 16 + rin;
    const u8* gp = g + (size_t)rloc * ld + ((c ^ swz4(rloc)) << 4);
    u8* sp = s + (wave * PER + ch * 16) * 64;   // wave-uniform; lane lands at +16B*lane
    __builtin_amdgcn_global_load_lds(
        (const __attribute__((address_space(1))) void*)gp,
        (__attribute__((address_space(3))) void*)sp, 16, 0, 0);
  }
}

// ---- wave computes (RT*16) x 64 outputs; block = 4 waves in 2x2 -> (RT*32) x 128 tile
template<int RT, int DEPTH = 64>
__device__ __forceinline__ void mfma_step(const u16* As, const u16* Bs, f32x4 (*acc)[4], int lane, int wave) {
  const int wr = (wave >> 1) * (RT * 16);
  const int wc = (wave & 1) * 64;
  const int l15 = lane & 15;
  const int lq = lane >> 4;
#pragma unroll
  for (int kk = 0; kk < DEPTH; kk += 32) {
    bf16x8 a[RT], b[4];
#pragma unroll
    for (int i = 0; i < RT; ++i)
      a[i] = *(const bf16x8*)(As + (wr + i * 16 + l15) * DEPTH + kk + lq * 8);
#pragma unroll
    for (int j = 0; j < 4; ++j)
      b[j] = *(const bf16x8*)(Bs + (wc + j * 16 + l15) * DEPTH + kk + lq * 8);
#pragma unroll
    for (int i = 0; i < RT; ++i)
#pragma unroll
      for (int j = 0; j < 4; ++j)
        acc[i][j] = __builtin_amdgcn_mfma_f32_16x16x32_bf16(a[i], b[j], acc[i][j], 0, 0, 0);
  }
}

// swizzled-read variant of mfma_step for DEPTH=32 (matches stage_sw layout)
__device__ __forceinline__ void mfma_step_sw(const u16* As, const u16* Bs, f32x4 (*acc)[4], int lane, int wave) {
  const int wr = (wave >> 1) * 32;
  const int wc = (wave & 1) * 64;
  const int l15 = lane & 15, lq = lane >> 4;
  bf16x8 a[2], b[4];
#pragma unroll
  for (int i = 0; i < 2; ++i) {
    int r = wr + i * 16 + l15;
    a[i] = *(const bf16x8*)(As + r * 32 + ((lq ^ ((r >> 1) & 3)) << 3));
  }
#pragma unroll
  for (int j = 0; j < 4; ++j) {
    int r = wc + j * 16 + l15;
    b[j] = *(const bf16x8*)(Bs + r * 32 + ((lq ^ ((r >> 1) & 3)) << 3));
  }
#pragma unroll
  for (int i = 0; i < 2; ++i)
#pragma unroll
    for (int j = 0; j < 4; ++j)
      acc[i][j] = __builtin_amdgcn_mfma_f32_16x16x32_bf16(a[i], b[j], acc[i][j], 0, 0, 0);
}

// fp8 MFMA step: 128x128 tile, 64 K-elems (64 B) per slice, swizzled LDS
__device__ __forceinline__ void mfma_step8(const u8* As, const u8* Bs, f32x4 (*acc)[4], int lane, int wave) {
  const int wr = (wave >> 1) * 64;
  const int wc = (wave & 1) * 64;
  const int l15 = lane & 15, lq = lane >> 4;
#pragma unroll
  for (int kk = 0; kk < 64; kk += 32) {
    long a[4], b[4];
    int gch = (kk >> 4) + (lq >> 1), half = (lq & 1) << 3;
#pragma unroll
    for (int i = 0; i < 4; ++i) {
      int r = wr + i * 16 + l15;
      a[i] = *(const long*)(As + r * 64 + ((gch ^ swz4(r)) << 4) + half);
    }
#pragma unroll
    for (int j = 0; j < 4; ++j) {
      int r = wc + j * 16 + l15;
      b[j] = *(const long*)(Bs + r * 64 + ((gch ^ swz4(r)) << 4) + half);
    }
#pragma unroll
    for (int i = 0; i < 4; ++i)
#pragma unroll
      for (int j = 0; j < 4; ++j)
        acc[i][j] = __builtin_amdgcn_mfma_f32_16x16x32_fp8_fp8(a[i], b[j], acc[i][j], 0, 0, 0);
  }
}

// double-buffered K-loop (full-drain variant, used by the dense bf16 GEMMs)
template<int RT>
__device__ __forceinline__ void gemm_loop_db(const u16* __restrict__ A, int lda,
                                             const u16* __restrict__ B, int ldb, int K,
                                             u16* As, u16* Bs, f32x4 (*acc)[4], int lane, int wave) {
  const int niter = K / 64;
  stage<RT * 32>(A, lda, As, wave, lane);
  stage<128>(B, ldb, Bs, wave, lane);
  for (int it = 0; it < niter; ++it) {
    __syncthreads();
    int nb = (it + 1) & 1;
    if (it + 1 < niter) {
      stage<RT * 32>(A + (it + 1) * 64, lda, As + nb * RT * 32 * 64, wave, lane);
      stage<128>(B + (it + 1) * 64, ldb, Bs + nb * 128 * 64, wave, lane);
    }
    int cb = it & 1;
    mfma_step<RT>(As + cb * RT * 32 * 64, Bs + cb * 128 * 64, acc, lane, wave);
  }
  __syncthreads();
}

// ---------------- merged prep kernel ----------------

__device__ __forceinline__ void conv4(const float* __restrict__ in, u16* __restrict__ out, int i) {
  float4 f = ((const float4*)in)[i];
  u16x4 o = { f2bf(f.x), f2bf(f.y), f2bf(f.z), f2bf(f.w) };
  *(u16x4*)(out + i * 4) = o;
}

#define N_WIN  (VV * HH * DD / 4)
#define N_WOUT (VV * DD * HH / 4)
#define N_WY   (HH * DYY / 4)
#define N_Y    (NN * DYY / 4)
#define N_X    (VV * NN * DD / 4)
#define N_MT   (VV * NPAD / 4)
#define N_PREP (N_WIN + N_WOUT + N_WY + N_Y + N_X + N_MT)

__global__ __launch_bounds__(256) void k_prep(const float* __restrict__ x, const float* __restrict__ y,
                                              const float* __restrict__ mask,
                                              const float* __restrict__ W_in, const float* __restrict__ W_out,
                                              const float* __restrict__ Wy,
                                              u16* __restrict__ xb, u16* __restrict__ yb,
                                              u16* __restrict__ winb, u16* __restrict__ woutb,
                                              u16* __restrict__ wyb, float* __restrict__ mT) {
  int i = blockIdx.x * 256 + threadIdx.x;
  if (i < N_X) {   // biggest segment first
    int idx = i * 4;
    int v = idx / (NN * DD);
    int rem = idx - v * (NN * DD);
    int n = rem / DD;
    int d = rem - n * DD;
    float4 f = *(const float4*)(x + idx);
    u16x4 o = { f2bf(f.x), f2bf(f.y), f2bf(f.z), f2bf(f.w) };
    *(u16x4*)(xb + (size_t)(v * NPAD + n) * DD + d) = o;
    return;
  }
  i -= N_X;
  if (i < N_Y)  { conv4(y, yb, i); return; }
  i -= N_Y;
  if (i < N_WIN) { conv4(W_in, winb, i); return; }
  i -= N_WIN;
  if (i < N_WOUT){ conv4(W_out, woutb, i); return; }
  i -= N_WOUT;
  if (i < N_WY) { conv4(Wy, wyb, i); return; }
  i -= N_WY;
  if (i < N_MT) {
#pragma unroll
    for (int t = 0; t < 4; ++t) {
      int idx = i * 4 + t;
      int v = idx / NPAD, n = idx - v * NPAD;
      mT[idx] = (n < NN) ? mask[n * VV + v] : 0.0f;
    }
  }
}

// ---------------- fused q-norm + hmT kernel (replaces k_qprep + k_hmt) ----------------
// One h pass per 64-row tile: row L2-norm -> qb (bf16), masked fp8 -> LDS tile
// -> transposed hmT write. Halves the 2x18.5 MB h read of the old pair.
__global__ __launch_bounds__(256) void k_qh(const float* __restrict__ h, const float* __restrict__ mT,
                                            u16* __restrict__ qb, u8* __restrict__ hmT) {
  __shared__ u8 t8[64][260];   // 260 = 4*65 (odd word stride -> conflict-free col reads)
  int m0 = blockIdx.x * 64, v = blockIdx.y;
  int lane = threadIdx.x & 63, wave = threadIdx.x >> 6;
#pragma unroll
  for (int rr = 0; rr < 16; ++rr) {
    int row = wave * 16 + rr;
    int m = m0 + row;
    float4 f = *(const float4*)(h + (size_t)(v * NPAD + m) * HH + lane * 4);
    float ss = f.x * f.x + f.y * f.y + f.z * f.z + f.w * f.w;
#pragma unroll
    for (int o = 32; o > 0; o >>= 1) ss += __shfl_xor(ss, o, 64);
    float inv = 1.0f / fmaxf(sqrtf(ss), 1e-12f);
    u16x4 qo = { f2bf(f.x * inv), f2bf(f.y * inv), f2bf(f.z * inv), f2bf(f.w * inv) };
    *(u16x4*)(qb + (size_t)(v * NPAD + m) * HH + lane * 4) = qo;
    float mrow = mT[v * NPAD + m];
    bool ok = (m < NN) && (mrow != 0.0f);   // m>=NN rows are garbage: force 0 (NaN*0 hazard)
    unsigned q0 = f2fp8_hw(ok ? mrow * f.x : 0.0f);
    unsigned q1 = f2fp8_hw(ok ? mrow * f.y : 0.0f);
    unsigned q2 = f2fp8_hw(ok ? mrow * f.z : 0.0f);
    unsigned q3 = f2fp8_hw(ok ? mrow * f.w : 0.0f);
    *(unsigned*)&t8[row][lane * 4] = q0 | (q1 << 8) | (q2 << 16) | (q3 << 24);
  }
  __syncthreads();
  // transposed write: hmT[v][j][m0..m0+63], u32-packed (16 threads x 4B per j-row)
  int m4 = threadIdx.x & 15, jb = threadIdx.x >> 4;
#pragma unroll
  for (int p = 0; p < 16; ++p) {
    int j = jb + p * 16;
    unsigned b0 = t8[m4 * 4 + 0][j], b1 = t8[m4 * 4 + 1][j];
    unsigned b2 = t8[m4 * 4 + 2][j], b3 = t8[m4 * 4 + 3][j];
    *(unsigned*)(hmT + (size_t)(v * HH + j) * NPAD + m0 + m4 * 4) =
        b0 | (b1 << 8) | (b2 << 16) | (b3 << 24);
  }
}

// ---------------- GEMM kernels ----------------

__global__ __launch_bounds__(256, 3) void k_gemm1(const u16* __restrict__ xb, const u16* __restrict__ winb,
                                                  const float* __restrict__ b_in, float* __restrict__ h) {
  __shared__ u16 As[2 * 64 * 64], Bs[2 * 128 * 64];
  int lane = threadIdx.x & 63, wave = threadIdx.x >> 6;
  int col0 = blockIdx.x * 128, row0 = blockIdx.y * 64, v = blockIdx.z;
  f32x4 acc[2][4];
  f32x4 z = {0.f, 0.f, 0.f, 0.f};
  for (int i = 0; i < 2; ++i) for (int j = 0; j < 4; ++j) acc[i][j] = z;
  gemm_loop_db<2>(xb + (size_t)(v * NPAD + row0) * DD, DD,
                  winb + (size_t)(v * HH + col0) * DD, DD, DD, As, Bs, acc, lane, wave);
  int wr = (wave >> 1) * 32, wc = (wave & 1) * 64, l15 = lane & 15, lq = lane >> 4;
#pragma unroll
  for (int i = 0; i < 2; ++i)
#pragma unroll
    for (int r = 0; r < 4; ++r) {
      int grow = row0 + wr + i * 16 + lq * 4 + r;
      if (grow < NN) {
#pragma unroll
        for (int j = 0; j < 4; ++j) {
          int gcol = col0 + wc + j * 16 + l15;
          h[(size_t)(v * NPAD + grow) * HH + gcol] = leaky(acc[i][j][r] + b_in[v * HH + gcol]);
        }
      }
    }
}

// A = max_v mask*exp(q_v q_v^T / beta), diag zeroed -> fp8 e4m3.
// 64x128 tile RT=2, 3-deep ring, single barrier per iter, counted vmcnt(3),
// 36 KB LDS -> 4 blocks/CU. Bijective XCD swizzle (2256 = 8*282).
__global__ __launch_bounds__(256, 4) void k_qk(const u16* __restrict__ qb, const float* __restrict__ mT,
                                               u8* __restrict__ Abf) {
  __shared__ u16 sh[3 * QK_BUF];   // 36864 B; reused for Dir/Tr in epilogue
  int lane = threadIdx.x & 63, wave = threadIdx.x >> 6;
  int bid = (blockIdx.x & 7) * 282 + (blockIdx.x >> 3);   // XCD swizzle (2256=8*282)
  int x = (int)((sqrtf((float)(4 * bid + 1)) - 1.0f) * 0.5f);
  while ((x + 1) * (x + 2) <= bid) ++x;
  while (x * (x + 1) > bid) --x;
  int y = bid - x * (x + 1);
  int col0 = x * 128, row0 = y * 64;

  const int wr = (wave >> 1) * 32, wc = (wave & 1) * 64;
  const int l15 = lane & 15, lq = lane >> 4;

  // mask bitmasks: rbm bit v*8+i*4+r = (mT[v][grow]!=0); cbm bit v*4+j
  unsigned rbm = 0, cbm = 0;
#pragma unroll
  for (int v = 0; v < VV; ++v) {
#pragma unroll
    for (int t = 0; t < 8; ++t) {
      int grow = row0 + wr + (t >> 2) * 16 + lq * 4 + (t & 3);
      if (mT[v * NPAD + grow] != 0.0f) rbm |= 1u << (v * 8 + t);
    }
#pragma unroll
    for (int j = 0; j < 4; ++j)
      if (mT[v * NPAD + col0 + wc + j * 16 + l15] != 0.0f) cbm |= 1u << (v * 4 + j);
  }
  // pin mask-load consumption here so no compiler vmcnt waits land in the loop
  asm volatile("" : "+v"(rbm), "+v"(cbm));

  f32x4 z = {0.f, 0.f, 0.f, 0.f};
  float ninf = -__builtin_inff();
  f32x4 nv = {ninf, ninf, ninf, ninf};
  f32x4 acc[2][4];
  f32x4 emax[2][4];
  for (int i = 0; i < 2; ++i)
    for (int j = 0; j < 4; ++j) { acc[i][j] = z; emax[i][j] = nv; }

  auto stage_it = [&](int it, u16* buf) {
    int v = it >> 3, k0 = (it & 7) * QK_BK;
    const u16* base = qb + (size_t)v * NPAD * HH + k0;
    stage_sw<64>(base + (size_t)row0 * HH, HH, buf, wave, lane);
    stage_sw<128>(base + (size_t)col0 * HH, HH, buf + 64 * QK_BK, wave, lane);
  };

  const int NIT = VV * (HH / QK_BK);   // 24
  stage_it(0, sh);
  stage_it(1, sh + QK_BUF);
#pragma unroll
  for (int it = 0; it < NIT; ++it) {
    if (it == NIT - 1) asm volatile("s_waitcnt vmcnt(0)" ::: "memory");
    else               asm volatile("s_waitcnt vmcnt(3)" ::: "memory");
    __builtin_amdgcn_sched_barrier(0);
    __builtin_amdgcn_s_barrier();
    __builtin_amdgcn_sched_barrier(0);
    if (it + 2 < NIT) stage_it(it + 2, sh + ((it + 2) % 3) * QK_BUF);
    const u16* cur = sh + (it % 3) * QK_BUF;
    __builtin_amdgcn_s_setprio(1);
    mfma_step_sw(cur, cur + 64 * QK_BK, acc, lane, wave);
    __builtin_amdgcn_s_setprio(0);
    if ((it & 7) == 7) {               // v complete: fold masked scores into emax
      int v = it >> 3;
#pragma unroll
      for (int i = 0; i < 2; ++i)
#pragma unroll
        for (int r = 0; r < 4; ++r) {
          bool rb = (rbm >> (v * 8 + i * 4 + r)) & 1;
#pragma unroll
          for (int j = 0; j < 4; ++j) {
            bool on = rb && ((cbm >> (v * 4 + j)) & 1);
            if (on) emax[i][j][r] = fmaxf(emax[i][j][r], acc[i][j][r]);
            acc[i][j][r] = 0.0f;
          }
        }
    }
  }
  __syncthreads();

  // epilogue: Dir [64][144] u8 (direct tile), Tr [128][80] u8 (mirror) in sh
  u8* Dir = (u8*)sh;
  u8* Tr  = (u8*)sh + 64 * 144;
#pragma unroll
  for (int i = 0; i < 2; ++i)
#pragma unroll
    for (int r = 0; r < 4; ++r) {
      int lrow = wr + i * 16 + lq * 4 + r;
      int grow = row0 + lrow;
#pragma unroll
      for (int j = 0; j < 4; ++j) {
        int lcol = wc + j * 16 + l15;
        int gcol = col0 + lcol;
        float val = __expf(emax[i][j][r] * 5.0f);
        if (grow == gcol) val = 0.0f;
        u8 q = f2fp8_hw(val);
        Dir[lrow * 144 + lcol] = q;
        Tr[lcol * 80 + lrow] = (gcol > grow) ? q : (u8)0;
      }
    }
  __syncthreads();
  if (col0 >= row0 + 64) {   // fully-upper tile: 16-B vector stores
    int c8 = threadIdx.x & 7, rr = threadIdx.x >> 3;
#pragma unroll
    for (int p = 0; p < 2; ++p) {
      int row = rr + p * 32;
      u32x4 ch = *(const u32x4*)(Dir + row * 144 + c8 * 16);
      *(u32x4*)(Abf + (size_t)(row0 + row) * NPAD + col0 + c8 * 16) = ch;
    }
    int c = threadIdx.x & 3; rr = threadIdx.x >> 2;
#pragma unroll
    for (int p = 0; p < 2; ++p) {
      int cc = rr + p * 64;
      u32x4 ch = *(const u32x4*)(Tr + cc * 80 + c * 16);
      *(u32x4*)(Abf + (size_t)(col0 + cc) * NPAD + row0 + c * 16) = ch;
    }
  } else {                    // straddle tile: predicated scalar
    for (int idx = threadIdx.x; idx < 64 * 128; idx += 256) {
      int row = idx >> 7, cc = idx & 127;
      int R = row0 + row, C = col0 + cc;
      u8 val = Dir[row * 144 + cc];
      if (C >= R) Abf[(size_t)R * NPAD + C] = val;
      if (C > R)  Abf[(size_t)C * NPAD + R] = val;
    }
  }
}

// S[n] = sum_m dequant(Abf[n][m]) — Abf holds both triangles, zero diag/pad.
__global__ __launch_bounds__(256) void k_rowsum(const u8* __restrict__ Abf, float* __restrict__ S) {
  int row = blockIdx.x;
  const u8* rp = Abf + (size_t)row * NPAD;
  float s = 0.0f;
  for (int c = threadIdx.x * 16; c < NPAD; c += 256 * 16) {
    u32x4 ch = *(const u32x4*)(rp + c);
#pragma unroll
    for (int w = 0; w < 4; ++w) {
      f32x2 lo = __builtin_amdgcn_cvt_pk_f32_fp8((int)ch[w], false);
      f32x2 hi = __builtin_amdgcn_cvt_pk_f32_fp8((int)ch[w], true);
      s += (lo[0] + lo[1]) + (hi[0] + hi[1]);
    }
  }
#pragma unroll
  for (int o = 32; o > 0; o >>= 1) s += __shfl_down(s, o, 64);
  __shared__ float red[4];
  if ((threadIdx.x & 63) == 0) red[threadIdx.x >> 6] = s;
  __syncthreads();
  if (threadIdx.x == 0) S[row] = red[0] + red[1] + red[2] + red[3];
}

// partial[z] = Abf[:, zK:(z+1)K] @ hmT_all[:, zK:(z+1)K]^T  (fp8 operands, f32 acc,
// bf16 partials). XCD-swizzled flat grid. Single-barrier 3-deep ring, counted
// vmcnt(4) — stage loads stay in flight across the barrier, hidden under MFMA.
__global__ __launch_bounds__(256, 3) void k_pvsk(const u8* __restrict__ Abf, const u8* __restrict__ hmT,
                                                 u16* __restrict__ part) {
  __shared__ u8 sh8[3 * 2 * 128 * 64];   // [ring3][A/B][128][64] = 48 KB
  int lane = threadIdx.x & 63, wave = threadIdx.x >> 6;
  int bid = blockIdx.x;                  // 576 (12 dummy)
  int xcd = bid & 7, s = bid >> 3;
  int row = (s / 12) * 8 + xcd;
  if (row >= 47) return;
  int k = s % 12;
  int col0 = (k % 6) * 128, row0 = row * 128, kb = (k / 6) * (NPAD / 2);

  f32x4 acc[4][4];
  f32x4 z = {0.f, 0.f, 0.f, 0.f};
  for (int i = 0; i < 4; ++i) for (int j = 0; j < 4; ++j) acc[i][j] = z;

  const u8* Ap = Abf + (size_t)row0 * NPAD + kb;
  const u8* Bp = hmT + (size_t)col0 * NPAD + kb;
  auto pv_stage = [&](int it, u8* base) {
    stage8<128>(Ap + it * 64, NPAD, base, wave, lane);
    stage8<128>(Bp + it * 64, NPAD, base + 8192, wave, lane);
  };
  const int niter = (NPAD / 2) / 64;   // 47
  pv_stage(0, sh8);
  pv_stage(1, sh8 + 16384);
  u8* cur = sh8;                 // buffer for compute(it)
  u8* nxt = sh8 + 2 * 16384;     // buffer for stage(it+2)
  for (int it = 0; it < niter; ++it) {
    if (it == niter - 1) asm volatile("s_waitcnt vmcnt(0)" ::: "memory");
    else                 asm volatile("s_waitcnt vmcnt(4)" ::: "memory");
    __builtin_amdgcn_sched_barrier(0);
    __builtin_amdgcn_s_barrier();
    __builtin_amdgcn_sched_barrier(0);
    if (it + 2 < niter) pv_stage(it + 2, nxt);
    __builtin_amdgcn_s_setprio(1);
    mfma_step8(cur, cur + 8192, acc, lane, wave);
    __builtin_amdgcn_s_setprio(0);
    cur += 16384; if (cur == sh8 + 3 * 16384) cur = sh8;
    nxt += 16384; if (nxt == sh8 + 3 * 16384) nxt = sh8;
  }

  u16* pp = part + (size_t)(k / 6) * NPAD * (VV * HH);
  int wr = (wave >> 1) * 64, wc = (wave & 1) * 64, l15 = lane & 15, lq = lane >> 4;
#pragma unroll
  for (int i = 0; i < 4; ++i)
#pragma unroll
    for (int r = 0; r < 4; ++r) {
      int grow = row0 + wr + i * 16 + lq * 4 + r;
#pragma unroll
      for (int j = 0; j < 4; ++j) {
        int gcol = col0 + wc + j * 16 + l15;
        pp[(size_t)grow * (VV * HH) + gcol] = f2bf(acc[i][j][r]);
      }
    }
}

// newx = blend((p0+p1)/S, h); writes out_newx (f32) and nxb (bf16)
__global__ __launch_bounds__(256) void k_pvred(const u16* __restrict__ part, const float* __restrict__ S,
                                               const float* __restrict__ mT, const float* __restrict__ h,
                                               float* __restrict__ out_newx, u16* __restrict__ nxb) {
  int i = (blockIdx.x * 256 + threadIdx.x) * 4;
  int v = i / (NN * HH);
  int rem = i - v * (NN * HH);
  int n = rem / HH;
  int j = rem - n * HH;
  int col = v * HH + j;
  u16x4 p0 = *(const u16x4*)(part + (size_t)n * (VV * HH) + col);
  u16x4 p1 = *(const u16x4*)(part + (size_t)NPAD * (VV * HH) + (size_t)n * (VV * HH) + col);
  float sc = 1.0f / (S[n] + 1e-9f);
  float mrow = mT[v * NPAD + n];
  float4 o;
  o.x = (bf2f(p0[0]) + bf2f(p1[0])) * sc;
  o.y = (bf2f(p0[1]) + bf2f(p1[1])) * sc;
  o.z = (bf2f(p0[2]) + bf2f(p1[2])) * sc;
  o.w = (bf2f(p0[3]) + bf2f(p1[3])) * sc;
  if (mrow != 0.0f) o = *(const float4*)(h + (size_t)(v * NPAD + n) * HH + j);
  *(float4*)(out_newx + (size_t)(v * NN + n) * HH + j) = o;
  u16x4 ob = { f2bf(o.x), f2bf(o.y), f2bf(o.z), f2bf(o.w) };
  *(u16x4*)(nxb + (size_t)(v * NPAD + n) * HH + j) = ob;
}

// x_new = leaky(new_x @ W_out^T + b_out), nan->0  [RT=2, double-buffered]
__global__ __launch_bounds__(256, 3) void k_gemm3(const u16* __restrict__ nxb, const u16* __restrict__ woutb,
                                                  const float* __restrict__ b_out, float* __restrict__ out_xnew) {
  __shared__ u16 As[2 * 64 * 64], Bs[2 * 128 * 64];
  int lane = threadIdx.x & 63, wave = threadIdx.x >> 6;
  int col0 = blockIdx.x * 128, row0 = blockIdx.y * 64, v = blockIdx.z;
  f32x4 acc[2][4];
  f32x4 z = {0.f, 0.f, 0.f, 0.f};
  for (int i = 0; i < 2; ++i) for (int j = 0; j < 4; ++j) acc[i][j] = z;
  gemm_loop_db<2>(nxb + (size_t)(v * NPAD + row0) * HH, HH,
                  woutb + (size_t)(v * DD + col0) * HH, HH, HH, As, Bs, acc, lane, wave);
  int wr = (wave >> 1) * 32, wc = (wave & 1) * 64, l15 = lane & 15, lq = lane >> 4;
#pragma unroll
  for (int i = 0; i < 2; ++i)
#pragma unroll
    for (int r = 0; r < 4; ++r) {
      int grow = row0 + wr + i * 16 + lq * 4 + r;
      if (grow < NN) {
#pragma unroll
        for (int j = 0; j < 4; ++j) {
          int gcol = col0 + wc + j * 16 + l15;
          float val = leaky(acc[i][j][r] + b_out[v * DD + gcol]);
          if (val != val) val = 0.0f;
          out_xnew[(size_t)(v * NN + grow) * DD + gcol] = val;
        }
      }
    }
}

// y_n = sigmoid(y @ Wy^T + by)  [RT=1: 32-row tiles -> 376 blocks, fills the chip]
__global__ __launch_bounds__(256, 3) void k_ygemm(const u16* __restrict__ yb, const u16* __restrict__ wyb,
                                                  const float* __restrict__ by, float* __restrict__ out_yn) {
  __shared__ u16 As[2 * 32 * 64], Bs[2 * 128 * 64];
  int lane = threadIdx.x & 63, wave = threadIdx.x >> 6;
  int col0 = blockIdx.x * 128, row0 = blockIdx.y * 32;
  f32x4 acc[1][4];
  f32x4 z = {0.f, 0.f, 0.f, 0.f};
  for (int j = 0; j < 4; ++j) acc[0][j] = z;
  gemm_loop_db<1>(yb + (size_t)row0 * DYY, DYY, wyb + (size_t)col0 * DYY, DYY, DYY, As, Bs, acc, lane, wave);
  int wr = (wave >> 1) * 16, wc = (wave & 1) * 64, l15 = lane & 15, lq = lane >> 4;
#pragma unroll
  for (int r = 0; r < 4; ++r) {
    int grow = row0 + wr + lq * 4 + r;
    if (grow < NN) {
#pragma unroll
      for (int j = 0; j < 4; ++j) {
        int gcol = col0 + wc + j * 16 + l15;
        float val = acc[0][j][r] + by[gcol];
        out_yn[(size_t)grow * HH + gcol] = 1.0f / (1.0f + __expf(-val));
      }
    }
  }
}

// ---------------- launch ----------------

extern "C" void kernel_launch(void* const* d_in, const int* in_sizes, int n_in,
                              void* d_out, int out_size, void* d_ws, size_t ws_size,
                              hipStream_t stream) {
  const float* x    = (const float*)d_in[0];
  const float* y    = (const float*)d_in[1];
  const float* mask = (const float*)d_in[2];
  const float* W_in = (const float*)d_in[3];
  const float* b_in = (const float*)d_in[4];
  const float* W_out= (const float*)d_in[5];
  const float* b_out= (const float*)d_in[6];
  const float* Wy   = (const float*)d_in[7];
  const float* by   = (const float*)d_in[8];

  float* out_newx = (float*)d_out;
  float* out_xnew = out_newx + (size_t)VV * NN * HH;
  float* out_yn   = out_xnew + (size_t)VV * NN * DD;

  char* w = (char*)d_ws;
  size_t off = 0;
  auto alloc = [&](size_t bytes) -> void* {
    void* p = w + off;
    off += (bytes + 255) & ~(size_t)255;
    return p;
  };
  u16*   xb    = (u16*)alloc((size_t)VV * NPAD * DD * 2);
  u16*   yb    = (u16*)alloc((size_t)NPAD * DYY * 2);
  u16*   winb  = (u16*)alloc((size_t)VV * HH * DD * 2);
  u16*   woutb = (u16*)alloc((size_t)VV * DD * HH * 2);
  u16*   wyb   = (u16*)alloc((size_t)HH * DYY * 2);
  float* h     = (float*)alloc((size_t)VV * NPAD * HH * 4);
  u16*   qb    = (u16*)alloc((size_t)VV * NPAD * HH * 2);
  u8*    hmT   = (u8*)alloc((size_t)VV * HH * NPAD);
  u16*   nxb   = (u16*)alloc((size_t)VV * NPAD * HH * 2);
  float* mT    = (float*)alloc((size_t)VV * NPAD * 4);
  float* S     = (float*)alloc((size_t)NPAD * 4);
  u8*    Abf   = (u8*)alloc((size_t)NPAD * NPAD);
  // split-K partials (2 x NPAD x 768 bf16 = 18.48 MB) reuse xb, dead after k_gemm1
  u16*   pvp   = xb;
  (void)ws_size; (void)in_sizes; (void)n_in; (void)out_size;

  // merged conversions (4x conv + convx + mT)
  k_prep<<<(N_PREP + 255) / 256, 256, 0, stream>>>(x, y, mask, W_in, W_out, Wy,
                                                   xb, yb, winb, woutb, wyb, mT);

  // h, then fused q-norm + hmT
  k_gemm1<<<dim3(2, 94, 3), 256, 0, stream>>>(xb, winb, b_in, h);
  k_qh<<<dim3(94, 3), 256, 0, stream>>>(h, mT, qb, hmT);

  // attention
  k_qk<<<2256, 256, 0, stream>>>(qb, mT, Abf);
  k_rowsum<<<NN, 256, 0, stream>>>(Abf, S);
  k_pvsk<<<576, 256, 0, stream>>>(Abf, hmT, pvp);
  k_pvred<<<4500, 256, 0, stream>>>(pvp, S, mT, h, out_newx, nxb);

  // outputs
  k_gemm3<<<dim3(4, 94, 3), 256, 0, stream>>>(nxb, woutb, b_out, out_xnew);
  k_ygemm<<<dim3(2, 188), 256, 0, stream>>>(yb, wyb, by, out_yn);
}

// Round 7
// 277.643 us; speedup vs baseline: 1.2771x; 1.0679x over previous
//
#include <hip/hip_runtime.h>

#define VV 3
#define NN 6000
#define DD 512
#define HH 256
#define DYY 512
#define NPAD 6016   // 47*128
#define QK_BK 32
#define QK_BUF (192 * QK_BK)   // u16 per ring slot: A 64 rows + B 128 rows (12288 B)

typedef unsigned short u16;
typedef unsigned char u8;
typedef __bf16 bf16x8 __attribute__((ext_vector_type(8)));
typedef u16 u16x8 __attribute__((ext_vector_type(8)));
typedef float f32x4 __attribute__((ext_vector_type(4)));
typedef float f32x2 __attribute__((ext_vector_type(2)));
typedef u16 u16x4 __attribute__((ext_vector_type(4)));
typedef unsigned int u32x4 __attribute__((ext_vector_type(4)));

__device__ __forceinline__ u16 f2bf(float f) {
  unsigned int b = __builtin_bit_cast(unsigned int, f);
  b += 0x7FFFu + ((b >> 16) & 1u);
  return (u16)(b >> 16);
}
__device__ __forceinline__ float bf2f(u16 u) {
  unsigned int b = ((unsigned int)u) << 16;
  return __builtin_bit_cast(float, b);
}
// hardware OCP e4m3fn convert (RNE, saturating) — 1 inst vs ~20 for manual
__device__ __forceinline__ u8 f2fp8_hw(float f) {
  unsigned int r;
  asm("v_cvt_pk_fp8_f32 %0, %1, %2" : "=v"(r) : "v"(f), "v"(f));
  return (u8)(r & 0xffu);
}
__device__ __forceinline__ float leaky(float v) { return v >= 0.0f ? v : 0.1f * v; }

// ---- swizzled DEPTH=32 stage: 16B chunk c of row r lands at LDS slot c^((r>>1)&3)
// (conflict-free ds_read_b128: 8 consecutive lanes cover all 8 bank groups)
template<int ROWS>
__device__ __forceinline__ void stage_sw(const u16* __restrict__ g, int ld, u16* s, int wave, int lane) {
  constexpr int PER = ROWS / 4;    // 4 lanes/row
  int rin = lane >> 2, c = lane & 3;
#pragma unroll
  for (int ch = 0; ch < PER / 16; ++ch) {
    int rloc = wave * PER + ch * 16 + rin;
    const u16* gp = g + (size_t)rloc * ld + ((c ^ ((rloc >> 1) & 3)) << 3);
    u16* sp = s + (wave * PER + ch * 16) * 32;   // linear dest; lane at +16B*lane
    __builtin_amdgcn_global_load_lds(
        (const __attribute__((address_space(1))) void*)gp,
        (__attribute__((address_space(3))) void*)sp, 16, 0, 0);
  }
}

// ---- fp8 stage: ROWS x 64-byte rows with 16-B-chunk XOR swizzle (bank-conflict-free reads)
__device__ __forceinline__ int swz4(int r) { return (r & 3) ^ ((r >> 2) & 3); }
template<int ROWS>
__device__ __forceinline__ void stage8(const u8* __restrict__ g, int ld, u8* s, int wave, int lane) {
  constexpr int PER = ROWS / 4;    // rows per wave (4 lanes/row, 16 rows per 64-lane chunk)
  int rin = lane >> 2, c = lane & 3;
#pragma unroll
  for (int ch = 0; ch < PER / 16; ++ch) {
    int rloc = wave * PER + ch * 16 + rin;
    const u8* gp = g + (size_t)rloc * ld + ((c ^ swz4(rloc)) << 4);
    u8* sp = s + (wave * PER + ch * 16) * 64;   // wave-uniform; lane lands at +16B*lane
    __builtin_amdgcn_global_load_lds(
        (const __attribute__((address_space(1))) void*)gp,
        (__attribute__((address_space(3))) void*)sp, 16, 0, 0);
  }
}

// swizzled-read MFMA step, DEPTH=32 (matches stage_sw layout): 64x128 block tile
__device__ __forceinline__ void mfma_step_sw(const u16* As, const u16* Bs, f32x4 (*acc)[4], int lane, int wave) {
  const int wr = (wave >> 1) * 32;
  const int wc = (wave & 1) * 64;
  const int l15 = lane & 15, lq = lane >> 4;
  bf16x8 a[2], b[4];
#pragma unroll
  for (int i = 0; i < 2; ++i) {
    int r = wr + i * 16 + l15;
    a[i] = *(const bf16x8*)(As + r * 32 + ((lq ^ ((r >> 1) & 3)) << 3));
  }
#pragma unroll
  for (int j = 0; j < 4; ++j) {
    int r = wc + j * 16 + l15;
    b[j] = *(const bf16x8*)(Bs + r * 32 + ((lq ^ ((r >> 1) & 3)) << 3));
  }
#pragma unroll
  for (int i = 0; i < 2; ++i)
#pragma unroll
    for (int j = 0; j < 4; ++j)
      acc[i][j] = __builtin_amdgcn_mfma_f32_16x16x32_bf16(a[i], b[j], acc[i][j], 0, 0, 0);
}

// fp8 MFMA step: 128x128 tile, 64 K-elems (64 B) per slice, swizzled LDS
__device__ __forceinline__ void mfma_step8(const u8* As, const u8* Bs, f32x4 (*acc)[4], int lane, int wave) {
  const int wr = (wave >> 1) * 64;
  const int wc = (wave & 1) * 64;
  const int l15 = lane & 15, lq = lane >> 4;
#pragma unroll
  for (int kk = 0; kk < 64; kk += 32) {
    long a[4], b[4];
    int gch = (kk >> 4) + (lq >> 1), half = (lq & 1) << 3;
#pragma unroll
    for (int i = 0; i < 4; ++i) {
      int r = wr + i * 16 + l15;
      a[i] = *(const long*)(As + r * 64 + ((gch ^ swz4(r)) << 4) + half);
    }
#pragma unroll
    for (int j = 0; j < 4; ++j) {
      int r = wc + j * 16 + l15;
      b[j] = *(const long*)(Bs + r * 64 + ((gch ^ swz4(r)) << 4) + half);
    }
#pragma unroll
    for (int i = 0; i < 4; ++i)
#pragma unroll
      for (int j = 0; j < 4; ++j)
        acc[i][j] = __builtin_amdgcn_mfma_f32_16x16x32_fp8_fp8(a[i], b[j], acc[i][j], 0, 0, 0);
  }
}

// ring-3 single-barrier counted-vmcnt bf16 K-loop (k_qk-proven structure).
// Per stage: 3 global_load_lds/wave (A 64 rows: 1, B 128 rows: 2) -> vmcnt(3)
// means "stage(it) done, stage(it+1) in flight". 36864 B LDS -> 4 blocks/CU.
__device__ __forceinline__ void gemm_loop_r3(const u16* __restrict__ A, int lda,
                                             const u16* __restrict__ B, int ldb, int K,
                                             u16* sh, f32x4 (*acc)[4], int lane, int wave) {
  const int niter = K / 32;
  auto st = [&](int it, u16* buf) {
    stage_sw<64>(A + it * 32, lda, buf, wave, lane);
    stage_sw<128>(B + it * 32, ldb, buf + 64 * 32, wave, lane);
  };
  st(0, sh);
  st(1, sh + QK_BUF);
  for (int it = 0; it < niter; ++it) {
    if (it == niter - 1) asm volatile("s_waitcnt vmcnt(0)" ::: "memory");
    else                 asm volatile("s_waitcnt vmcnt(3)" ::: "memory");
    __builtin_amdgcn_sched_barrier(0);
    __builtin_amdgcn_s_barrier();
    __builtin_amdgcn_sched_barrier(0);
    if (it + 2 < niter) st(it + 2, sh + ((it + 2) % 3) * QK_BUF);
    const u16* cur = sh + (it % 3) * QK_BUF;
    __builtin_amdgcn_s_setprio(1);
    mfma_step_sw(cur, cur + 64 * 32, acc, lane, wave);
    __builtin_amdgcn_s_setprio(0);
  }
  __syncthreads();
}

// ---------------- merged prep kernel ----------------

__device__ __forceinline__ void conv4(const float* __restrict__ in, u16* __restrict__ out, int i) {
  float4 f = ((const float4*)in)[i];
  u16x4 o = { f2bf(f.x), f2bf(f.y), f2bf(f.z), f2bf(f.w) };
  *(u16x4*)(out + i * 4) = o;
}

#define N_WIN  (VV * HH * DD / 4)
#define N_WOUT (VV * DD * HH / 4)
#define N_WY   (HH * DYY / 4)
#define N_Y    (NN * DYY / 4)
#define N_X    (VV * NN * DD / 4)
#define N_MT   (VV * NPAD / 4)
#define N_PREP (N_WIN + N_WOUT + N_WY + N_Y + N_X + N_MT)

__global__ __launch_bounds__(256) void k_prep(const float* __restrict__ x, const float* __restrict__ y,
                                              const float* __restrict__ mask,
                                              const float* __restrict__ W_in, const float* __restrict__ W_out,
                                              const float* __restrict__ Wy,
                                              u16* __restrict__ xb, u16* __restrict__ yb,
                                              u16* __restrict__ winb, u16* __restrict__ woutb,
                                              u16* __restrict__ wyb, float* __restrict__ mT) {
  int i = blockIdx.x * 256 + threadIdx.x;
  if (i < N_X) {   // biggest segment first
    int idx = i * 4;
    int v = idx / (NN * DD);
    int rem = idx - v * (NN * DD);
    int n = rem / DD;
    int d = rem - n * DD;
    float4 f = *(const float4*)(x + idx);
    u16x4 o = { f2bf(f.x), f2bf(f.y), f2bf(f.z), f2bf(f.w) };
    *(u16x4*)(xb + (size_t)(v * NPAD + n) * DD + d) = o;
    return;
  }
  i -= N_X;
  if (i < N_Y)  { conv4(y, yb, i); return; }
  i -= N_Y;
  if (i < N_WIN) { conv4(W_in, winb, i); return; }
  i -= N_WIN;
  if (i < N_WOUT){ conv4(W_out, woutb, i); return; }
  i -= N_WOUT;
  if (i < N_WY) { conv4(Wy, wyb, i); return; }
  i -= N_WY;
  if (i < N_MT) {
#pragma unroll
    for (int t = 0; t < 4; ++t) {
      int idx = i * 4 + t;
      int v = idx / NPAD, n = idx - v * NPAD;
      mT[idx] = (n < NN) ? mask[n * VV + v] : 0.0f;
    }
  }
}

// ---------------- fused q-norm + hmT kernel ----------------
// One h pass per 64-row tile: row L2-norm -> qb (bf16), masked fp8 -> LDS tile
// -> transposed hmT write.
__global__ __launch_bounds__(256) void k_qh(const float* __restrict__ h, const float* __restrict__ mT,
                                            u16* __restrict__ qb, u8* __restrict__ hmT) {
  __shared__ u8 t8[64][260];   // 260 = 4*65 (odd word stride -> conflict-free col reads)
  int m0 = blockIdx.x * 64, v = blockIdx.y;
  int lane = threadIdx.x & 63, wave = threadIdx.x >> 6;
#pragma unroll
  for (int rr = 0; rr < 16; ++rr) {
    int row = wave * 16 + rr;
    int m = m0 + row;
    float4 f = *(const float4*)(h + (size_t)(v * NPAD + m) * HH + lane * 4);
    float ss = f.x * f.x + f.y * f.y + f.z * f.z + f.w * f.w;
#pragma unroll
    for (int o = 32; o > 0; o >>= 1) ss += __shfl_xor(ss, o, 64);
    float inv = 1.0f / fmaxf(sqrtf(ss), 1e-12f);
    u16x4 qo = { f2bf(f.x * inv), f2bf(f.y * inv), f2bf(f.z * inv), f2bf(f.w * inv) };
    *(u16x4*)(qb + (size_t)(v * NPAD + m) * HH + lane * 4) = qo;
    float mrow = mT[v * NPAD + m];
    bool ok = (m < NN) && (mrow != 0.0f);   // m>=NN rows are garbage: force 0 (NaN*0 hazard)
    unsigned q0 = f2fp8_hw(ok ? mrow * f.x : 0.0f);
    unsigned q1 = f2fp8_hw(ok ? mrow * f.y : 0.0f);
    unsigned q2 = f2fp8_hw(ok ? mrow * f.z : 0.0f);
    unsigned q3 = f2fp8_hw(ok ? mrow * f.w : 0.0f);
    *(unsigned*)&t8[row][lane * 4] = q0 | (q1 << 8) | (q2 << 16) | (q3 << 24);
  }
  __syncthreads();
  // transposed write: hmT[v][j][m0..m0+63], u32-packed (16 threads x 4B per j-row)
  int m4 = threadIdx.x & 15, jb = threadIdx.x >> 4;
#pragma unroll
  for (int p = 0; p < 16; ++p) {
    int j = jb + p * 16;
    unsigned b0 = t8[m4 * 4 + 0][j], b1 = t8[m4 * 4 + 1][j];
    unsigned b2 = t8[m4 * 4 + 2][j], b3 = t8[m4 * 4 + 3][j];
    *(unsigned*)(hmT + (size_t)(v * HH + j) * NPAD + m0 + m4 * 4) =
        b0 | (b1 << 8) | (b2 << 16) | (b3 << 24);
  }
}

// ---------------- GEMM kernels ----------------

// h = leaky(x @ W_in^T + b_in)  [ring-3 counted-vmcnt loop]
__global__ __launch_bounds__(256, 4) void k_gemm1(const u16* __restrict__ xb, const u16* __restrict__ winb,
                                                  const float* __restrict__ b_in, float* __restrict__ h) {
  __shared__ u16 sh[3 * QK_BUF];
  int lane = threadIdx.x & 63, wave = threadIdx.x >> 6;
  int col0 = blockIdx.x * 128, row0 = blockIdx.y * 64, v = blockIdx.z;
  f32x4 acc[2][4];
  f32x4 z = {0.f, 0.f, 0.f, 0.f};
  for (int i = 0; i < 2; ++i) for (int j = 0; j < 4; ++j) acc[i][j] = z;
  gemm_loop_r3(xb + (size_t)(v * NPAD + row0) * DD, DD,
               winb + (size_t)(v * HH + col0) * DD, DD, DD, sh, acc, lane, wave);
  int wr = (wave >> 1) * 32, wc = (wave & 1) * 64, l15 = lane & 15, lq = lane >> 4;
#pragma unroll
  for (int i = 0; i < 2; ++i)
#pragma unroll
    for (int r = 0; r < 4; ++r) {
      int grow = row0 + wr + i * 16 + lq * 4 + r;
      if (grow < NN) {
#pragma unroll
        for (int j = 0; j < 4; ++j) {
          int gcol = col0 + wc + j * 16 + l15;
          h[(size_t)(v * NPAD + grow) * HH + gcol] = leaky(acc[i][j][r] + b_in[v * HH + gcol]);
        }
      }
    }
}

// A = max_v mask*exp(q_v q_v^T / beta), diag zeroed -> fp8 e4m3.
// 64x128 tile RT=2, 3-deep ring, single barrier per iter, counted vmcnt(3),
// 36 KB LDS -> 4 blocks/CU. Bijective XCD swizzle (2256 = 8*282).
__global__ __launch_bounds__(256, 4) void k_qk(const u16* __restrict__ qb, const float* __restrict__ mT,
                                               u8* __restrict__ Abf) {
  __shared__ u16 sh[3 * QK_BUF];   // 36864 B; reused for Dir/Tr in epilogue
  int lane = threadIdx.x & 63, wave = threadIdx.x >> 6;
  int bid = (blockIdx.x & 7) * 282 + (blockIdx.x >> 3);   // XCD swizzle (2256=8*282)
  int x = (int)((sqrtf((float)(4 * bid + 1)) - 1.0f) * 0.5f);
  while ((x + 1) * (x + 2) <= bid) ++x;
  while (x * (x + 1) > bid) --x;
  int y = bid - x * (x + 1);
  int col0 = x * 128, row0 = y * 64;

  const int wr = (wave >> 1) * 32, wc = (wave & 1) * 64;
  const int l15 = lane & 15, lq = lane >> 4;

  // mask bitmasks: rbm bit v*8+i*4+r = (mT[v][grow]!=0); cbm bit v*4+j
  unsigned rbm = 0, cbm = 0;
#pragma unroll
  for (int v = 0; v < VV; ++v) {
#pragma unroll
    for (int t = 0; t < 8; ++t) {
      int grow = row0 + wr + (t >> 2) * 16 + lq * 4 + (t & 3);
      if (mT[v * NPAD + grow] != 0.0f) rbm |= 1u << (v * 8 + t);
    }
#pragma unroll
    for (int j = 0; j < 4; ++j)
      if (mT[v * NPAD + col0 + wc + j * 16 + l15] != 0.0f) cbm |= 1u << (v * 4 + j);
  }
  // pin mask-load consumption here so no compiler vmcnt waits land in the loop
  asm volatile("" : "+v"(rbm), "+v"(cbm));

  f32x4 z = {0.f, 0.f, 0.f, 0.f};
  float ninf = -__builtin_inff();
  f32x4 nv = {ninf, ninf, ninf, ninf};
  f32x4 acc[2][4];
  f32x4 emax[2][4];
  for (int i = 0; i < 2; ++i)
    for (int j = 0; j < 4; ++j) { acc[i][j] = z; emax[i][j] = nv; }

  auto stage_it = [&](int it, u16* buf) {
    int v = it >> 3, k0 = (it & 7) * QK_BK;
    const u16* base = qb + (size_t)v * NPAD * HH + k0;
    stage_sw<64>(base + (size_t)row0 * HH, HH, buf, wave, lane);
    stage_sw<128>(base + (size_t)col0 * HH, HH, buf + 64 * QK_BK, wave, lane);
  };

  const int NIT = VV * (HH / QK_BK);   // 24
  stage_it(0, sh);
  stage_it(1, sh + QK_BUF);
#pragma unroll
  for (int it = 0; it < NIT; ++it) {
    if (it == NIT - 1) asm volatile("s_waitcnt vmcnt(0)" ::: "memory");
    else               asm volatile("s_waitcnt vmcnt(3)" ::: "memory");
    __builtin_amdgcn_sched_barrier(0);
    __builtin_amdgcn_s_barrier();
    __builtin_amdgcn_sched_barrier(0);
    if (it + 2 < NIT) stage_it(it + 2, sh + ((it + 2) % 3) * QK_BUF);
    const u16* cur = sh + (it % 3) * QK_BUF;
    __builtin_amdgcn_s_setprio(1);
    mfma_step_sw(cur, cur + 64 * QK_BK, acc, lane, wave);
    __builtin_amdgcn_s_setprio(0);
    if ((it & 7) == 7) {               // v complete: fold masked scores into emax
      int v = it >> 3;
#pragma unroll
      for (int i = 0; i < 2; ++i)
#pragma unroll
        for (int r = 0; r < 4; ++r) {
          bool rb = (rbm >> (v * 8 + i * 4 + r)) & 1;
#pragma unroll
          for (int j = 0; j < 4; ++j) {
            bool on = rb && ((cbm >> (v * 4 + j)) & 1);
            if (on) emax[i][j][r] = fmaxf(emax[i][j][r], acc[i][j][r]);
            acc[i][j][r] = 0.0f;
          }
        }
    }
  }
  __syncthreads();

  // epilogue: Dir [64][144] u8 (direct tile), Tr [128][80] u8 (mirror) in sh
  u8* Dir = (u8*)sh;
  u8* Tr  = (u8*)sh + 64 * 144;
#pragma unroll
  for (int i = 0; i < 2; ++i)
#pragma unroll
    for (int r = 0; r < 4; ++r) {
      int lrow = wr + i * 16 + lq * 4 + r;
      int grow = row0 + lrow;
#pragma unroll
      for (int j = 0; j < 4; ++j) {
        int lcol = wc + j * 16 + l15;
        int gcol = col0 + lcol;
        float val = __expf(emax[i][j][r] * 5.0f);
        if (grow == gcol) val = 0.0f;
        u8 q = f2fp8_hw(val);
        Dir[lrow * 144 + lcol] = q;
        Tr[lcol * 80 + lrow] = (gcol > grow) ? q : (u8)0;
      }
    }
  __syncthreads();
  if (col0 >= row0 + 64) {   // fully-upper tile: 16-B vector stores
    int c8 = threadIdx.x & 7, rr = threadIdx.x >> 3;
#pragma unroll
    for (int p = 0; p < 2; ++p) {
      int row = rr + p * 32;
      u32x4 ch = *(const u32x4*)(Dir + row * 144 + c8 * 16);
      *(u32x4*)(Abf + (size_t)(row0 + row) * NPAD + col0 + c8 * 16) = ch;
    }
    int c = threadIdx.x & 3; rr = threadIdx.x >> 2;
#pragma unroll
    for (int p = 0; p < 2; ++p) {
      int cc = rr + p * 64;
      u32x4 ch = *(const u32x4*)(Tr + cc * 80 + c * 16);
      *(u32x4*)(Abf + (size_t)(col0 + cc) * NPAD + row0 + c * 16) = ch;
    }
  } else {                    // straddle tile: predicated scalar
    for (int idx = threadIdx.x; idx < 64 * 128; idx += 256) {
      int row = idx >> 7, cc = idx & 127;
      int R = row0 + row, C = col0 + cc;
      u8 val = Dir[row * 144 + cc];
      if (C >= R) Abf[(size_t)R * NPAD + C] = val;
      if (C > R)  Abf[(size_t)C * NPAD + R] = val;
    }
  }
}

// S[n] = sum_m dequant(Abf[n][m]) — Abf holds both triangles, zero diag/pad.
__global__ __launch_bounds__(256) void k_rowsum(const u8* __restrict__ Abf, float* __restrict__ S) {
  int row = blockIdx.x;
  const u8* rp = Abf + (size_t)row * NPAD;
  float s = 0.0f;
  for (int c = threadIdx.x * 16; c < NPAD; c += 256 * 16) {
    u32x4 ch = *(const u32x4*)(rp + c);
#pragma unroll
    for (int w = 0; w < 4; ++w) {
      f32x2 lo = __builtin_amdgcn_cvt_pk_f32_fp8((int)ch[w], false);
      f32x2 hi = __builtin_amdgcn_cvt_pk_f32_fp8((int)ch[w], true);
      s += (lo[0] + lo[1]) + (hi[0] + hi[1]);
    }
  }
#pragma unroll
  for (int o = 32; o > 0; o >>= 1) s += __shfl_down(s, o, 64);
  __shared__ float red[4];
  if ((threadIdx.x & 63) == 0) red[threadIdx.x >> 6] = s;
  __syncthreads();
  if (threadIdx.x == 0) S[row] = red[0] + red[1] + red[2] + red[3];
}

// partial[z] = Abf[:, zK:(z+1)K] @ hmT_all[:, zK:(z+1)K]^T  (fp8 operands, f32 acc,
// bf16 partials). XCD-swizzled flat grid. Single-barrier 3-deep ring, counted
// vmcnt(4) — stage loads stay in flight across the barrier, hidden under MFMA.
__global__ __launch_bounds__(256, 3) void k_pvsk(const u8* __restrict__ Abf, const u8* __restrict__ hmT,
                                                 u16* __restrict__ part) {
  __shared__ u8 sh8[3 * 2 * 128 * 64];   // [ring3][A/B][128][64] = 48 KB
  int lane = threadIdx.x & 63, wave = threadIdx.x >> 6;
  int bid = blockIdx.x;                  // 576 (12 dummy)
  int xcd = bid & 7, s = bid >> 3;
  int row = (s / 12) * 8 + xcd;
  if (row >= 47) return;
  int k = s % 12;
  int col0 = (k % 6) * 128, row0 = row * 128, kb = (k / 6) * (NPAD / 2);

  f32x4 acc[4][4];
  f32x4 z = {0.f, 0.f, 0.f, 0.f};
  for (int i = 0; i < 4; ++i) for (int j = 0; j < 4; ++j) acc[i][j] = z;

  const u8* Ap = Abf + (size_t)row0 * NPAD + kb;
  const u8* Bp = hmT + (size_t)col0 * NPAD + kb;
  auto pv_stage = [&](int it, u8* base) {
    stage8<128>(Ap + it * 64, NPAD, base, wave, lane);
    stage8<128>(Bp + it * 64, NPAD, base + 8192, wave, lane);
  };
  const int niter = (NPAD / 2) / 64;   // 47
  pv_stage(0, sh8);
  pv_stage(1, sh8 + 16384);
  u8* cur = sh8;                 // buffer for compute(it)
  u8* nxt = sh8 + 2 * 16384;     // buffer for stage(it+2)
  for (int it = 0; it < niter; ++it) {
    if (it == niter - 1) asm volatile("s_waitcnt vmcnt(0)" ::: "memory");
    else                 asm volatile("s_waitcnt vmcnt(4)" ::: "memory");
    __builtin_amdgcn_sched_barrier(0);
    __builtin_amdgcn_s_barrier();
    __builtin_amdgcn_sched_barrier(0);
    if (it + 2 < niter) pv_stage(it + 2, nxt);
    __builtin_amdgcn_s_setprio(1);
    mfma_step8(cur, cur + 8192, acc, lane, wave);
    __builtin_amdgcn_s_setprio(0);
    cur += 16384; if (cur == sh8 + 3 * 16384) cur = sh8;
    nxt += 16384; if (nxt == sh8 + 3 * 16384) nxt = sh8;
  }

  u16* pp = part + (size_t)(k / 6) * NPAD * (VV * HH);
  int wr = (wave >> 1) * 64, wc = (wave & 1) * 64, l15 = lane & 15, lq = lane >> 4;
#pragma unroll
  for (int i = 0; i < 4; ++i)
#pragma unroll
    for (int r = 0; r < 4; ++r) {
      int grow = row0 + wr + i * 16 + lq * 4 + r;
#pragma unroll
      for (int j = 0; j < 4; ++j) {
        int gcol = col0 + wc + j * 16 + l15;
        pp[(size_t)grow * (VV * HH) + gcol] = f2bf(acc[i][j][r]);
      }
    }
}

// newx = blend((p0+p1)/S, h); writes out_newx (f32) and nxb (bf16)
__global__ __launch_bounds__(256) void k_pvred(const u16* __restrict__ part, const float* __restrict__ S,
                                               const float* __restrict__ mT, const float* __restrict__ h,
                                               float* __restrict__ out_newx, u16* __restrict__ nxb) {
  int i = (blockIdx.x * 256 + threadIdx.x) * 4;
  int v = i / (NN * HH);
  int rem = i - v * (NN * HH);
  int n = rem / HH;
  int j = rem - n * HH;
  int col = v * HH + j;
  u16x4 p0 = *(const u16x4*)(part + (size_t)n * (VV * HH) + col);
  u16x4 p1 = *(const u16x4*)(part + (size_t)NPAD * (VV * HH) + (size_t)n * (VV * HH) + col);
  float sc = 1.0f / (S[n] + 1e-9f);
  float mrow = mT[v * NPAD + n];
  float4 o;
  o.x = (bf2f(p0[0]) + bf2f(p1[0])) * sc;
  o.y = (bf2f(p0[1]) + bf2f(p1[1])) * sc;
  o.z = (bf2f(p0[2]) + bf2f(p1[2])) * sc;
  o.w = (bf2f(p0[3]) + bf2f(p1[3])) * sc;
  if (mrow != 0.0f) o = *(const float4*)(h + (size_t)(v * NPAD + n) * HH + j);
  *(float4*)(out_newx + (size_t)(v * NN + n) * HH + j) = o;
  u16x4 ob = { f2bf(o.x), f2bf(o.y), f2bf(o.z), f2bf(o.w) };
  *(u16x4*)(nxb + (size_t)(v * NPAD + n) * HH + j) = ob;
}

// merged output GEMMs: bid<1128 -> x_new = leaky(new_x @ W_out^T + b_out), nan->0;
// bid>=1128 -> y_n = sigmoid(y @ Wy^T + by). One dispatch: ygemm's 188 blocks
// ride inside gemm3's grid (no separate under-filled launch + gap).
__global__ __launch_bounds__(256, 4) void k_out(const u16* __restrict__ nxb, const u16* __restrict__ woutb,
                                                const float* __restrict__ b_out,
                                                const u16* __restrict__ yb, const u16* __restrict__ wyb,
                                                const float* __restrict__ by,
                                                float* __restrict__ out_xnew, float* __restrict__ out_yn) {
  __shared__ u16 sh[3 * QK_BUF];
  int lane = threadIdx.x & 63, wave = threadIdx.x >> 6;
  int bid = blockIdx.x;
  f32x4 acc[2][4];
  f32x4 z = {0.f, 0.f, 0.f, 0.f};
  for (int i = 0; i < 2; ++i) for (int j = 0; j < 4; ++j) acc[i][j] = z;
  int wr = (wave >> 1) * 32, wc = (wave & 1) * 64, l15 = lane & 15, lq = lane >> 4;
  if (bid < 1128) {          // gemm3: grid (4 col, 94 row, 3 v) flattened
    int v = bid / 376, r2 = bid - v * 376;
    int col0 = (r2 & 3) * 128, row0 = (r2 >> 2) * 64;
    gemm_loop_r3(nxb + (size_t)(v * NPAD + row0) * HH, HH,
                 woutb + (size_t)(v * DD + col0) * HH, HH, HH, sh, acc, lane, wave);
#pragma unroll
    for (int i = 0; i < 2; ++i)
#pragma unroll
      for (int r = 0; r < 4; ++r) {
        int grow = row0 + wr + i * 16 + lq * 4 + r;
        if (grow < NN) {
#pragma unroll
          for (int j = 0; j < 4; ++j) {
            int gcol = col0 + wc + j * 16 + l15;
            float val = leaky(acc[i][j][r] + b_out[v * DD + gcol]);
            if (val != val) val = 0.0f;
            out_xnew[(size_t)(v * NN + grow) * DD + gcol] = val;
          }
        }
      }
  } else {                   // ygemm: grid (2 col, 94 row)
    int yid = bid - 1128;
    int col0 = (yid & 1) * 128, row0 = (yid >> 1) * 64;
    gemm_loop_r3(yb + (size_t)row0 * DYY, DYY,
                 wyb + (size_t)col0 * DYY, DYY, DYY, sh, acc, lane, wave);
#pragma unroll
    for (int i = 0; i < 2; ++i)
#pragma unroll
      for (int r = 0; r < 4; ++r) {
        int grow = row0 + wr + i * 16 + lq * 4 + r;
        if (grow < NN) {
#pragma unroll
          for (int j = 0; j < 4; ++j) {
            int gcol = col0 + wc + j * 16 + l15;
            float val = acc[i][j][r] + by[gcol];
            out_yn[(size_t)grow * HH + gcol] = 1.0f / (1.0f + __expf(-val));
          }
        }
      }
  }
}

// ---------------- launch ----------------

extern "C" void kernel_launch(void* const* d_in, const int* in_sizes, int n_in,
                              void* d_out, int out_size, void* d_ws, size_t ws_size,
                              hipStream_t stream) {
  const float* x    = (const float*)d_in[0];
  const float* y    = (const float*)d_in[1];
  const float* mask = (const float*)d_in[2];
  const float* W_in = (const float*)d_in[3];
  const float* b_in = (const float*)d_in[4];
  const float* W_out= (const float*)d_in[5];
  const float* b_out= (const float*)d_in[6];
  const float* Wy   = (const float*)d_in[7];
  const float* by   = (const float*)d_in[8];

  float* out_newx = (float*)d_out;
  float* out_xnew = out_newx + (size_t)VV * NN * HH;
  float* out_yn   = out_xnew + (size_t)VV * NN * DD;

  char* w = (char*)d_ws;
  size_t off = 0;
  auto alloc = [&](size_t bytes) -> void* {
    void* p = w + off;
    off += (bytes + 255) & ~(size_t)255;
    return p;
  };
  u16*   xb    = (u16*)alloc((size_t)VV * NPAD * DD * 2);
  u16*   yb    = (u16*)alloc((size_t)NPAD * DYY * 2);
  u16*   winb  = (u16*)alloc((size_t)VV * HH * DD * 2);
  u16*   woutb = (u16*)alloc((size_t)VV * DD * HH * 2);
  u16*   wyb   = (u16*)alloc((size_t)HH * DYY * 2);
  float* h     = (float*)alloc((size_t)VV * NPAD * HH * 4);
  u16*   qb    = (u16*)alloc((size_t)VV * NPAD * HH * 2);
  u8*    hmT   = (u8*)alloc((size_t)VV * HH * NPAD);
  u16*   nxb   = (u16*)alloc((size_t)VV * NPAD * HH * 2);
  float* mT    = (float*)alloc((size_t)VV * NPAD * 4);
  float* S     = (float*)alloc((size_t)NPAD * 4);
  u8*    Abf   = (u8*)alloc((size_t)NPAD * NPAD);
  // split-K partials (2 x NPAD x 768 bf16 = 18.48 MB) reuse xb, dead after k_gemm1
  u16*   pvp   = xb;
  (void)ws_size; (void)in_sizes; (void)n_in; (void)out_size;

  // merged conversions (4x conv + convx + mT)
  k_prep<<<(N_PREP + 255) / 256, 256, 0, stream>>>(x, y, mask, W_in, W_out, Wy,
                                                   xb, yb, winb, woutb, wyb, mT);

  // h, then fused q-norm + hmT
  k_gemm1<<<dim3(2, 94, 3), 256, 0, stream>>>(xb, winb, b_in, h);
  k_qh<<<dim3(94, 3), 256, 0, stream>>>(h, mT, qb, hmT);

  // attention
  k_qk<<<2256, 256, 0, stream>>>(qb, mT, Abf);
  k_rowsum<<<NN, 256, 0, stream>>>(Abf, S);
  k_pvsk<<<576, 256, 0, stream>>>(Abf, hmT, pvp);
  k_pvred<<<4500, 256, 0, stream>>>(pvp, S, mT, h, out_newx, nxb);

  // outputs: gemm3 (1128) + ygemm (188) in one dispatch
  k_out<<<1316, 256, 0, stream>>>(nxb, woutb, b_out, yb, wyb, by, out_xnew, out_yn);
}